// Round 6
// baseline (438.702 us; speedup 1.0000x reference)
//
#include <hip/hip_runtime.h>
#include <hip/hip_bf16.h>

#define NN 131072   // nodes per side
#define NE 524288   // edges per side
#define NB 1024     // batch (graphs per side)

typedef __attribute__((ext_vector_type(8))) short short8;   // 8 bf16
typedef __attribute__((ext_vector_type(4))) float f32x4;

__device__ __forceinline__ float wsum(float v){
#pragma unroll
  for (int o = 32; o > 0; o >>= 1) v += __shfl_xor(v, o, 64);
  return v;
}
__device__ __forceinline__ short f2bs(float f){
  __hip_bfloat16 t = __float2bfloat16(f);
  union { __hip_bfloat16 b; short s; } u; u.b = t; return u.s;
}
__device__ __forceinline__ float bs2f(short s){
  return __uint_as_float(((unsigned)(unsigned short)s) << 16);
}
__device__ __forceinline__ float ulo2f(unsigned v){ return __uint_as_float(v << 16); }
__device__ __forceinline__ float uhi2f(unsigned v){ return __uint_as_float(v & 0xFFFF0000u); }
__device__ __forceinline__ unsigned fpack(float x, float y){
  return (unsigned)(unsigned short)f2bs(x) | ((unsigned)(unsigned short)f2bs(y) << 16);
}

// ---------------- mega: hist(+slot record, 4 counters/64B line) | frag pack | waA/ba/rtab | wconv | prep ----------------
__global__ void k_mega(int wconvB,
                       const int* __restrict__ u_ei, const int* __restrict__ i_ei,
                       int* __restrict__ cnt, int* __restrict__ loff,
                       const float* __restrict__ wemb, unsigned* __restrict__ wtab,
                       int n32,
                       const float* __restrict__ cuW, const float* __restrict__ ciW,
                       const float* __restrict__ pW,
                       const float* __restrict__ cub, const float* __restrict__ cib,
                       const float* __restrict__ uatt, const float* __restrict__ iatt,
                       const float* __restrict__ urel, const float* __restrict__ irel,
                       short8* __restrict__ frag, float* __restrict__ waA,
                       float* __restrict__ ba, float* __restrict__ rtab,
                       const int* __restrict__ uid, const int* __restrict__ iid,
                       const float* __restrict__ uemb, const float* __restrict__ iemb,
                       const float* __restrict__ uiW, const float* __restrict__ uib,
                       const float* __restrict__ iiW, const float* __restrict__ iib,
                       const float* __restrict__ utW, const float* __restrict__ utb,
                       const float* __restrict__ itW, const float* __restrict__ itb,
                       float* __restrict__ xfm, float* __restrict__ q){
  const int histB = 2 * NE / 256;     // single pass, all lanes live
  int blk = blockIdx.x, tid = threadIdx.x;
  if (blk < histB){
    // histogram + per-edge slot record; 4 counters per 64B line
    int ee = blk * 256 + tid;
    int side = ee >= NE;
    int e = ee - side * NE;
    const int* ei = side ? i_ei : u_ei;
    int dst = ei[NE + e] + side * NN;
    int p = atomicAdd(&cnt[dst << 2], 1);
    loff[ee] = p;                     // coalesced
  } else if (blk < histB + 10){
    int b2 = blk - histB;
    int mat = b2 >> 1;
    const float* W = mat < 2 ? cuW + mat * 4096 : (mat < 4 ? ciW + (mat - 2) * 4096 : pW);
    int g = (b2 & 1) * 256 + tid;     // [0,512)
    int lane = g & 63, rest = g >> 6;
    int hh = rest & 1, t = rest >> 1;
    int m = lane & 15, qq = lane >> 4;
    short8 v;
#pragma unroll
    for (int j = 0; j < 8; j++)
      v[j] = f2bs(W[(hh * 32 + qq * 8 + j) * 64 + (t * 16 + m)]);
    frag[mat * 512 + g] = v;
  } else if (blk < histB + 12){
    int side = blk - histB - 10;
    const float* W    = side ? ciW : cuW;
    const float* bias = side ? cib : cub;
    const float* att  = side ? iatt : uatt;
    const float* rel  = side ? irel : urel;
    int l = tid >> 7, a = (tid >> 6) & 1, kk = tid & 63;
    float s = 0.f;
    for (int c = 0; c < 64; c++) s += W[l * 4096 + kk * 64 + c] * att[l * 192 + a * 64 + c];
    waA[((side * 2 + l) * 2 + a) * 64 + kk] = s;
    if (tid < 4){
      int l2 = tid >> 1, a2 = tid & 1;
      float sb = 0.f;
      for (int c = 0; c < 64; c++) sb += bias[l2 * 64 + c] * att[l2 * 192 + a2 * 64 + c];
      ba[(side * 2 + l2) * 2 + a2] = sb;
    }
    if (tid >= 4 && tid < 12){
      int id = tid - 4, l2 = id >> 2, tt = id & 3;
      float sr = 0.f;
      for (int c = 0; c < 64; c++) sr += rel[l2 * 256 + tt * 64 + c] * att[l2 * 192 + 128 + c];
      rtab[(side * 2 + l2) * 4 + tt] = sr;
    }
  } else if (blk < histB + 12 + wconvB){
    int id = (blk - histB - 12) * 256 + tid;
    if (id < n32){
      const float2* src = (const float2*)wemb;
      float2 v = src[id];
      wtab[id] = fpack(v.x, v.y);
    }
  } else {
    int lane = tid & 63, w = tid >> 6;
    int b = (blk - histB - 12 - wconvB) * 4 + w;   // [0, 2NB)
    int side = b >= NB;
    int lb = b - side * NB;
    const int* ids = side ? iid : uid;
    const float* emb = side ? iemb : uemb;
    const float* interW = side ? iiW : uiW;
    const float* interB = side ? iib : uib;
    const float* transW = side ? itW : utW;
    const float* transB = side ? itb : utb;
    int repOff = side ? 192 : 0;
    float xe = emb[(long)ids[lb] * 64 + lane];
    float o = interB[lane];
#pragma unroll
    for (int k = 0; k < 64; k++) o += __shfl(xe, k, 64) * interW[k * 64 + lane];
    xfm[lb * 384 + repOff + lane] = fmaxf(o, 0.f);
    for (int l = 0; l < 2; l++){
      float t = transB[l * 64 + lane];
#pragma unroll
      for (int k = 0; k < 64; k++) t += __shfl(xe, k, 64) * transW[l * 4096 + k * 64 + lane];
      q[((size_t)(side * 2 + l) * NB + lb) * 64 + lane] = fmaxf(t, 0.f);
    }
  }
}

__global__ void k_scan1(const int* __restrict__ cnt, int* __restrict__ rowptr,
                        int* __restrict__ bsum){
  __shared__ int sh[256];
  int i = blockIdx.x * 256 + threadIdx.x;
  int v = cnt[i << 2];
  sh[threadIdx.x] = v; __syncthreads();
  for (int off = 1; off < 256; off <<= 1){
    int t = (threadIdx.x >= off) ? sh[threadIdx.x - off] : 0;
    __syncthreads();
    sh[threadIdx.x] += t;
    __syncthreads();
  }
  int incl = sh[threadIdx.x];
  rowptr[i] = incl - v;
  if (threadIdx.x == 255) bsum[blockIdx.x] = incl;
}

__global__ void k_scan2(int* __restrict__ bsum){
  __shared__ int sh[1024];
  int v = bsum[threadIdx.x];
  sh[threadIdx.x] = v; __syncthreads();
  for (int off = 1; off < 1024; off <<= 1){
    int t = (threadIdx.x >= off) ? sh[threadIdx.x - off] : 0;
    __syncthreads();
    sh[threadIdx.x] += t;
    __syncthreads();
  }
  bsum[threadIdx.x] = sh[threadIdx.x] - v;  // exclusive
}

// ---------------- atomic-free scatter | word-level a0/a1 tables | rowptr finalize ----------------
__global__ void k_scw(const int* __restrict__ u_ei, const int* __restrict__ i_ei,
                      const int* __restrict__ u_et, const int* __restrict__ i_et,
                      const int* __restrict__ rowptr, const int* __restrict__ bsum,
                      const int* __restrict__ loff, int* __restrict__ pedge,
                      int* __restrict__ rowfin,
                      const short* __restrict__ wtab, int nwords, int wgB,
                      const float* __restrict__ waA, const float* __restrict__ ba,
                      float* __restrict__ wa0, float* __restrict__ wa1){
  const int scatB = 2 * NE / 256;
  int blk = blockIdx.x, tid = threadIdx.x;
  if (blk < scatB){
    int ee = blk * 256 + tid;
    int side = ee >= NE;
    int e = ee - side * NE;
    const int* ei = side ? i_ei : u_ei;
    const int* et = side ? i_et : u_et;
    int dst = ei[NE + e] + side * NN;
    int src = ei[e] + side * NN;
    int p = rowptr[dst] + bsum[dst >> 8] + loff[ee];
    pedge[p] = src | (et[e] << 18);
  } else if (blk < scatB + wgB){
    // wa0/wa1[side][word] = wtab[word] . waA(side,l=0,a) + ba
    int lane = tid & 63, w = tid >> 6;
    int q = lane >> 4, cl = lane & 15;
    int sw0 = ((blk - scatB) * 4 + w) * 8;
    const uint2* wt2 = (const uint2*)wtab;
    for (int it = 0; it < 2; it++){
      int wj = sw0 + it * 4 + q;
      if (wj >= 2 * nwords) continue;
      int side = wj >= nwords;
      int wid = wj - side * nwords;
      const float* A0 = waA + (side * 2 + 0) * 2 * 64;
      const float* A1 = A0 + 64;
      uint2 v = wt2[(long)wid * 16 + cl];
      int d = 4 * cl;
      float p0 = ulo2f(v.x) * A0[d] + uhi2f(v.x) * A0[d + 1] +
                 ulo2f(v.y) * A0[d + 2] + uhi2f(v.y) * A0[d + 3];
      float p1 = ulo2f(v.x) * A1[d] + uhi2f(v.x) * A1[d + 1] +
                 ulo2f(v.y) * A1[d + 2] + uhi2f(v.y) * A1[d + 3];
      p0 += __shfl_xor(p0, 1, 64); p0 += __shfl_xor(p0, 2, 64);
      p0 += __shfl_xor(p0, 4, 64); p0 += __shfl_xor(p0, 8, 64);
      p1 += __shfl_xor(p1, 1, 64); p1 += __shfl_xor(p1, 2, 64);
      p1 += __shfl_xor(p1, 4, 64); p1 += __shfl_xor(p1, 8, 64);
      if (cl == 0){
        wa0[(size_t)side * nwords + wid] = p0 + ba[side * 4 + 0];
        wa1[(size_t)side * nwords + wid] = p1 + ba[side * 4 + 1];
      }
    }
  } else {
    // finalize rowptr into a separate array (scatter blocks still read the partial one)
    int i = (blk - scatB - wgB) * 256 + tid;
    rowfin[i] = rowptr[i] + bsum[i >> 8];
    if (i == 0) rowfin[2 * NN] = 2 * NE;
  }
}

// ---------------- aggregation: xagg[dst] = sum_e softmax(e) * x[src_e] (no relu) ----------------
// Shuffle-free: one node per 16-lane group (4 nodes/wave). All 16 lanes walk the
// node's edge list together; scalar values (pedge, a0, wid) load via same-address
// broadcast; exp computed redundantly per lane; features gathered as uint2 slices;
// accumulators stay in-lane -> zero cross-lane ops.
template<int L>
__device__ __forceinline__ void dev_agg(
    const int* __restrict__ rowptr, const int* __restrict__ pedge,
    const float* __restrict__ a0, const float* __restrict__ a1,        // L==1
    const float* __restrict__ wa0, const float* __restrict__ wa1,      // L==0
    const int* __restrict__ u_nodes, const int* __restrict__ i_nodes, int nwords,
    const float* __restrict__ rtab, const short* __restrict__ rows,
    unsigned* __restrict__ xo32){
  int lane = threadIdx.x & 63, w = threadIdx.x >> 6;
  int grp = lane >> 4, cl = lane & 15;
  int n = (blockIdx.x * 4 + w) * 4 + grp;         // node for this 16-lane group
  int side = n >= NN;                              // uniform per block (16 | NN)
  const float* rt = rtab + (side * 2 + L) * 4;
  float rt0 = rt[0], rt1 = rt[1], rt2 = rt[2], rt3 = rt[3];
  const int* nodesS = side ? i_nodes : u_nodes;
  const float* wa0S = wa0 + (size_t)side * nwords;
  const float* wa1S = wa1 + (size_t)side * nwords;
  const uint2* h2 = (const uint2*)rows;

  int r0 = rowptr[n], r1 = rowptr[n + 1];          // broadcast loads
  float a1n;
  if (L == 0) a1n = wa1S[nodesS[n - side * NN]];
  else        a1n = a1[n];

  float ax0 = 0.f, ay0 = 0.f, ax1 = 0.f, ay1 = 0.f, den = 0.f;
  for (int e = r0; e < r1; ++e){
    int pe = pedge[e];                             // broadcast (L2-hot)
    int s = pe & 0x3FFFF;
    int et = (pe >> 18) & 3;
    float rr = (et & 2) ? ((et & 1) ? rt3 : rt2) : ((et & 1) ? rt1 : rt0);
    float av; long row;
    if (L == 0){ int wid = nodesS[s - side * NN]; av = wa0S[wid]; row = wid; }
    else       { av = a0[s]; row = s; }
    float v = av + a1n + rr;
    v = (v > 0.f) ? v : 0.2f * v;
    float ex = __expf(v);
    uint2 hv = h2[row * 16 + cl];                  // per-lane feature slice
    ax0 += ex * ulo2f(hv.x); ay0 += ex * uhi2f(hv.x);
    ax1 += ex * ulo2f(hv.y); ay1 += ex * uhi2f(hv.y);
    den += ex;
  }
  float inv = 1.f / (den + 1e-16f);
  uint2 o;
  o.x = fpack(ax0 * inv, ay0 * inv);
  o.y = fpack(ax1 * inv, ay1 * inv);
  ((uint2*)xo32)[(long)n * 16 + cl] = o;           // coalesced: 512B per wave
}

__global__ __launch_bounds__(256) void k_agg0(
    const int* __restrict__ rowptr, const int* __restrict__ pedge,
    const float* __restrict__ wa0, const float* __restrict__ wa1,
    const int* __restrict__ u_nodes, const int* __restrict__ i_nodes, int nwords,
    const float* __restrict__ rtab, const short* __restrict__ wtab,
    unsigned* __restrict__ xo32){
  dev_agg<0>(rowptr, pedge, nullptr, nullptr, wa0, wa1, u_nodes, i_nodes, nwords,
             rtab, wtab, xo32);
}

__global__ __launch_bounds__(256) void k_agg1(
    const int* __restrict__ rowptr, const int* __restrict__ pedge,
    const float* __restrict__ a0, const float* __restrict__ a1,
    const float* __restrict__ rtab, const short* __restrict__ x,
    unsigned* __restrict__ xo32){
  dev_agg<1>(rowptr, pedge, a0, a1, nullptr, nullptr, nullptr, nullptr, 0,
             rtab, x, xo32);
}

// ---------------- fused post: x=relu(xagg@W+b); gates; gmp; trans_w; gated X1 + a0/a1 ----------------
__global__ __launch_bounds__(256) void k_gp(
    int l, const short* __restrict__ xagg, const short8* __restrict__ frag,
    const float* __restrict__ cub, const float* __restrict__ cib,
    const float* __restrict__ waA_all, const float* __restrict__ ba_all,
    const float* __restrict__ qbuf, const float* __restrict__ twW_all,
    const float* __restrict__ twb_all, float* __restrict__ xfm,
    short* __restrict__ xnext, float* __restrict__ a0, float* __restrict__ a1){
  __shared__ short xt[128 * 72];       // padded rows (72 shorts) for bank spread
  __shared__ float gates[128];
  __shared__ float red[4][64];
  int b = blockIdx.x;                  // [0, 2NB)
  int side = b >= NB;
  int g = b - side * NB;
  long base = (long)side * NN + (long)g * 128;
  int tid = threadIdx.x, lane = tid & 63, w = tid >> 6;
  int m = lane & 15, q = lane >> 4;
  // stage A: conv GEMM
  const short8* wfrag = frag + (side * 2 + l) * 512;
  const float* bias = (side ? cib : cub) + l * 64;
  short8 Bf[4][2];
#pragma unroll
  for (int t = 0; t < 4; t++)
#pragma unroll
    for (int hh = 0; hh < 2; hh++)
      Bf[t][hh] = wfrag[(t * 2 + hh) * 64 + lane];
  float bs[4];
#pragma unroll
  for (int t = 0; t < 4; t++) bs[t] = bias[t * 16 + m];
  f32x4 accA[2][4];
#pragma unroll
  for (int rb = 0; rb < 2; rb++){
    long n0 = base + w * 32 + rb * 16;
    const short8* xr = (const short8*)(xagg + (n0 + m) * 64);
    short8 A0 = xr[q];
    short8 A1 = xr[q + 4];
#pragma unroll
    for (int t = 0; t < 4; t++){
      f32x4 acc = (f32x4){bs[t], bs[t], bs[t], bs[t]};
      acc = __builtin_amdgcn_mfma_f32_16x16x32_bf16(A0, Bf[t][0], acc, 0, 0, 0);
      acc = __builtin_amdgcn_mfma_f32_16x16x32_bf16(A1, Bf[t][1], acc, 0, 0, 0);
#pragma unroll
      for (int r = 0; r < 4; r++) acc[r] = fmaxf(acc[r], 0.f);
      accA[rb][t] = acc;
#pragma unroll
      for (int r = 0; r < 4; r++)
        xt[(w * 32 + rb * 16 + q * 4 + r) * 72 + t * 16 + m] = f2bs(acc[r]);
    }
  }
  __syncthreads();
  // stage B: pool GEMM from LDS -> gates
  const short8* pfrag = frag + 4 * 512;
  const float* qv_ = qbuf + ((size_t)(side * 2 + l) * NB + g) * 64;
  short8 Pf[4][2];
#pragma unroll
  for (int t = 0; t < 4; t++)
#pragma unroll
    for (int hh = 0; hh < 2; hh++)
      Pf[t][hh] = pfrag[(t * 2 + hh) * 64 + lane];
  float qv[4];
#pragma unroll
  for (int t = 0; t < 4; t++) qv[t] = qv_[t * 16 + m];
#pragma unroll
  for (int rb = 0; rb < 2; rb++){
    int rowb = w * 32 + rb * 16;
    short8 A0 = *(const short8*)(xt + (rowb + m) * 72 + q * 8);
    short8 A1 = *(const short8*)(xt + (rowb + m) * 72 + 32 + q * 8);
    f32x4 accp[4];
#pragma unroll
    for (int t = 0; t < 4; t++){
      accp[t] = (f32x4){0.f, 0.f, 0.f, 0.f};
      accp[t] = __builtin_amdgcn_mfma_f32_16x16x32_bf16(A0, Pf[t][0], accp[t], 0, 0, 0);
      accp[t] = __builtin_amdgcn_mfma_f32_16x16x32_bf16(A1, Pf[t][1], accp[t], 0, 0, 0);
    }
#pragma unroll
    for (int r = 0; r < 4; r++){
      float p = accp[0][r] * qv[0] + accp[1][r] * qv[1] +
                accp[2][r] * qv[2] + accp[3][r] * qv[3];
      p += __shfl_xor(p, 1, 64); p += __shfl_xor(p, 2, 64);
      p += __shfl_xor(p, 4, 64); p += __shfl_xor(p, 8, 64);
      if (m == 0)
        gates[rowb + q * 4 + r] = 1.f / (1.f + __expf(-p * 0.125f));
    }
  }
  __syncthreads();
  // gated max pool
  const unsigned* xt32 = (const unsigned*)xt;
  int c = lane & 31, half = lane >> 5;
  float mxx = 0.f, mxy = 0.f;
#pragma unroll
  for (int p = 0; p < 16; p++){
    int nn = w * 32 + 2 * p + half;
    unsigned v = xt32[nn * 36 + c];
    float gt = gates[nn];
    mxx = fmaxf(mxx, ulo2f(v) * gt);
    mxy = fmaxf(mxy, uhi2f(v) * gt);
  }
  mxx = fmaxf(mxx, __shfl_xor(mxx, 32, 64));
  mxy = fmaxf(mxy, __shfl_xor(mxy, 32, 64));
  if (half == 0){ red[w][2 * c] = mxx; red[w][2 * c + 1] = mxy; }
  __syncthreads();
  if (tid < 64){
    const float* twW = twW_all + l * 4096;
    const float* twb = twb_all + l * 64;
    int off = (side ? 256 : 64) + l * 64;
    float p = fmaxf(fmaxf(red[0][tid], red[1][tid]), fmaxf(red[2][tid], red[3][tid]));
    float o = twb[tid];
    red[0][tid] = p;
    __syncwarp();
    for (int d = 0; d < 64; d++) o += red[0][d] * twW[d * 64 + tid];
    xfm[g * 384 + off + tid] = fmaxf(o, 0.f);
  }
  if (l == 0){
    // gated next-layer input write (coalesced via LDS)
#pragma unroll
    for (int p = 0; p < 4; p++){
      int row = p * 32 + (tid >> 3);
      int col8 = (tid & 7) * 8;
      float gt = gates[row];
      short8 v = *(const short8*)(xt + row * 72 + col8);
      short8 o;
#pragma unroll
      for (int j = 0; j < 8; j++) o[j] = f2bs(bs2f(v[j]) * gt);
      *(short8*)(xnext + (base + row) * 64 + col8) = o;
    }
    // next-layer a0/a1 from gated x_next: a = g*(x.waA1) + ba1
    const float* wn0p = waA_all + ((side * 2 + 1) * 2 + 0) * 64;
    const float* wn1p = wn0p + 64;
    float wn0[4], wn1[4];
#pragma unroll
    for (int t = 0; t < 4; t++){ wn0[t] = wn0p[t * 16 + m]; wn1[t] = wn1p[t * 16 + m]; }
    float ban0 = ba_all[(side * 2 + 1) * 2 + 0];
    float ban1 = ba_all[(side * 2 + 1) * 2 + 1];
#pragma unroll
    for (int rb = 0; rb < 2; rb++)
#pragma unroll
      for (int r = 0; r < 4; r++){
        float p0 = accA[rb][0][r] * wn0[0] + accA[rb][1][r] * wn0[1] +
                   accA[rb][2][r] * wn0[2] + accA[rb][3][r] * wn0[3];
        float p1 = accA[rb][0][r] * wn1[0] + accA[rb][1][r] * wn1[1] +
                   accA[rb][2][r] * wn1[2] + accA[rb][3][r] * wn1[3];
        p0 += __shfl_xor(p0, 1, 64); p0 += __shfl_xor(p0, 2, 64);
        p0 += __shfl_xor(p0, 4, 64); p0 += __shfl_xor(p0, 8, 64);
        p1 += __shfl_xor(p1, 1, 64); p1 += __shfl_xor(p1, 2, 64);
        p1 += __shfl_xor(p1, 4, 64); p1 += __shfl_xor(p1, 8, 64);
        if (m == 0){
          int row = w * 32 + rb * 16 + q * 4 + r;
          float gr = gates[row];
          a0[base + row] = p0 * gr + ban0;
          a1[base + row] = p1 * gr + ban1;
        }
      }
  }
}

// ---------------- FM head: 4 graphs per block, V streamed once per block ----------------
__global__ __launch_bounds__(384) void k_fm(
    const float* __restrict__ xfm, const float* __restrict__ V,
    const float* __restrict__ fw, const float* __restrict__ bu,
    const float* __restrict__ bi, const float* __restrict__ b0,
    const int* __restrict__ uid, const int* __restrict__ iid,
    float* __restrict__ out){
  __shared__ float xsh[4][384];
  __shared__ float xsq[4][384];
  __shared__ float part[4][384];
  int j = threadIdx.x;
  int g0 = blockIdx.x * 4;
#pragma unroll
  for (int b = 0; b < 4; b++){
    float xv_ = xfm[(g0 + b) * 384 + j];
    xsh[b][j] = xv_;
    xsq[b][j] = xv_ * xv_;
  }
  __syncthreads();
  float xv[4] = {0.f, 0.f, 0.f, 0.f};
  float vv[4] = {0.f, 0.f, 0.f, 0.f};
  for (int k = 0; k < 384; k++){
    float v = V[(size_t)k * 384 + j];
    float v2 = v * v;
#pragma unroll
    for (int b = 0; b < 4; b++){
      xv[b] = fmaf(xsh[b][k], v, xv[b]);
      vv[b] = fmaf(xsq[b][k], v2, vv[b]);
    }
  }
  float fwj = fw[j];
#pragma unroll
  for (int b = 0; b < 4; b++)
    part[b][j] = 0.5f * (xv[b] * xv[b] - vv[b]) + xsh[b][j] * fwj;
  __syncthreads();
  int w = j >> 6, lane = j & 63;
  if (w < 4){
    float s = part[w][lane] + part[w][lane + 64] + part[w][lane + 128] +
              part[w][lane + 192] + part[w][lane + 256] + part[w][lane + 320];
    s = wsum(s);
    if (lane == 0){
      int b = g0 + w;
      out[b] = s + bu[uid[b]] + bi[iid[b]] + b0[0];
    }
  }
}

extern "C" void kernel_launch(void* const* d_in, const int* in_sizes, int n_in,
                              void* d_out, int out_size, void* d_ws, size_t ws_size,
                              hipStream_t stream) {
  const int* uid      = (const int*)d_in[0];
  const int* iid      = (const int*)d_in[1];
  const int* u_nodes  = (const int*)d_in[2];
  const int* i_nodes  = (const int*)d_in[3];
  const int* u_ei     = (const int*)d_in[4];
  const int* i_ei     = (const int*)d_in[5];
  const int* u_et     = (const int*)d_in[6];
  const int* i_et     = (const int*)d_in[7];
  const float* user_emb = (const float*)d_in[10];
  const float* item_emb = (const float*)d_in[11];
  const float* word_emb = (const float*)d_in[12];
  const float* trans_u_W = (const float*)d_in[13];
  const float* trans_u_b = (const float*)d_in[14];
  const float* trans_i_W = (const float*)d_in[15];
  const float* trans_i_b = (const float*)d_in[16];
  const float* trans_w_W = (const float*)d_in[17];
  const float* trans_w_b = (const float*)d_in[18];
  const float* inter_u_W = (const float*)d_in[19];
  const float* inter_u_b = (const float*)d_in[20];
  const float* inter_i_W = (const float*)d_in[21];
  const float* inter_i_b = (const float*)d_in[22];
  const float* conv_u_W  = (const float*)d_in[23];
  const float* conv_u_b  = (const float*)d_in[24];
  const float* conv_u_att= (const float*)d_in[25];
  const float* conv_u_rel= (const float*)d_in[26];
  const float* conv_i_W  = (const float*)d_in[27];
  const float* conv_i_b  = (const float*)d_in[28];
  const float* conv_i_att= (const float*)d_in[29];
  const float* conv_i_rel= (const float*)d_in[30];
  const float* pool_W    = (const float*)d_in[31];
  const float* fm_w      = (const float*)d_in[32];
  const float* fm_V      = (const float*)d_in[33];
  const float* fm_bias_u = (const float*)d_in[34];
  const float* fm_bias_i = (const float*)d_in[35];
  const float* fm_bias   = (const float*)d_in[36];
  float* out = (float*)d_out;
  int n32 = in_sizes[12] / 2;          // packed uints in word table
  int nwords = in_sizes[12] / 64;      // words (HID=64)
  int wconvB = (n32 + 255) / 256;

  // workspace carve-up (cnt aliases X1; loff aliases X0 — both dead before X0/X1 are written)
  char* w = (char*)d_ws;
  short* X0   = (short*)w;          w += (size_t)2 * NN * 64 * 2;   // 32 MB
  short* X1   = (short*)w;          w += (size_t)2 * NN * 64 * 2;   // 32 MB
  short* wtab = (short*)w;          w += (size_t)in_sizes[12] * 2;  // bf16 word table
  int* pedge  = (int*)w;            w += (size_t)2 * NE * 4;
  float* a0   = (float*)w;          w += (size_t)2 * NN * 4;
  float* a1   = (float*)w;          w += (size_t)2 * NN * 4;
  float* wa0  = (float*)w;          w += (size_t)2 * nwords * 4;
  float* wa1  = (float*)w;          w += (size_t)2 * nwords * 4;
  int* rowptr = (int*)w;            w += (size_t)2 * NN * 4;        // partial (block-local scan)
  int* rowfin = (int*)w;            w += (size_t)(2 * NN + 256) * 4;
  int* bsum   = (int*)w;            w += 1024 * 4;
  short8* frag = (short8*)w;        w += (size_t)5 * 512 * 16;
  float* waA  = (float*)w;          w += 2 * 2 * 2 * 64 * 4;
  float* ba   = (float*)w;          w += 64;
  float* rtab = (float*)w;          w += 64;
  float* qbuf = (float*)w;          w += (size_t)4 * NB * 64 * 4;
  float* xfm  = (float*)w;          w += (size_t)NB * 384 * 4;
  int* cnt  = (int*)X1;             // 2*NN*16 B = 4 MB, dead before k_gp<0> writes X1
  int* loff = (int*)X0;             // 2*NE*4 B = 4 MB, dead before k_agg0 writes X0

  hipMemsetAsync(cnt, 0, (size_t)2 * NN * 16, stream);

  int histB = 2 * NE / 256;
  int megaB = histB + 12 + wconvB + 2 * NB / 4;
  k_mega<<<megaB, 256, 0, stream>>>(wconvB, u_ei, i_ei, cnt, loff,
                                    word_emb, (unsigned*)wtab, n32,
                                    conv_u_W, conv_i_W, pool_W, conv_u_b, conv_i_b,
                                    conv_u_att, conv_i_att, conv_u_rel, conv_i_rel,
                                    frag, waA, ba, rtab,
                                    uid, iid, user_emb, item_emb,
                                    inter_u_W, inter_u_b, inter_i_W, inter_i_b,
                                    trans_u_W, trans_u_b, trans_i_W, trans_i_b,
                                    xfm, qbuf);
  k_scan1<<<2 * NN / 256, 256, 0, stream>>>(cnt, rowptr, bsum);
  k_scan2<<<1, 1024, 0, stream>>>(bsum);
  int wgB = (2 * nwords + 31) / 32;
  int scatB = 2 * NE / 256;
  int finB = 2 * NN / 256;
  k_scw<<<scatB + wgB + finB, 256, 0, stream>>>(u_ei, i_ei, u_et, i_et,
                                                rowptr, bsum, loff, pedge, rowfin,
                                                wtab, nwords, wgB, waA, ba, wa0, wa1);

  // layer 0: aggregate straight from the word table
  k_agg0<<<2 * NN / 16, 256, 0, stream>>>(rowfin, pedge, wa0, wa1,
                                          u_nodes, i_nodes, nwords, rtab,
                                          wtab, (unsigned*)X0);
  k_gp  <<<2 * NB, 256, 0, stream>>>(0, X0, frag, conv_u_b, conv_i_b, waA, ba,
                                     qbuf, trans_w_W, trans_w_b, xfm, X1, a0, a1);
  // layer 1
  k_agg1<<<2 * NN / 16, 256, 0, stream>>>(rowfin, pedge, a0, a1, rtab,
                                          X1, (unsigned*)X0);
  k_gp  <<<2 * NB, 256, 0, stream>>>(1, X0, frag, conv_u_b, conv_i_b, waA, ba,
                                     qbuf, trans_w_W, trans_w_b, xfm,
                                     nullptr, nullptr, nullptr);

  k_fm<<<NB / 4, 384, 0, stream>>>(xfm, fm_V, fm_w, fm_bias_u, fm_bias_i, fm_bias,
                                   uid, iid, out);
}

// Round 7
// 414.411 us; speedup vs baseline: 1.0586x; 1.0586x over previous
//
#include <hip/hip_runtime.h>
#include <hip/hip_bf16.h>

#define NN 131072   // nodes per side
#define NE 524288   // edges per side
#define NB 1024     // batch (graphs per side)

typedef __attribute__((ext_vector_type(8))) short short8;   // 8 bf16
typedef __attribute__((ext_vector_type(4))) float f32x4;

__device__ __forceinline__ float wsum(float v){
#pragma unroll
  for (int o = 32; o > 0; o >>= 1) v += __shfl_xor(v, o, 64);
  return v;
}
__device__ __forceinline__ short f2bs(float f){
  __hip_bfloat16 t = __float2bfloat16(f);
  union { __hip_bfloat16 b; short s; } u; u.b = t; return u.s;
}
__device__ __forceinline__ float bs2f(short s){
  return __uint_as_float(((unsigned)(unsigned short)s) << 16);
}
__device__ __forceinline__ float ulo2f(unsigned v){ return __uint_as_float(v << 16); }
__device__ __forceinline__ float uhi2f(unsigned v){ return __uint_as_float(v & 0xFFFF0000u); }
__device__ __forceinline__ unsigned fpack(float x, float y){
  return (unsigned)(unsigned short)f2bs(x) | ((unsigned)(unsigned short)f2bs(y) << 16);
}

// ---------------- mega: hist(+slot record, 4 counters/64B line) | frag pack | waA/ba/rtab | wconv | prep ----------------
__global__ void k_mega(int wconvB,
                       const int* __restrict__ u_ei, const int* __restrict__ i_ei,
                       int* __restrict__ cnt, int* __restrict__ loff,
                       const float* __restrict__ wemb, unsigned* __restrict__ wtab,
                       int n32,
                       const float* __restrict__ cuW, const float* __restrict__ ciW,
                       const float* __restrict__ pW,
                       const float* __restrict__ cub, const float* __restrict__ cib,
                       const float* __restrict__ uatt, const float* __restrict__ iatt,
                       const float* __restrict__ urel, const float* __restrict__ irel,
                       short8* __restrict__ frag, float* __restrict__ waA,
                       float* __restrict__ ba, float* __restrict__ rtab,
                       const int* __restrict__ uid, const int* __restrict__ iid,
                       const float* __restrict__ uemb, const float* __restrict__ iemb,
                       const float* __restrict__ uiW, const float* __restrict__ uib,
                       const float* __restrict__ iiW, const float* __restrict__ iib,
                       const float* __restrict__ utW, const float* __restrict__ utb,
                       const float* __restrict__ itW, const float* __restrict__ itb,
                       float* __restrict__ xfm, float* __restrict__ q){
  const int histB = 2 * NE / 256;     // single pass, all lanes live
  int blk = blockIdx.x, tid = threadIdx.x;
  if (blk < histB){
    // histogram + per-edge slot record; 4 counters per 64B line
    int ee = blk * 256 + tid;
    int side = ee >= NE;
    int e = ee - side * NE;
    const int* ei = side ? i_ei : u_ei;
    int dst = ei[NE + e] + side * NN;
    int p = atomicAdd(&cnt[dst << 2], 1);
    loff[ee] = p;                     // coalesced
  } else if (blk < histB + 10){
    int b2 = blk - histB;
    int mat = b2 >> 1;
    const float* W = mat < 2 ? cuW + mat * 4096 : (mat < 4 ? ciW + (mat - 2) * 4096 : pW);
    int g = (b2 & 1) * 256 + tid;     // [0,512)
    int lane = g & 63, rest = g >> 6;
    int hh = rest & 1, t = rest >> 1;
    int m = lane & 15, qq = lane >> 4;
    short8 v;
#pragma unroll
    for (int j = 0; j < 8; j++)
      v[j] = f2bs(W[(hh * 32 + qq * 8 + j) * 64 + (t * 16 + m)]);
    frag[mat * 512 + g] = v;
  } else if (blk < histB + 12){
    int side = blk - histB - 10;
    const float* W    = side ? ciW : cuW;
    const float* bias = side ? cib : cub;
    const float* att  = side ? iatt : uatt;
    const float* rel  = side ? irel : urel;
    int l = tid >> 7, a = (tid >> 6) & 1, kk = tid & 63;
    float s = 0.f;
    for (int c = 0; c < 64; c++) s += W[l * 4096 + kk * 64 + c] * att[l * 192 + a * 64 + c];
    waA[((side * 2 + l) * 2 + a) * 64 + kk] = s;
    if (tid < 4){
      int l2 = tid >> 1, a2 = tid & 1;
      float sb = 0.f;
      for (int c = 0; c < 64; c++) sb += bias[l2 * 64 + c] * att[l2 * 192 + a2 * 64 + c];
      ba[(side * 2 + l2) * 2 + a2] = sb;
    }
    if (tid >= 4 && tid < 12){
      int id = tid - 4, l2 = id >> 2, tt = id & 3;
      float sr = 0.f;
      for (int c = 0; c < 64; c++) sr += rel[l2 * 256 + tt * 64 + c] * att[l2 * 192 + 128 + c];
      rtab[(side * 2 + l2) * 4 + tt] = sr;
    }
  } else if (blk < histB + 12 + wconvB){
    int id = (blk - histB - 12) * 256 + tid;
    if (id < n32){
      const float2* src = (const float2*)wemb;
      float2 v = src[id];
      wtab[id] = fpack(v.x, v.y);
    }
  } else {
    int lane = tid & 63, w = tid >> 6;
    int b = (blk - histB - 12 - wconvB) * 4 + w;   // [0, 2NB)
    int side = b >= NB;
    int lb = b - side * NB;
    const int* ids = side ? iid : uid;
    const float* emb = side ? iemb : uemb;
    const float* interW = side ? iiW : uiW;
    const float* interB = side ? iib : uib;
    const float* transW = side ? itW : utW;
    const float* transB = side ? itb : utb;
    int repOff = side ? 192 : 0;
    float xe = emb[(long)ids[lb] * 64 + lane];
    float o = interB[lane];
#pragma unroll
    for (int k = 0; k < 64; k++) o += __shfl(xe, k, 64) * interW[k * 64 + lane];
    xfm[lb * 384 + repOff + lane] = fmaxf(o, 0.f);
    for (int l = 0; l < 2; l++){
      float t = transB[l * 64 + lane];
#pragma unroll
      for (int k = 0; k < 64; k++) t += __shfl(xe, k, 64) * transW[l * 4096 + k * 64 + lane];
      q[((size_t)(side * 2 + l) * NB + lb) * 64 + lane] = fmaxf(t, 0.f);
    }
  }
}

__global__ void k_scan1(const int* __restrict__ cnt, int* __restrict__ rowptr,
                        int* __restrict__ bsum){
  __shared__ int sh[256];
  int i = blockIdx.x * 256 + threadIdx.x;
  int v = cnt[i << 2];
  sh[threadIdx.x] = v; __syncthreads();
  for (int off = 1; off < 256; off <<= 1){
    int t = (threadIdx.x >= off) ? sh[threadIdx.x - off] : 0;
    __syncthreads();
    sh[threadIdx.x] += t;
    __syncthreads();
  }
  int incl = sh[threadIdx.x];
  rowptr[i] = incl - v;
  if (threadIdx.x == 255) bsum[blockIdx.x] = incl;
}

__global__ void k_scan2(int* __restrict__ bsum){
  __shared__ int sh[1024];
  int v = bsum[threadIdx.x];
  sh[threadIdx.x] = v; __syncthreads();
  for (int off = 1; off < 1024; off <<= 1){
    int t = (threadIdx.x >= off) ? sh[threadIdx.x - off] : 0;
    __syncthreads();
    sh[threadIdx.x] += t;
    __syncthreads();
  }
  bsum[threadIdx.x] = sh[threadIdx.x] - v;  // exclusive
}

// ---------------- atomic-free scatter | word-level a0/a1 tables | rowptr finalize ----------------
__global__ void k_scw(const int* __restrict__ u_ei, const int* __restrict__ i_ei,
                      const int* __restrict__ u_et, const int* __restrict__ i_et,
                      const int* __restrict__ rowptr, const int* __restrict__ bsum,
                      const int* __restrict__ loff, int* __restrict__ pedge,
                      int* __restrict__ rowfin,
                      const short* __restrict__ wtab, int nwords, int wgB,
                      const float* __restrict__ waA, const float* __restrict__ ba,
                      float* __restrict__ wa0, float* __restrict__ wa1){
  const int scatB = 2 * NE / 256;
  int blk = blockIdx.x, tid = threadIdx.x;
  if (blk < scatB){
    int ee = blk * 256 + tid;
    int side = ee >= NE;
    int e = ee - side * NE;
    const int* ei = side ? i_ei : u_ei;
    const int* et = side ? i_et : u_et;
    int dst = ei[NE + e] + side * NN;
    int src = ei[e] + side * NN;
    int p = rowptr[dst] + bsum[dst >> 8] + loff[ee];
    pedge[p] = src | (et[e] << 18);
  } else if (blk < scatB + wgB){
    // wa0/wa1[side][word] = wtab[word] . waA(side,l=0,a) + ba
    int lane = tid & 63, w = tid >> 6;
    int q = lane >> 4, cl = lane & 15;
    int sw0 = ((blk - scatB) * 4 + w) * 8;
    const uint2* wt2 = (const uint2*)wtab;
    for (int it = 0; it < 2; it++){
      int wj = sw0 + it * 4 + q;
      if (wj >= 2 * nwords) continue;
      int side = wj >= nwords;
      int wid = wj - side * nwords;
      const float* A0 = waA + (side * 2 + 0) * 2 * 64;
      const float* A1 = A0 + 64;
      uint2 v = wt2[(long)wid * 16 + cl];
      int d = 4 * cl;
      float p0 = ulo2f(v.x) * A0[d] + uhi2f(v.x) * A0[d + 1] +
                 ulo2f(v.y) * A0[d + 2] + uhi2f(v.y) * A0[d + 3];
      float p1 = ulo2f(v.x) * A1[d] + uhi2f(v.x) * A1[d + 1] +
                 ulo2f(v.y) * A1[d + 2] + uhi2f(v.y) * A1[d + 3];
      p0 += __shfl_xor(p0, 1, 64); p0 += __shfl_xor(p0, 2, 64);
      p0 += __shfl_xor(p0, 4, 64); p0 += __shfl_xor(p0, 8, 64);
      p1 += __shfl_xor(p1, 1, 64); p1 += __shfl_xor(p1, 2, 64);
      p1 += __shfl_xor(p1, 4, 64); p1 += __shfl_xor(p1, 8, 64);
      if (cl == 0){
        wa0[(size_t)side * nwords + wid] = p0 + ba[side * 4 + 0];
        wa1[(size_t)side * nwords + wid] = p1 + ba[side * 4 + 1];
      }
    }
  } else {
    // finalize rowptr into a separate array (scatter blocks still read the partial one)
    int i = (blk - scatB - wgB) * 256 + tid;
    rowfin[i] = rowptr[i] + bsum[i >> 8];
    if (i == 0) rowfin[2 * NN] = 2 * NE;
  }
}

// ---------------- aggregation: xagg[dst] = sum_e softmax(e) * x[src_e] (no relu) ----------------
// One node per 16-lane group, 2 nodes per group serially (8 nodes/wave).
// All edge loads statically unrolled (8 predicated steps) so they issue in
// parallel: pedge -> (av, hv) is a 2-deep chain per node, no runtime-bound
// serial dependent loop (round-6 failure), no cross-lane reduction (round-5 cost).
template<int L>
__device__ __forceinline__ void dev_agg(
    const int* __restrict__ rowptr, const int* __restrict__ pedge,
    const float* __restrict__ a0, const float* __restrict__ a1,        // L==1
    const float* __restrict__ wa0, const float* __restrict__ wa1,      // L==0
    const int* __restrict__ u_nodes, const int* __restrict__ i_nodes, int nwords,
    const float* __restrict__ rtab, const short* __restrict__ rows,
    unsigned* __restrict__ xo32){
  int lane = threadIdx.x & 63, w = threadIdx.x >> 6;
  int grp = lane >> 4, cl = lane & 15;
  int nb = (blockIdx.x * 4 + w) * 8;               // 8 nodes per wave
  int side = nb >= NN;                              // NN % 8 == 0: no straddle
  const float* rt = rtab + (side * 2 + L) * 4;
  float rt0 = rt[0], rt1 = rt[1], rt2 = rt[2], rt3 = rt[3];
  const int* nodesS = side ? i_nodes : u_nodes;
  const float* wa0S = wa0 + (size_t)side * nwords;
  const float* wa1S = wa1 + (size_t)side * nwords;
  const uint2* h2 = (const uint2*)rows;

  for (int t = 0; t < 2; t++){
    int n = nb + grp * 2 + t;                      // group's node
    int r0 = rowptr[n], r1 = rowptr[n + 1];        // broadcast loads
    int deg = r1 - r0;
    float a1n;
    if (L == 0) a1n = wa1S[nodesS[n - side * NN]];
    else        a1n = a1[n];

    int pe[8]; int rowv[8]; float av[8]; uint2 hv[8];
#pragma unroll
    for (int j = 0; j < 8; j++)
      pe[j] = (j < deg) ? pedge[r0 + j] : 0;       // 8 independent broadcast loads
#pragma unroll
    for (int j = 0; j < 8; j++){
      int s = pe[j] & 0x3FFFF;
      if (L == 0){
        int wid = 0;
        if (j < deg) wid = nodesS[s - side * NN];
        rowv[j] = wid;
      } else {
        rowv[j] = s;
      }
    }
#pragma unroll
    for (int j = 0; j < 8; j++){
      av[j] = 0.f;
      if (j < deg) av[j] = (L == 0) ? wa0S[rowv[j]] : a0[rowv[j]];
      uint2 z; z.x = 0u; z.y = 0u;
      hv[j] = z;
      if (j < deg) hv[j] = h2[(long)rowv[j] * 16 + cl];  // per-lane feature slice
    }
    float ax0 = 0.f, ay0 = 0.f, ax1 = 0.f, ay1 = 0.f, den = 0.f;
#pragma unroll
    for (int j = 0; j < 8; j++){
      int et = (pe[j] >> 18) & 3;
      float rr = (et & 2) ? ((et & 1) ? rt3 : rt2) : ((et & 1) ? rt1 : rt0);
      float v = av[j] + a1n + rr;
      v = (v > 0.f) ? v : 0.2f * v;
      float ex = (j < deg) ? __expf(v) : 0.f;
      ax0 += ex * ulo2f(hv[j].x); ay0 += ex * uhi2f(hv[j].x);
      ax1 += ex * ulo2f(hv[j].y); ay1 += ex * uhi2f(hv[j].y);
      den += ex;
    }
    // rare tail: deg > 8 (~2% of nodes at Poisson(4))
    for (int e = r0 + 8; e < r1; ++e){
      int pe2 = pedge[e];
      int s = pe2 & 0x3FFFF;
      int et = (pe2 >> 18) & 3;
      float rr = (et & 2) ? ((et & 1) ? rt3 : rt2) : ((et & 1) ? rt1 : rt0);
      float avv; long row;
      if (L == 0){ int wid = nodesS[s - side * NN]; avv = wa0S[wid]; row = wid; }
      else       { avv = a0[s]; row = s; }
      float v = avv + a1n + rr;
      v = (v > 0.f) ? v : 0.2f * v;
      float ex = __expf(v);
      uint2 hvv = h2[row * 16 + cl];
      ax0 += ex * ulo2f(hvv.x); ay0 += ex * uhi2f(hvv.x);
      ax1 += ex * ulo2f(hvv.y); ay1 += ex * uhi2f(hvv.y);
      den += ex;
    }
    float inv = 1.f / (den + 1e-16f);
    uint2 o;
    o.x = fpack(ax0 * inv, ay0 * inv);
    o.y = fpack(ax1 * inv, ay1 * inv);
    ((uint2*)xo32)[(long)n * 16 + cl] = o;         // full 128B row per group
  }
}

__global__ __launch_bounds__(256) void k_agg0(
    const int* __restrict__ rowptr, const int* __restrict__ pedge,
    const float* __restrict__ wa0, const float* __restrict__ wa1,
    const int* __restrict__ u_nodes, const int* __restrict__ i_nodes, int nwords,
    const float* __restrict__ rtab, const short* __restrict__ wtab,
    unsigned* __restrict__ xo32){
  dev_agg<0>(rowptr, pedge, nullptr, nullptr, wa0, wa1, u_nodes, i_nodes, nwords,
             rtab, wtab, xo32);
}

__global__ __launch_bounds__(256) void k_agg1(
    const int* __restrict__ rowptr, const int* __restrict__ pedge,
    const float* __restrict__ a0, const float* __restrict__ a1,
    const float* __restrict__ rtab, const short* __restrict__ x,
    unsigned* __restrict__ xo32){
  dev_agg<1>(rowptr, pedge, a0, a1, nullptr, nullptr, nullptr, nullptr, 0,
             rtab, x, xo32);
}

// ---------------- fused post: x=relu(xagg@W+b); gates; gmp; trans_w; gated X1 + a0/a1 ----------------
__global__ __launch_bounds__(256) void k_gp(
    int l, const short* __restrict__ xagg, const short8* __restrict__ frag,
    const float* __restrict__ cub, const float* __restrict__ cib,
    const float* __restrict__ waA_all, const float* __restrict__ ba_all,
    const float* __restrict__ qbuf, const float* __restrict__ twW_all,
    const float* __restrict__ twb_all, float* __restrict__ xfm,
    short* __restrict__ xnext, float* __restrict__ a0, float* __restrict__ a1){
  __shared__ short xt[128 * 72];       // padded rows (72 shorts) for bank spread
  __shared__ float gates[128];
  __shared__ float red[4][64];
  int b = blockIdx.x;                  // [0, 2NB)
  int side = b >= NB;
  int g = b - side * NB;
  long base = (long)side * NN + (long)g * 128;
  int tid = threadIdx.x, lane = tid & 63, w = tid >> 6;
  int m = lane & 15, q = lane >> 4;
  // stage A: conv GEMM
  const short8* wfrag = frag + (side * 2 + l) * 512;
  const float* bias = (side ? cib : cub) + l * 64;
  short8 Bf[4][2];
#pragma unroll
  for (int t = 0; t < 4; t++)
#pragma unroll
    for (int hh = 0; hh < 2; hh++)
      Bf[t][hh] = wfrag[(t * 2 + hh) * 64 + lane];
  float bs[4];
#pragma unroll
  for (int t = 0; t < 4; t++) bs[t] = bias[t * 16 + m];
  f32x4 accA[2][4];
#pragma unroll
  for (int rb = 0; rb < 2; rb++){
    long n0 = base + w * 32 + rb * 16;
    const short8* xr = (const short8*)(xagg + (n0 + m) * 64);
    short8 A0 = xr[q];
    short8 A1 = xr[q + 4];
#pragma unroll
    for (int t = 0; t < 4; t++){
      f32x4 acc = (f32x4){bs[t], bs[t], bs[t], bs[t]};
      acc = __builtin_amdgcn_mfma_f32_16x16x32_bf16(A0, Bf[t][0], acc, 0, 0, 0);
      acc = __builtin_amdgcn_mfma_f32_16x16x32_bf16(A1, Bf[t][1], acc, 0, 0, 0);
#pragma unroll
      for (int r = 0; r < 4; r++) acc[r] = fmaxf(acc[r], 0.f);
      accA[rb][t] = acc;
#pragma unroll
      for (int r = 0; r < 4; r++)
        xt[(w * 32 + rb * 16 + q * 4 + r) * 72 + t * 16 + m] = f2bs(acc[r]);
    }
  }
  __syncthreads();
  // stage B: pool GEMM from LDS -> gates
  const short8* pfrag = frag + 4 * 512;
  const float* qv_ = qbuf + ((size_t)(side * 2 + l) * NB + g) * 64;
  short8 Pf[4][2];
#pragma unroll
  for (int t = 0; t < 4; t++)
#pragma unroll
    for (int hh = 0; hh < 2; hh++)
      Pf[t][hh] = pfrag[(t * 2 + hh) * 64 + lane];
  float qv[4];
#pragma unroll
  for (int t = 0; t < 4; t++) qv[t] = qv_[t * 16 + m];
#pragma unroll
  for (int rb = 0; rb < 2; rb++){
    int rowb = w * 32 + rb * 16;
    short8 A0 = *(const short8*)(xt + (rowb + m) * 72 + q * 8);
    short8 A1 = *(const short8*)(xt + (rowb + m) * 72 + 32 + q * 8);
    f32x4 accp[4];
#pragma unroll
    for (int t = 0; t < 4; t++){
      accp[t] = (f32x4){0.f, 0.f, 0.f, 0.f};
      accp[t] = __builtin_amdgcn_mfma_f32_16x16x32_bf16(A0, Pf[t][0], accp[t], 0, 0, 0);
      accp[t] = __builtin_amdgcn_mfma_f32_16x16x32_bf16(A1, Pf[t][1], accp[t], 0, 0, 0);
    }
#pragma unroll
    for (int r = 0; r < 4; r++){
      float p = accp[0][r] * qv[0] + accp[1][r] * qv[1] +
                accp[2][r] * qv[2] + accp[3][r] * qv[3];
      p += __shfl_xor(p, 1, 64); p += __shfl_xor(p, 2, 64);
      p += __shfl_xor(p, 4, 64); p += __shfl_xor(p, 8, 64);
      if (m == 0)
        gates[rowb + q * 4 + r] = 1.f / (1.f + __expf(-p * 0.125f));
    }
  }
  __syncthreads();
  // gated max pool
  const unsigned* xt32 = (const unsigned*)xt;
  int c = lane & 31, half = lane >> 5;
  float mxx = 0.f, mxy = 0.f;
#pragma unroll
  for (int p = 0; p < 16; p++){
    int nn = w * 32 + 2 * p + half;
    unsigned v = xt32[nn * 36 + c];
    float gt = gates[nn];
    mxx = fmaxf(mxx, ulo2f(v) * gt);
    mxy = fmaxf(mxy, uhi2f(v) * gt);
  }
  mxx = fmaxf(mxx, __shfl_xor(mxx, 32, 64));
  mxy = fmaxf(mxy, __shfl_xor(mxy, 32, 64));
  if (half == 0){ red[w][2 * c] = mxx; red[w][2 * c + 1] = mxy; }
  __syncthreads();
  if (tid < 64){
    const float* twW = twW_all + l * 4096;
    const float* twb = twb_all + l * 64;
    int off = (side ? 256 : 64) + l * 64;
    float p = fmaxf(fmaxf(red[0][tid], red[1][tid]), fmaxf(red[2][tid], red[3][tid]));
    float o = twb[tid];
    red[0][tid] = p;
    __syncwarp();
    for (int d = 0; d < 64; d++) o += red[0][d] * twW[d * 64 + tid];
    xfm[g * 384 + off + tid] = fmaxf(o, 0.f);
  }
  if (l == 0){
    // gated next-layer input write (coalesced via LDS)
#pragma unroll
    for (int p = 0; p < 4; p++){
      int row = p * 32 + (tid >> 3);
      int col8 = (tid & 7) * 8;
      float gt = gates[row];
      short8 v = *(const short8*)(xt + row * 72 + col8);
      short8 o;
#pragma unroll
      for (int j = 0; j < 8; j++) o[j] = f2bs(bs2f(v[j]) * gt);
      *(short8*)(xnext + (base + row) * 64 + col8) = o;
    }
    // next-layer a0/a1 from gated x_next: a = g*(x.waA1) + ba1
    const float* wn0p = waA_all + ((side * 2 + 1) * 2 + 0) * 64;
    const float* wn1p = wn0p + 64;
    float wn0[4], wn1[4];
#pragma unroll
    for (int t = 0; t < 4; t++){ wn0[t] = wn0p[t * 16 + m]; wn1[t] = wn1p[t * 16 + m]; }
    float ban0 = ba_all[(side * 2 + 1) * 2 + 0];
    float ban1 = ba_all[(side * 2 + 1) * 2 + 1];
#pragma unroll
    for (int rb = 0; rb < 2; rb++)
#pragma unroll
      for (int r = 0; r < 4; r++){
        float p0 = accA[rb][0][r] * wn0[0] + accA[rb][1][r] * wn0[1] +
                   accA[rb][2][r] * wn0[2] + accA[rb][3][r] * wn0[3];
        float p1 = accA[rb][0][r] * wn1[0] + accA[rb][1][r] * wn1[1] +
                   accA[rb][2][r] * wn1[2] + accA[rb][3][r] * wn1[3];
        p0 += __shfl_xor(p0, 1, 64); p0 += __shfl_xor(p0, 2, 64);
        p0 += __shfl_xor(p0, 4, 64); p0 += __shfl_xor(p0, 8, 64);
        p1 += __shfl_xor(p1, 1, 64); p1 += __shfl_xor(p1, 2, 64);
        p1 += __shfl_xor(p1, 4, 64); p1 += __shfl_xor(p1, 8, 64);
        if (m == 0){
          int row = w * 32 + rb * 16 + q * 4 + r;
          float gr = gates[row];
          a0[base + row] = p0 * gr + ban0;
          a1[base + row] = p1 * gr + ban1;
        }
      }
  }
}

// ---------------- FM head: 4 graphs per block, V streamed once per block ----------------
__global__ __launch_bounds__(384) void k_fm(
    const float* __restrict__ xfm, const float* __restrict__ V,
    const float* __restrict__ fw, const float* __restrict__ bu,
    const float* __restrict__ bi, const float* __restrict__ b0,
    const int* __restrict__ uid, const int* __restrict__ iid,
    float* __restrict__ out){
  __shared__ float xsh[4][384];
  __shared__ float xsq[4][384];
  __shared__ float part[4][384];
  int j = threadIdx.x;
  int g0 = blockIdx.x * 4;
#pragma unroll
  for (int b = 0; b < 4; b++){
    float xv_ = xfm[(g0 + b) * 384 + j];
    xsh[b][j] = xv_;
    xsq[b][j] = xv_ * xv_;
  }
  __syncthreads();
  float xv[4] = {0.f, 0.f, 0.f, 0.f};
  float vv[4] = {0.f, 0.f, 0.f, 0.f};
  for (int k = 0; k < 384; k++){
    float v = V[(size_t)k * 384 + j];
    float v2 = v * v;
#pragma unroll
    for (int b = 0; b < 4; b++){
      xv[b] = fmaf(xsh[b][k], v, xv[b]);
      vv[b] = fmaf(xsq[b][k], v2, vv[b]);
    }
  }
  float fwj = fw[j];
#pragma unroll
  for (int b = 0; b < 4; b++)
    part[b][j] = 0.5f * (xv[b] * xv[b] - vv[b]) + xsh[b][j] * fwj;
  __syncthreads();
  int w = j >> 6, lane = j & 63;
  if (w < 4){
    float s = part[w][lane] + part[w][lane + 64] + part[w][lane + 128] +
              part[w][lane + 192] + part[w][lane + 256] + part[w][lane + 320];
    s = wsum(s);
    if (lane == 0){
      int b = g0 + w;
      out[b] = s + bu[uid[b]] + bi[iid[b]] + b0[0];
    }
  }
}

extern "C" void kernel_launch(void* const* d_in, const int* in_sizes, int n_in,
                              void* d_out, int out_size, void* d_ws, size_t ws_size,
                              hipStream_t stream) {
  const int* uid      = (const int*)d_in[0];
  const int* iid      = (const int*)d_in[1];
  const int* u_nodes  = (const int*)d_in[2];
  const int* i_nodes  = (const int*)d_in[3];
  const int* u_ei     = (const int*)d_in[4];
  const int* i_ei     = (const int*)d_in[5];
  const int* u_et     = (const int*)d_in[6];
  const int* i_et     = (const int*)d_in[7];
  const float* user_emb = (const float*)d_in[10];
  const float* item_emb = (const float*)d_in[11];
  const float* word_emb = (const float*)d_in[12];
  const float* trans_u_W = (const float*)d_in[13];
  const float* trans_u_b = (const float*)d_in[14];
  const float* trans_i_W = (const float*)d_in[15];
  const float* trans_i_b = (const float*)d_in[16];
  const float* trans_w_W = (const float*)d_in[17];
  const float* trans_w_b = (const float*)d_in[18];
  const float* inter_u_W = (const float*)d_in[19];
  const float* inter_u_b = (const float*)d_in[20];
  const float* inter_i_W = (const float*)d_in[21];
  const float* inter_i_b = (const float*)d_in[22];
  const float* conv_u_W  = (const float*)d_in[23];
  const float* conv_u_b  = (const float*)d_in[24];
  const float* conv_u_att= (const float*)d_in[25];
  const float* conv_u_rel= (const float*)d_in[26];
  const float* conv_i_W  = (const float*)d_in[27];
  const float* conv_i_b  = (const float*)d_in[28];
  const float* conv_i_att= (const float*)d_in[29];
  const float* conv_i_rel= (const float*)d_in[30];
  const float* pool_W    = (const float*)d_in[31];
  const float* fm_w      = (const float*)d_in[32];
  const float* fm_V      = (const float*)d_in[33];
  const float* fm_bias_u = (const float*)d_in[34];
  const float* fm_bias_i = (const float*)d_in[35];
  const float* fm_bias   = (const float*)d_in[36];
  float* out = (float*)d_out;
  int n32 = in_sizes[12] / 2;          // packed uints in word table
  int nwords = in_sizes[12] / 64;      // words (HID=64)
  int wconvB = (n32 + 255) / 256;

  // workspace carve-up (cnt aliases X1; loff aliases X0 — both dead before X0/X1 are written)
  char* w = (char*)d_ws;
  short* X0   = (short*)w;          w += (size_t)2 * NN * 64 * 2;   // 32 MB
  short* X1   = (short*)w;          w += (size_t)2 * NN * 64 * 2;   // 32 MB
  short* wtab = (short*)w;          w += (size_t)in_sizes[12] * 2;  // bf16 word table
  int* pedge  = (int*)w;            w += (size_t)2 * NE * 4;
  float* a0   = (float*)w;          w += (size_t)2 * NN * 4;
  float* a1   = (float*)w;          w += (size_t)2 * NN * 4;
  float* wa0  = (float*)w;          w += (size_t)2 * nwords * 4;
  float* wa1  = (float*)w;          w += (size_t)2 * nwords * 4;
  int* rowptr = (int*)w;            w += (size_t)2 * NN * 4;        // partial (block-local scan)
  int* rowfin = (int*)w;            w += (size_t)(2 * NN + 256) * 4;
  int* bsum   = (int*)w;            w += 1024 * 4;
  short8* frag = (short8*)w;        w += (size_t)5 * 512 * 16;
  float* waA  = (float*)w;          w += 2 * 2 * 2 * 64 * 4;
  float* ba   = (float*)w;          w += 64;
  float* rtab = (float*)w;          w += 64;
  float* qbuf = (float*)w;          w += (size_t)4 * NB * 64 * 4;
  float* xfm  = (float*)w;          w += (size_t)NB * 384 * 4;
  int* cnt  = (int*)X1;             // 2*NN*16 B = 4 MB, dead before k_gp<0> writes X1
  int* loff = (int*)X0;             // 2*NE*4 B = 4 MB, dead before k_agg0 writes X0

  hipMemsetAsync(cnt, 0, (size_t)2 * NN * 16, stream);

  int histB = 2 * NE / 256;
  int megaB = histB + 12 + wconvB + 2 * NB / 4;
  k_mega<<<megaB, 256, 0, stream>>>(wconvB, u_ei, i_ei, cnt, loff,
                                    word_emb, (unsigned*)wtab, n32,
                                    conv_u_W, conv_i_W, pool_W, conv_u_b, conv_i_b,
                                    conv_u_att, conv_i_att, conv_u_rel, conv_i_rel,
                                    frag, waA, ba, rtab,
                                    uid, iid, user_emb, item_emb,
                                    inter_u_W, inter_u_b, inter_i_W, inter_i_b,
                                    trans_u_W, trans_u_b, trans_i_W, trans_i_b,
                                    xfm, qbuf);
  k_scan1<<<2 * NN / 256, 256, 0, stream>>>(cnt, rowptr, bsum);
  k_scan2<<<1, 1024, 0, stream>>>(bsum);
  int wgB = (2 * nwords + 31) / 32;
  int scatB = 2 * NE / 256;
  int finB = 2 * NN / 256;
  k_scw<<<scatB + wgB + finB, 256, 0, stream>>>(u_ei, i_ei, u_et, i_et,
                                                rowptr, bsum, loff, pedge, rowfin,
                                                wtab, nwords, wgB, waA, ba, wa0, wa1);

  // layer 0: aggregate straight from the word table
  k_agg0<<<2 * NN / 32, 256, 0, stream>>>(rowfin, pedge, wa0, wa1,
                                          u_nodes, i_nodes, nwords, rtab,
                                          wtab, (unsigned*)X0);
  k_gp  <<<2 * NB, 256, 0, stream>>>(0, X0, frag, conv_u_b, conv_i_b, waA, ba,
                                     qbuf, trans_w_W, trans_w_b, xfm, X1, a0, a1);
  // layer 1
  k_agg1<<<2 * NN / 32, 256, 0, stream>>>(rowfin, pedge, a0, a1, rtab,
                                          X1, (unsigned*)X0);
  k_gp  <<<2 * NB, 256, 0, stream>>>(1, X0, frag, conv_u_b, conv_i_b, waA, ba,
                                     qbuf, trans_w_W, trans_w_b, xfm,
                                     nullptr, nullptr, nullptr);

  k_fm<<<NB / 4, 384, 0, stream>>>(xfm, fm_V, fm_w, fm_bias_u, fm_bias_i, fm_bias,
                                   uid, iid, out);
}

// Round 8
// 374.577 us; speedup vs baseline: 1.1712x; 1.1063x over previous
//
#include <hip/hip_runtime.h>
#include <hip/hip_bf16.h>

#define NN 131072   // nodes per side
#define NE 524288   // edges per side
#define NB 1024     // batch (graphs per side)
#define NBKT 512    // dst buckets (512-node ranges); 2NN/NBKT = 512 nodes/bucket
#define K1B 512     // edge-chunk blocks; CHUNK = 2NE/K1B = 2048 edges (8/thread)

typedef __attribute__((ext_vector_type(8))) short short8;   // 8 bf16
typedef __attribute__((ext_vector_type(4))) float f32x4;

__device__ __forceinline__ float wsum(float v){
#pragma unroll
  for (int o = 32; o > 0; o >>= 1) v += __shfl_xor(v, o, 64);
  return v;
}
__device__ __forceinline__ short f2bs(float f){
  __hip_bfloat16 t = __float2bfloat16(f);
  union { __hip_bfloat16 b; short s; } u; u.b = t; return u.s;
}
__device__ __forceinline__ float bs2f(short s){
  return __uint_as_float(((unsigned)(unsigned short)s) << 16);
}
__device__ __forceinline__ float ulo2f(unsigned v){ return __uint_as_float(v << 16); }
__device__ __forceinline__ float uhi2f(unsigned v){ return __uint_as_float(v & 0xFFFF0000u); }
__device__ __forceinline__ unsigned fpack(float x, float y){
  return (unsigned)(unsigned short)f2bs(x) | ((unsigned)(unsigned short)f2bs(y) << 16);
}

// ---------------- mega: K1 bucket-count (LDS hist, no global atomics) | frag | waA/ba/rtab | wconv | prep ----------------
__global__ void k_mega(int wconvB,
                       const int* __restrict__ u_ei, const int* __restrict__ i_ei,
                       int* __restrict__ cntmat,
                       const float* __restrict__ wemb, unsigned* __restrict__ wtab,
                       int n32,
                       const float* __restrict__ cuW, const float* __restrict__ ciW,
                       const float* __restrict__ pW,
                       const float* __restrict__ cub, const float* __restrict__ cib,
                       const float* __restrict__ uatt, const float* __restrict__ iatt,
                       const float* __restrict__ urel, const float* __restrict__ irel,
                       short8* __restrict__ frag, float* __restrict__ waA,
                       float* __restrict__ ba, float* __restrict__ rtab,
                       const int* __restrict__ uid, const int* __restrict__ iid,
                       const float* __restrict__ uemb, const float* __restrict__ iemb,
                       const float* __restrict__ uiW, const float* __restrict__ uib,
                       const float* __restrict__ iiW, const float* __restrict__ iib,
                       const float* __restrict__ utW, const float* __restrict__ utb,
                       const float* __restrict__ itW, const float* __restrict__ itb,
                       float* __restrict__ xfm, float* __restrict__ q){
  int blk = blockIdx.x, tid = threadIdx.x;
  if (blk < K1B){
    // per-chunk bucket histogram in LDS; write matrix row (no global atomics)
    __shared__ int hist[NBKT];
    hist[tid] = 0; hist[tid + 256] = 0;
    __syncthreads();
#pragma unroll
    for (int k = 0; k < 8; k++){
      int ee = blk * 2048 + k * 256 + tid;
      int side = ee >= NE;
      int e = ee - side * NE;
      const int* ei = side ? i_ei : u_ei;
      int dst = ei[NE + e] + side * NN;
      atomicAdd(&hist[dst >> 9], 1);
    }
    __syncthreads();
    cntmat[blk * NBKT + tid] = hist[tid];
    cntmat[blk * NBKT + tid + 256] = hist[tid + 256];
  } else if (blk < K1B + 10){
    int b2 = blk - K1B;
    int mat = b2 >> 1;
    const float* W = mat < 2 ? cuW + mat * 4096 : (mat < 4 ? ciW + (mat - 2) * 4096 : pW);
    int g = (b2 & 1) * 256 + tid;     // [0,512)
    int lane = g & 63, rest = g >> 6;
    int hh = rest & 1, t = rest >> 1;
    int m = lane & 15, qq = lane >> 4;
    short8 v;
#pragma unroll
    for (int j = 0; j < 8; j++)
      v[j] = f2bs(W[(hh * 32 + qq * 8 + j) * 64 + (t * 16 + m)]);
    frag[mat * 512 + g] = v;
  } else if (blk < K1B + 12){
    int side = blk - K1B - 10;
    const float* W    = side ? ciW : cuW;
    const float* bias = side ? cib : cub;
    const float* att  = side ? iatt : uatt;
    const float* rel  = side ? irel : urel;
    int l = tid >> 7, a = (tid >> 6) & 1, kk = tid & 63;
    float s = 0.f;
    for (int c = 0; c < 64; c++) s += W[l * 4096 + kk * 64 + c] * att[l * 192 + a * 64 + c];
    waA[((side * 2 + l) * 2 + a) * 64 + kk] = s;
    if (tid < 4){
      int l2 = tid >> 1, a2 = tid & 1;
      float sb = 0.f;
      for (int c = 0; c < 64; c++) sb += bias[l2 * 64 + c] * att[l2 * 192 + a2 * 64 + c];
      ba[(side * 2 + l2) * 2 + a2] = sb;
    }
    if (tid >= 4 && tid < 12){
      int id = tid - 4, l2 = id >> 2, tt = id & 3;
      float sr = 0.f;
      for (int c = 0; c < 64; c++) sr += rel[l2 * 256 + tt * 64 + c] * att[l2 * 192 + 128 + c];
      rtab[(side * 2 + l2) * 4 + tt] = sr;
    }
  } else if (blk < K1B + 12 + wconvB){
    int id = (blk - K1B - 12) * 256 + tid;
    if (id < n32){
      const float2* src = (const float2*)wemb;
      float2 v = src[id];
      wtab[id] = fpack(v.x, v.y);
    }
  } else {
    int lane = tid & 63, w = tid >> 6;
    int b = (blk - K1B - 12 - wconvB) * 4 + w;   // [0, 2NB)
    int side = b >= NB;
    int lb = b - side * NB;
    const int* ids = side ? iid : uid;
    const float* emb = side ? iemb : uemb;
    const float* interW = side ? iiW : uiW;
    const float* interB = side ? iib : uib;
    const float* transW = side ? itW : utW;
    const float* transB = side ? itb : utb;
    int repOff = side ? 192 : 0;
    float xe = emb[(long)ids[lb] * 64 + lane];
    float o = interB[lane];
#pragma unroll
    for (int k = 0; k < 64; k++) o += __shfl(xe, k, 64) * interW[k * 64 + lane];
    xfm[lb * 384 + repOff + lane] = fmaxf(o, 0.f);
    for (int l = 0; l < 2; l++){
      float t = transB[l * 64 + lane];
#pragma unroll
      for (int k = 0; k < 64; k++) t += __shfl(xe, k, 64) * transW[l * 4096 + k * 64 + lane];
      q[((size_t)(side * 2 + l) * NB + lb) * 64 + lane] = fmaxf(t, 0.f);
    }
  }
}

// column-exclusive-prefix of cntmat (per bucket over chunks) + bucket totals
__global__ void k_colscan(int* __restrict__ cntmat, int* __restrict__ btot){
  __shared__ int sh[256];
  int b = blockIdx.x, t = threadIdx.x;
  int c0 = cntmat[(2 * t) * NBKT + b];
  int c1 = cntmat[(2 * t + 1) * NBKT + b];
  int s = c0 + c1;
  sh[t] = s; __syncthreads();
  for (int off = 1; off < 256; off <<= 1){
    int v = (t >= off) ? sh[t - off] : 0;
    __syncthreads();
    sh[t] += v;
    __syncthreads();
  }
  int incl = sh[t];
  int excl = incl - s;
  cntmat[(2 * t) * NBKT + b] = excl;
  cntmat[(2 * t + 1) * NBKT + b] = excl + c0;
  if (t == 255) btot[b] = incl;
}

// exclusive scan of bucket totals -> bucket bases (+sentinel)
__global__ void k_bscan(const int* __restrict__ btot, int* __restrict__ bbase){
  __shared__ int sh[NBKT];
  int t = threadIdx.x;
  int v = btot[t];
  sh[t] = v; __syncthreads();
  for (int off = 1; off < NBKT; off <<= 1){
    int x = (t >= off) ? sh[t - off] : 0;
    __syncthreads();
    sh[t] += x;
    __syncthreads();
  }
  bbase[t] = sh[t] - v;
  if (t == NBKT - 1) bbase[NBKT] = 2 * NE;
}

// ---------------- scatter edges into bucket runs (LDS slots, no global atomics) | wa tables ----------------
__global__ void k_scat(const int* __restrict__ u_ei, const int* __restrict__ i_ei,
                       const int* __restrict__ u_et, const int* __restrict__ i_et,
                       const int* __restrict__ cntmat, const int* __restrict__ bbase,
                       int* __restrict__ ebuf,
                       const short* __restrict__ wtab, int nwords,
                       const float* __restrict__ waA, const float* __restrict__ ba,
                       float* __restrict__ wa0, float* __restrict__ wa1){
  int blk = blockIdx.x, tid = threadIdx.x;
  if (blk < K1B){
    __shared__ int hist[NBKT];
    __shared__ int mb[NBKT];
    hist[tid] = 0; hist[tid + 256] = 0;
    mb[tid]       = cntmat[blk * NBKT + tid]       + bbase[tid];
    mb[tid + 256] = cntmat[blk * NBKT + tid + 256] + bbase[tid + 256];
    __syncthreads();
#pragma unroll
    for (int k = 0; k < 8; k++){
      int ee = blk * 2048 + k * 256 + tid;
      int side = ee >= NE;
      int e = ee - side * NE;
      const int* ei = side ? i_ei : u_ei;
      const int* et = side ? i_et : u_et;
      int dst = ei[NE + e] + side * NN;
      int src = ei[e] + side * NN;
      int bin = dst >> 9;
      int slot = atomicAdd(&hist[bin], 1);
      ebuf[mb[bin] + slot] = src | (et[e] << 18) | ((dst & 511) << 20);
    }
  } else {
    // wa0/wa1[side][word] = wtab[word] . waA(side,l=0,a) + ba
    int lane = tid & 63, w = tid >> 6;
    int q = lane >> 4, cl = lane & 15;
    int sw0 = ((blk - K1B) * 4 + w) * 8;
    const uint2* wt2 = (const uint2*)wtab;
    for (int it = 0; it < 2; it++){
      int wj = sw0 + it * 4 + q;
      if (wj >= 2 * nwords) continue;
      int side = wj >= nwords;
      int wid = wj - side * nwords;
      const float* A0 = waA + (side * 2 + 0) * 2 * 64;
      const float* A1 = A0 + 64;
      uint2 v = wt2[(long)wid * 16 + cl];
      int d = 4 * cl;
      float p0 = ulo2f(v.x) * A0[d] + uhi2f(v.x) * A0[d + 1] +
                 ulo2f(v.y) * A0[d + 2] + uhi2f(v.y) * A0[d + 3];
      float p1 = ulo2f(v.x) * A1[d] + uhi2f(v.x) * A1[d + 1] +
                 ulo2f(v.y) * A1[d + 2] + uhi2f(v.y) * A1[d + 3];
      p0 += __shfl_xor(p0, 1, 64); p0 += __shfl_xor(p0, 2, 64);
      p0 += __shfl_xor(p0, 4, 64); p0 += __shfl_xor(p0, 8, 64);
      p1 += __shfl_xor(p1, 1, 64); p1 += __shfl_xor(p1, 2, 64);
      p1 += __shfl_xor(p1, 4, 64); p1 += __shfl_xor(p1, 8, 64);
      if (cl == 0){
        wa0[(size_t)side * nwords + wid] = p0 + ba[side * 4 + 0];
        wa1[(size_t)side * nwords + wid] = p1 + ba[side * 4 + 1];
      }
    }
  }
}

// ---------------- per-bucket CSR finalize: counts -> local scan -> rowfin + dst-grouped pedge ----------------
__global__ __launch_bounds__(256) void k_csr(
    const int* __restrict__ bbase, const int* __restrict__ ebuf,
    int* __restrict__ rowfin, int* __restrict__ pedge){
  __shared__ int hist[NBKT];   // 512 node-bins for this bucket; later reused as cursor
  __shared__ int sh[256];
  int b = blockIdx.x, t = threadIdx.x;
  int eb0 = bbase[b], eb1 = bbase[b + 1];
  hist[t] = 0; hist[t + 256] = 0;
  __syncthreads();
  for (int e = eb0 + t; e < eb1; e += 256)
    atomicAdd(&hist[(ebuf[e] >> 20) & 511], 1);
  __syncthreads();
  int c0 = hist[2 * t], c1 = hist[2 * t + 1];
  int s = c0 + c1;
  sh[t] = s; __syncthreads();
  for (int off = 1; off < 256; off <<= 1){
    int v = (t >= off) ? sh[t - off] : 0;
    __syncthreads();
    sh[t] += v;
    __syncthreads();
  }
  int excl = sh[t] - s;
  int nbase = b * 512;
  rowfin[nbase + 2 * t] = eb0 + excl;
  rowfin[nbase + 2 * t + 1] = eb0 + excl + c0;
  hist[2 * t] = excl;            // cursor init (own bins; all reads done above)
  hist[2 * t + 1] = excl + c0;
  __syncthreads();
  for (int e = eb0 + t; e < eb1; e += 256){
    int rec = ebuf[e];
    int bin = (rec >> 20) & 511;
    int p = atomicAdd(&hist[bin], 1);
    pedge[eb0 + p] = rec & 0xFFFFF;   // src | et<<18
  }
  if (b == NBKT - 1 && t == 0) rowfin[2 * NN] = 2 * NE;
}

// ---------------- aggregation (round-7 winner, unchanged) ----------------
template<int L>
__device__ __forceinline__ void dev_agg(
    const int* __restrict__ rowptr, const int* __restrict__ pedge,
    const float* __restrict__ a0, const float* __restrict__ a1,        // L==1
    const float* __restrict__ wa0, const float* __restrict__ wa1,      // L==0
    const int* __restrict__ u_nodes, const int* __restrict__ i_nodes, int nwords,
    const float* __restrict__ rtab, const short* __restrict__ rows,
    unsigned* __restrict__ xo32){
  int lane = threadIdx.x & 63, w = threadIdx.x >> 6;
  int grp = lane >> 4, cl = lane & 15;
  int nb = (blockIdx.x * 4 + w) * 8;               // 8 nodes per wave
  int side = nb >= NN;                              // NN % 8 == 0: no straddle
  const float* rt = rtab + (side * 2 + L) * 4;
  float rt0 = rt[0], rt1 = rt[1], rt2 = rt[2], rt3 = rt[3];
  const int* nodesS = side ? i_nodes : u_nodes;
  const float* wa0S = wa0 + (size_t)side * nwords;
  const float* wa1S = wa1 + (size_t)side * nwords;
  const uint2* h2 = (const uint2*)rows;

  for (int t = 0; t < 2; t++){
    int n = nb + grp * 2 + t;                      // group's node
    int r0 = rowptr[n], r1 = rowptr[n + 1];        // broadcast loads
    int deg = r1 - r0;
    float a1n;
    if (L == 0) a1n = wa1S[nodesS[n - side * NN]];
    else        a1n = a1[n];

    int pe[8]; int rowv[8]; float av[8]; uint2 hv[8];
#pragma unroll
    for (int j = 0; j < 8; j++)
      pe[j] = (j < deg) ? pedge[r0 + j] : 0;       // 8 independent broadcast loads
#pragma unroll
    for (int j = 0; j < 8; j++){
      int s = pe[j] & 0x3FFFF;
      if (L == 0){
        int wid = 0;
        if (j < deg) wid = nodesS[s - side * NN];
        rowv[j] = wid;
      } else {
        rowv[j] = s;
      }
    }
#pragma unroll
    for (int j = 0; j < 8; j++){
      av[j] = 0.f;
      if (j < deg) av[j] = (L == 0) ? wa0S[rowv[j]] : a0[rowv[j]];
      uint2 z; z.x = 0u; z.y = 0u;
      hv[j] = z;
      if (j < deg) hv[j] = h2[(long)rowv[j] * 16 + cl];  // per-lane feature slice
    }
    float ax0 = 0.f, ay0 = 0.f, ax1 = 0.f, ay1 = 0.f, den = 0.f;
#pragma unroll
    for (int j = 0; j < 8; j++){
      int et = (pe[j] >> 18) & 3;
      float rr = (et & 2) ? ((et & 1) ? rt3 : rt2) : ((et & 1) ? rt1 : rt0);
      float v = av[j] + a1n + rr;
      v = (v > 0.f) ? v : 0.2f * v;
      float ex = (j < deg) ? __expf(v) : 0.f;
      ax0 += ex * ulo2f(hv[j].x); ay0 += ex * uhi2f(hv[j].x);
      ax1 += ex * ulo2f(hv[j].y); ay1 += ex * uhi2f(hv[j].y);
      den += ex;
    }
    // rare tail: deg > 8 (~2% of nodes at Poisson(4))
    for (int e = r0 + 8; e < r1; ++e){
      int pe2 = pedge[e];
      int s = pe2 & 0x3FFFF;
      int et = (pe2 >> 18) & 3;
      float rr = (et & 2) ? ((et & 1) ? rt3 : rt2) : ((et & 1) ? rt1 : rt0);
      float avv; long row;
      if (L == 0){ int wid = nodesS[s - side * NN]; avv = wa0S[wid]; row = wid; }
      else       { avv = a0[s]; row = s; }
      float v = avv + a1n + rr;
      v = (v > 0.f) ? v : 0.2f * v;
      float ex = __expf(v);
      uint2 hvv = h2[row * 16 + cl];
      ax0 += ex * ulo2f(hvv.x); ay0 += ex * uhi2f(hvv.x);
      ax1 += ex * ulo2f(hvv.y); ay1 += ex * uhi2f(hvv.y);
      den += ex;
    }
    float inv = 1.f / (den + 1e-16f);
    uint2 o;
    o.x = fpack(ax0 * inv, ay0 * inv);
    o.y = fpack(ax1 * inv, ay1 * inv);
    ((uint2*)xo32)[(long)n * 16 + cl] = o;         // full 128B row per group
  }
}

__global__ __launch_bounds__(256) void k_agg0(
    const int* __restrict__ rowptr, const int* __restrict__ pedge,
    const float* __restrict__ wa0, const float* __restrict__ wa1,
    const int* __restrict__ u_nodes, const int* __restrict__ i_nodes, int nwords,
    const float* __restrict__ rtab, const short* __restrict__ wtab,
    unsigned* __restrict__ xo32){
  dev_agg<0>(rowptr, pedge, nullptr, nullptr, wa0, wa1, u_nodes, i_nodes, nwords,
             rtab, wtab, xo32);
}

__global__ __launch_bounds__(256) void k_agg1(
    const int* __restrict__ rowptr, const int* __restrict__ pedge,
    const float* __restrict__ a0, const float* __restrict__ a1,
    const float* __restrict__ rtab, const short* __restrict__ x,
    unsigned* __restrict__ xo32){
  dev_agg<1>(rowptr, pedge, a0, a1, nullptr, nullptr, nullptr, nullptr, 0,
             rtab, x, xo32);
}

// ---------------- fused post: x=relu(xagg@W+b); gates; gmp; trans_w; gated X1 + a0/a1 ----------------
__global__ __launch_bounds__(256) void k_gp(
    int l, const short* __restrict__ xagg, const short8* __restrict__ frag,
    const float* __restrict__ cub, const float* __restrict__ cib,
    const float* __restrict__ waA_all, const float* __restrict__ ba_all,
    const float* __restrict__ qbuf, const float* __restrict__ twW_all,
    const float* __restrict__ twb_all, float* __restrict__ xfm,
    short* __restrict__ xnext, float* __restrict__ a0, float* __restrict__ a1){
  __shared__ short xt[128 * 72];       // padded rows (72 shorts) for bank spread
  __shared__ float gates[128];
  __shared__ float red[4][64];
  int b = blockIdx.x;                  // [0, 2NB)
  int side = b >= NB;
  int g = b - side * NB;
  long base = (long)side * NN + (long)g * 128;
  int tid = threadIdx.x, lane = tid & 63, w = tid >> 6;
  int m = lane & 15, q = lane >> 4;
  // stage A: conv GEMM
  const short8* wfrag = frag + (side * 2 + l) * 512;
  const float* bias = (side ? cib : cub) + l * 64;
  short8 Bf[4][2];
#pragma unroll
  for (int t = 0; t < 4; t++)
#pragma unroll
    for (int hh = 0; hh < 2; hh++)
      Bf[t][hh] = wfrag[(t * 2 + hh) * 64 + lane];
  float bs[4];
#pragma unroll
  for (int t = 0; t < 4; t++) bs[t] = bias[t * 16 + m];
  f32x4 accA[2][4];
#pragma unroll
  for (int rb = 0; rb < 2; rb++){
    long n0 = base + w * 32 + rb * 16;
    const short8* xr = (const short8*)(xagg + (n0 + m) * 64);
    short8 A0 = xr[q];
    short8 A1 = xr[q + 4];
#pragma unroll
    for (int t = 0; t < 4; t++){
      f32x4 acc = (f32x4){bs[t], bs[t], bs[t], bs[t]};
      acc = __builtin_amdgcn_mfma_f32_16x16x32_bf16(A0, Bf[t][0], acc, 0, 0, 0);
      acc = __builtin_amdgcn_mfma_f32_16x16x32_bf16(A1, Bf[t][1], acc, 0, 0, 0);
#pragma unroll
      for (int r = 0; r < 4; r++) acc[r] = fmaxf(acc[r], 0.f);
      accA[rb][t] = acc;
#pragma unroll
      for (int r = 0; r < 4; r++)
        xt[(w * 32 + rb * 16 + q * 4 + r) * 72 + t * 16 + m] = f2bs(acc[r]);
    }
  }
  __syncthreads();
  // stage B: pool GEMM from LDS -> gates
  const short8* pfrag = frag + 4 * 512;
  const float* qv_ = qbuf + ((size_t)(side * 2 + l) * NB + g) * 64;
  short8 Pf[4][2];
#pragma unroll
  for (int t = 0; t < 4; t++)
#pragma unroll
    for (int hh = 0; hh < 2; hh++)
      Pf[t][hh] = pfrag[(t * 2 + hh) * 64 + lane];
  float qv[4];
#pragma unroll
  for (int t = 0; t < 4; t++) qv[t] = qv_[t * 16 + m];
#pragma unroll
  for (int rb = 0; rb < 2; rb++){
    int rowb = w * 32 + rb * 16;
    short8 A0 = *(const short8*)(xt + (rowb + m) * 72 + q * 8);
    short8 A1 = *(const short8*)(xt + (rowb + m) * 72 + 32 + q * 8);
    f32x4 accp[4];
#pragma unroll
    for (int t = 0; t < 4; t++){
      accp[t] = (f32x4){0.f, 0.f, 0.f, 0.f};
      accp[t] = __builtin_amdgcn_mfma_f32_16x16x32_bf16(A0, Pf[t][0], accp[t], 0, 0, 0);
      accp[t] = __builtin_amdgcn_mfma_f32_16x16x32_bf16(A1, Pf[t][1], accp[t], 0, 0, 0);
    }
#pragma unroll
    for (int r = 0; r < 4; r++){
      float p = accp[0][r] * qv[0] + accp[1][r] * qv[1] +
                accp[2][r] * qv[2] + accp[3][r] * qv[3];
      p += __shfl_xor(p, 1, 64); p += __shfl_xor(p, 2, 64);
      p += __shfl_xor(p, 4, 64); p += __shfl_xor(p, 8, 64);
      if (m == 0)
        gates[rowb + q * 4 + r] = 1.f / (1.f + __expf(-p * 0.125f));
    }
  }
  __syncthreads();
  // gated max pool
  const unsigned* xt32 = (const unsigned*)xt;
  int c = lane & 31, half = lane >> 5;
  float mxx = 0.f, mxy = 0.f;
#pragma unroll
  for (int p = 0; p < 16; p++){
    int nn = w * 32 + 2 * p + half;
    unsigned v = xt32[nn * 36 + c];
    float gt = gates[nn];
    mxx = fmaxf(mxx, ulo2f(v) * gt);
    mxy = fmaxf(mxy, uhi2f(v) * gt);
  }
  mxx = fmaxf(mxx, __shfl_xor(mxx, 32, 64));
  mxy = fmaxf(mxy, __shfl_xor(mxy, 32, 64));
  if (half == 0){ red[w][2 * c] = mxx; red[w][2 * c + 1] = mxy; }
  __syncthreads();
  if (tid < 64){
    const float* twW = twW_all + l * 4096;
    const float* twb = twb_all + l * 64;
    int off = (side ? 256 : 64) + l * 64;
    float p = fmaxf(fmaxf(red[0][tid], red[1][tid]), fmaxf(red[2][tid], red[3][tid]));
    float o = twb[tid];
    red[0][tid] = p;
    __syncwarp();
    for (int d = 0; d < 64; d++) o += red[0][d] * twW[d * 64 + tid];
    xfm[g * 384 + off + tid] = fmaxf(o, 0.f);
  }
  if (l == 0){
    // gated next-layer input write (coalesced via LDS)
#pragma unroll
    for (int p = 0; p < 4; p++){
      int row = p * 32 + (tid >> 3);
      int col8 = (tid & 7) * 8;
      float gt = gates[row];
      short8 v = *(const short8*)(xt + row * 72 + col8);
      short8 o;
#pragma unroll
      for (int j = 0; j < 8; j++) o[j] = f2bs(bs2f(v[j]) * gt);
      *(short8*)(xnext + (base + row) * 64 + col8) = o;
    }
    // next-layer a0/a1 from gated x_next: a = g*(x.waA1) + ba1
    const float* wn0p = waA_all + ((side * 2 + 1) * 2 + 0) * 64;
    const float* wn1p = wn0p + 64;
    float wn0[4], wn1[4];
#pragma unroll
    for (int t = 0; t < 4; t++){ wn0[t] = wn0p[t * 16 + m]; wn1[t] = wn1p[t * 16 + m]; }
    float ban0 = ba_all[(side * 2 + 1) * 2 + 0];
    float ban1 = ba_all[(side * 2 + 1) * 2 + 1];
#pragma unroll
    for (int rb = 0; rb < 2; rb++)
#pragma unroll
      for (int r = 0; r < 4; r++){
        float p0 = accA[rb][0][r] * wn0[0] + accA[rb][1][r] * wn0[1] +
                   accA[rb][2][r] * wn0[2] + accA[rb][3][r] * wn0[3];
        float p1 = accA[rb][0][r] * wn1[0] + accA[rb][1][r] * wn1[1] +
                   accA[rb][2][r] * wn1[2] + accA[rb][3][r] * wn1[3];
        p0 += __shfl_xor(p0, 1, 64); p0 += __shfl_xor(p0, 2, 64);
        p0 += __shfl_xor(p0, 4, 64); p0 += __shfl_xor(p0, 8, 64);
        p1 += __shfl_xor(p1, 1, 64); p1 += __shfl_xor(p1, 2, 64);
        p1 += __shfl_xor(p1, 4, 64); p1 += __shfl_xor(p1, 8, 64);
        if (m == 0){
          int row = w * 32 + rb * 16 + q * 4 + r;
          float gr = gates[row];
          a0[base + row] = p0 * gr + ban0;
          a1[base + row] = p1 * gr + ban1;
        }
      }
  }
}

// ---------------- FM head: 4 graphs per block, V streamed once per block ----------------
__global__ __launch_bounds__(384) void k_fm(
    const float* __restrict__ xfm, const float* __restrict__ V,
    const float* __restrict__ fw, const float* __restrict__ bu,
    const float* __restrict__ bi, const float* __restrict__ b0,
    const int* __restrict__ uid, const int* __restrict__ iid,
    float* __restrict__ out){
  __shared__ float xsh[4][384];
  __shared__ float xsq[4][384];
  __shared__ float part[4][384];
  int j = threadIdx.x;
  int g0 = blockIdx.x * 4;
#pragma unroll
  for (int b = 0; b < 4; b++){
    float xv_ = xfm[(g0 + b) * 384 + j];
    xsh[b][j] = xv_;
    xsq[b][j] = xv_ * xv_;
  }
  __syncthreads();
  float xv[4] = {0.f, 0.f, 0.f, 0.f};
  float vv[4] = {0.f, 0.f, 0.f, 0.f};
  for (int k = 0; k < 384; k++){
    float v = V[(size_t)k * 384 + j];
    float v2 = v * v;
#pragma unroll
    for (int b = 0; b < 4; b++){
      xv[b] = fmaf(xsh[b][k], v, xv[b]);
      vv[b] = fmaf(xsq[b][k], v2, vv[b]);
    }
  }
  float fwj = fw[j];
#pragma unroll
  for (int b = 0; b < 4; b++)
    part[b][j] = 0.5f * (xv[b] * xv[b] - vv[b]) + xsh[b][j] * fwj;
  __syncthreads();
  int w = j >> 6, lane = j & 63;
  if (w < 4){
    float s = part[w][lane] + part[w][lane + 64] + part[w][lane + 128] +
              part[w][lane + 192] + part[w][lane + 256] + part[w][lane + 320];
    s = wsum(s);
    if (lane == 0){
      int b = g0 + w;
      out[b] = s + bu[uid[b]] + bi[iid[b]] + b0[0];
    }
  }
}

extern "C" void kernel_launch(void* const* d_in, const int* in_sizes, int n_in,
                              void* d_out, int out_size, void* d_ws, size_t ws_size,
                              hipStream_t stream) {
  const int* uid      = (const int*)d_in[0];
  const int* iid      = (const int*)d_in[1];
  const int* u_nodes  = (const int*)d_in[2];
  const int* i_nodes  = (const int*)d_in[3];
  const int* u_ei     = (const int*)d_in[4];
  const int* i_ei     = (const int*)d_in[5];
  const int* u_et     = (const int*)d_in[6];
  const int* i_et     = (const int*)d_in[7];
  const float* user_emb = (const float*)d_in[10];
  const float* item_emb = (const float*)d_in[11];
  const float* word_emb = (const float*)d_in[12];
  const float* trans_u_W = (const float*)d_in[13];
  const float* trans_u_b = (const float*)d_in[14];
  const float* trans_i_W = (const float*)d_in[15];
  const float* trans_i_b = (const float*)d_in[16];
  const float* trans_w_W = (const float*)d_in[17];
  const float* trans_w_b = (const float*)d_in[18];
  const float* inter_u_W = (const float*)d_in[19];
  const float* inter_u_b = (const float*)d_in[20];
  const float* inter_i_W = (const float*)d_in[21];
  const float* inter_i_b = (const float*)d_in[22];
  const float* conv_u_W  = (const float*)d_in[23];
  const float* conv_u_b  = (const float*)d_in[24];
  const float* conv_u_att= (const float*)d_in[25];
  const float* conv_u_rel= (const float*)d_in[26];
  const float* conv_i_W  = (const float*)d_in[27];
  const float* conv_i_b  = (const float*)d_in[28];
  const float* conv_i_att= (const float*)d_in[29];
  const float* conv_i_rel= (const float*)d_in[30];
  const float* pool_W    = (const float*)d_in[31];
  const float* fm_w      = (const float*)d_in[32];
  const float* fm_V      = (const float*)d_in[33];
  const float* fm_bias_u = (const float*)d_in[34];
  const float* fm_bias_i = (const float*)d_in[35];
  const float* fm_bias   = (const float*)d_in[36];
  float* out = (float*)d_out;
  int n32 = in_sizes[12] / 2;          // packed uints in word table
  int nwords = in_sizes[12] / 64;      // words (HID=64)
  int wconvB = (n32 + 255) / 256;

  // workspace carve-up (ebuf aliases X0 — dead before k_agg0 writes X0)
  char* w = (char*)d_ws;
  short* X0   = (short*)w;          w += (size_t)2 * NN * 64 * 2;   // 32 MB
  short* X1   = (short*)w;          w += (size_t)2 * NN * 64 * 2;   // 32 MB
  short* wtab = (short*)w;          w += (size_t)in_sizes[12] * 2;  // bf16 word table
  int* pedge  = (int*)w;            w += (size_t)2 * NE * 4;
  float* a0   = (float*)w;          w += (size_t)2 * NN * 4;
  float* a1   = (float*)w;          w += (size_t)2 * NN * 4;
  float* wa0  = (float*)w;          w += (size_t)2 * nwords * 4;
  float* wa1  = (float*)w;          w += (size_t)2 * nwords * 4;
  int* cntmat = (int*)w;            w += (size_t)K1B * NBKT * 4;    // 1 MB
  int* rowfin = (int*)w;            w += (size_t)(2 * NN + 256) * 4;
  int* btot   = (int*)w;            w += NBKT * 4;
  int* bbase  = (int*)w;            w += (NBKT + 1) * 4;
  short8* frag = (short8*)w;        w += (size_t)5 * 512 * 16;
  float* waA  = (float*)w;          w += 2 * 2 * 2 * 64 * 4;
  float* ba   = (float*)w;          w += 64;
  float* rtab = (float*)w;          w += 64;
  float* qbuf = (float*)w;          w += (size_t)4 * NB * 64 * 4;
  float* xfm  = (float*)w;          w += (size_t)NB * 384 * 4;
  int* ebuf = (int*)X0;             // 2*NE*4 B = 4 MB, dead before k_agg0 writes X0

  int megaB = K1B + 12 + wconvB + 2 * NB / 4;
  k_mega<<<megaB, 256, 0, stream>>>(wconvB, u_ei, i_ei, cntmat,
                                    word_emb, (unsigned*)wtab, n32,
                                    conv_u_W, conv_i_W, pool_W, conv_u_b, conv_i_b,
                                    conv_u_att, conv_i_att, conv_u_rel, conv_i_rel,
                                    frag, waA, ba, rtab,
                                    uid, iid, user_emb, item_emb,
                                    inter_u_W, inter_u_b, inter_i_W, inter_i_b,
                                    trans_u_W, trans_u_b, trans_i_W, trans_i_b,
                                    xfm, qbuf);
  k_colscan<<<NBKT, 256, 0, stream>>>(cntmat, btot);
  k_bscan<<<1, NBKT, 0, stream>>>(btot, bbase);
  int wgB = (2 * nwords + 31) / 32;
  k_scat<<<K1B + wgB, 256, 0, stream>>>(u_ei, i_ei, u_et, i_et, cntmat, bbase,
                                        ebuf, wtab, nwords, waA, ba, wa0, wa1);
  k_csr<<<NBKT, 256, 0, stream>>>(bbase, ebuf, rowfin, pedge);

  // layer 0: aggregate straight from the word table
  k_agg0<<<2 * NN / 32, 256, 0, stream>>>(rowfin, pedge, wa0, wa1,
                                          u_nodes, i_nodes, nwords, rtab,
                                          wtab, (unsigned*)X0);
  k_gp  <<<2 * NB, 256, 0, stream>>>(0, X0, frag, conv_u_b, conv_i_b, waA, ba,
                                     qbuf, trans_w_W, trans_w_b, xfm, X1, a0, a1);
  // layer 1
  k_agg1<<<2 * NN / 32, 256, 0, stream>>>(rowfin, pedge, a0, a1, rtab,
                                          X1, (unsigned*)X0);
  k_gp  <<<2 * NB, 256, 0, stream>>>(1, X0, frag, conv_u_b, conv_i_b, waA, ba,
                                     qbuf, trans_w_W, trans_w_b, xfm,
                                     nullptr, nullptr, nullptr);

  k_fm<<<NB / 4, 384, 0, stream>>>(xfm, fm_V, fm_w, fm_bias_u, fm_bias_i, fm_bias,
                                   uid, iid, out);
}

// Round 9
// 358.429 us; speedup vs baseline: 1.2240x; 1.0451x over previous
//
#include <hip/hip_runtime.h>
#include <hip/hip_bf16.h>

#define NN 131072   // nodes per side
#define NE 524288   // edges per side
#define NB 1024     // batch (graphs per side)
#define NBKT 512    // dst buckets (512-node ranges); 2NN/NBKT = 512 nodes/bucket
#define K1B 512     // edge-chunk blocks; CHUNK = 2NE/K1B = 2048 edges (8/thread)

typedef __attribute__((ext_vector_type(8))) short short8;   // 8 bf16
typedef __attribute__((ext_vector_type(4))) float f32x4;

__device__ __forceinline__ float wsum(float v){
#pragma unroll
  for (int o = 32; o > 0; o >>= 1) v += __shfl_xor(v, o, 64);
  return v;
}
__device__ __forceinline__ short f2bs(float f){
  __hip_bfloat16 t = __float2bfloat16(f);
  union { __hip_bfloat16 b; short s; } u; u.b = t; return u.s;
}
__device__ __forceinline__ float bs2f(short s){
  return __uint_as_float(((unsigned)(unsigned short)s) << 16);
}
__device__ __forceinline__ float ulo2f(unsigned v){ return __uint_as_float(v << 16); }
__device__ __forceinline__ float uhi2f(unsigned v){ return __uint_as_float(v & 0xFFFF0000u); }
__device__ __forceinline__ unsigned fpack(float x, float y){
  return (unsigned)(unsigned short)f2bs(x) | ((unsigned)(unsigned short)f2bs(y) << 16);
}

// ---------------- mega: K1 bucket-count (LDS hist, no global atomics) | frag | waA/ba/rtab | wconv | prep ----------------
__global__ void k_mega(int wconvB,
                       const int* __restrict__ u_ei, const int* __restrict__ i_ei,
                       int* __restrict__ cntmat,
                       const float* __restrict__ wemb, unsigned* __restrict__ wtab,
                       int n32,
                       const float* __restrict__ cuW, const float* __restrict__ ciW,
                       const float* __restrict__ pW,
                       const float* __restrict__ cub, const float* __restrict__ cib,
                       const float* __restrict__ uatt, const float* __restrict__ iatt,
                       const float* __restrict__ urel, const float* __restrict__ irel,
                       short8* __restrict__ frag, float* __restrict__ waA,
                       float* __restrict__ ba, float* __restrict__ rtab,
                       const int* __restrict__ uid, const int* __restrict__ iid,
                       const float* __restrict__ uemb, const float* __restrict__ iemb,
                       const float* __restrict__ uiW, const float* __restrict__ uib,
                       const float* __restrict__ iiW, const float* __restrict__ iib,
                       const float* __restrict__ utW, const float* __restrict__ utb,
                       const float* __restrict__ itW, const float* __restrict__ itb,
                       float* __restrict__ xfm, float* __restrict__ q){
  int blk = blockIdx.x, tid = threadIdx.x;
  if (blk < K1B){
    // per-chunk bucket histogram in LDS; write matrix row (no global atomics)
    __shared__ int hist[NBKT];
    hist[tid] = 0; hist[tid + 256] = 0;
    __syncthreads();
#pragma unroll
    for (int k = 0; k < 8; k++){
      int ee = blk * 2048 + k * 256 + tid;
      int side = ee >= NE;
      int e = ee - side * NE;
      const int* ei = side ? i_ei : u_ei;
      int dst = ei[NE + e] + side * NN;
      atomicAdd(&hist[dst >> 9], 1);
    }
    __syncthreads();
    cntmat[blk * NBKT + tid] = hist[tid];
    cntmat[blk * NBKT + tid + 256] = hist[tid + 256];
  } else if (blk < K1B + 10){
    int b2 = blk - K1B;
    int mat = b2 >> 1;
    const float* W = mat < 2 ? cuW + mat * 4096 : (mat < 4 ? ciW + (mat - 2) * 4096 : pW);
    int g = (b2 & 1) * 256 + tid;     // [0,512)
    int lane = g & 63, rest = g >> 6;
    int hh = rest & 1, t = rest >> 1;
    int m = lane & 15, qq = lane >> 4;
    short8 v;
#pragma unroll
    for (int j = 0; j < 8; j++)
      v[j] = f2bs(W[(hh * 32 + qq * 8 + j) * 64 + (t * 16 + m)]);
    frag[mat * 512 + g] = v;
  } else if (blk < K1B + 12){
    int side = blk - K1B - 10;
    const float* W    = side ? ciW : cuW;
    const float* bias = side ? cib : cub;
    const float* att  = side ? iatt : uatt;
    const float* rel  = side ? irel : urel;
    int l = tid >> 7, a = (tid >> 6) & 1, kk = tid & 63;
    float s = 0.f;
    for (int c = 0; c < 64; c++) s += W[l * 4096 + kk * 64 + c] * att[l * 192 + a * 64 + c];
    waA[((side * 2 + l) * 2 + a) * 64 + kk] = s;
    if (tid < 4){
      int l2 = tid >> 1, a2 = tid & 1;
      float sb = 0.f;
      for (int c = 0; c < 64; c++) sb += bias[l2 * 64 + c] * att[l2 * 192 + a2 * 64 + c];
      ba[(side * 2 + l2) * 2 + a2] = sb;
    }
    if (tid >= 4 && tid < 12){
      int id = tid - 4, l2 = id >> 2, tt = id & 3;
      float sr = 0.f;
      for (int c = 0; c < 64; c++) sr += rel[l2 * 256 + tt * 64 + c] * att[l2 * 192 + 128 + c];
      rtab[(side * 2 + l2) * 4 + tt] = sr;
    }
  } else if (blk < K1B + 12 + wconvB){
    int id = (blk - K1B - 12) * 256 + tid;
    if (id < n32){
      const float2* src = (const float2*)wemb;
      float2 v = src[id];
      wtab[id] = fpack(v.x, v.y);
    }
  } else {
    int lane = tid & 63, w = tid >> 6;
    int b = (blk - K1B - 12 - wconvB) * 4 + w;   // [0, 2NB)
    int side = b >= NB;
    int lb = b - side * NB;
    const int* ids = side ? iid : uid;
    const float* emb = side ? iemb : uemb;
    const float* interW = side ? iiW : uiW;
    const float* interB = side ? iib : uib;
    const float* transW = side ? itW : utW;
    const float* transB = side ? itb : utb;
    int repOff = side ? 192 : 0;
    float xe = emb[(long)ids[lb] * 64 + lane];
    float o = interB[lane];
#pragma unroll
    for (int k = 0; k < 64; k++) o += __shfl(xe, k, 64) * interW[k * 64 + lane];
    xfm[lb * 384 + repOff + lane] = fmaxf(o, 0.f);
    for (int l = 0; l < 2; l++){
      float t = transB[l * 64 + lane];
#pragma unroll
      for (int k = 0; k < 64; k++) t += __shfl(xe, k, 64) * transW[l * 4096 + k * 64 + lane];
      q[((size_t)(side * 2 + l) * NB + lb) * 64 + lane] = fmaxf(t, 0.f);
    }
  }
}

// column-exclusive-prefix of cntmat (per bucket over chunks) + bucket totals
__global__ void k_colscan(int* __restrict__ cntmat, int* __restrict__ btot){
  __shared__ int sh[256];
  int b = blockIdx.x, t = threadIdx.x;
  int c0 = cntmat[(2 * t) * NBKT + b];
  int c1 = cntmat[(2 * t + 1) * NBKT + b];
  int s = c0 + c1;
  sh[t] = s; __syncthreads();
  for (int off = 1; off < 256; off <<= 1){
    int v = (t >= off) ? sh[t - off] : 0;
    __syncthreads();
    sh[t] += v;
    __syncthreads();
  }
  int incl = sh[t];
  int excl = incl - s;
  cntmat[(2 * t) * NBKT + b] = excl;
  cntmat[(2 * t + 1) * NBKT + b] = excl + c0;
  if (t == 255) btot[b] = incl;
}

// exclusive scan of bucket totals -> bucket bases (+sentinel)
__global__ void k_bscan(const int* __restrict__ btot, int* __restrict__ bbase){
  __shared__ int sh[NBKT];
  int t = threadIdx.x;
  int v = btot[t];
  sh[t] = v; __syncthreads();
  for (int off = 1; off < NBKT; off <<= 1){
    int x = (t >= off) ? sh[t - off] : 0;
    __syncthreads();
    sh[t] += x;
    __syncthreads();
  }
  bbase[t] = sh[t] - v;
  if (t == NBKT - 1) bbase[NBKT] = 2 * NE;
}

// ---------------- scatter edges into bucket runs (LDS slots, no global atomics) | wa tables ----------------
__global__ void k_scat(const int* __restrict__ u_ei, const int* __restrict__ i_ei,
                       const int* __restrict__ u_et, const int* __restrict__ i_et,
                       const int* __restrict__ cntmat, const int* __restrict__ bbase,
                       int* __restrict__ ebuf,
                       const short* __restrict__ wtab, int nwords,
                       const float* __restrict__ waA, const float* __restrict__ ba,
                       float* __restrict__ wa0, float* __restrict__ wa1){
  int blk = blockIdx.x, tid = threadIdx.x;
  if (blk < K1B){
    __shared__ int hist[NBKT];
    __shared__ int mb[NBKT];
    hist[tid] = 0; hist[tid + 256] = 0;
    mb[tid]       = cntmat[blk * NBKT + tid]       + bbase[tid];
    mb[tid + 256] = cntmat[blk * NBKT + tid + 256] + bbase[tid + 256];
    __syncthreads();
#pragma unroll
    for (int k = 0; k < 8; k++){
      int ee = blk * 2048 + k * 256 + tid;
      int side = ee >= NE;
      int e = ee - side * NE;
      const int* ei = side ? i_ei : u_ei;
      const int* et = side ? i_et : u_et;
      int dst = ei[NE + e] + side * NN;
      int src = ei[e] + side * NN;
      int bin = dst >> 9;
      int slot = atomicAdd(&hist[bin], 1);
      ebuf[mb[bin] + slot] = src | (et[e] << 18) | ((dst & 511) << 20);
    }
  } else {
    // wa0/wa1[side][word] = wtab[word] . waA(side,l=0,a) + ba
    int lane = tid & 63, w = tid >> 6;
    int q = lane >> 4, cl = lane & 15;
    int sw0 = ((blk - K1B) * 4 + w) * 8;
    const uint2* wt2 = (const uint2*)wtab;
    for (int it = 0; it < 2; it++){
      int wj = sw0 + it * 4 + q;
      if (wj >= 2 * nwords) continue;
      int side = wj >= nwords;
      int wid = wj - side * nwords;
      const float* A0 = waA + (side * 2 + 0) * 2 * 64;
      const float* A1 = A0 + 64;
      uint2 v = wt2[(long)wid * 16 + cl];
      int d = 4 * cl;
      float p0 = ulo2f(v.x) * A0[d] + uhi2f(v.x) * A0[d + 1] +
                 ulo2f(v.y) * A0[d + 2] + uhi2f(v.y) * A0[d + 3];
      float p1 = ulo2f(v.x) * A1[d] + uhi2f(v.x) * A1[d + 1] +
                 ulo2f(v.y) * A1[d + 2] + uhi2f(v.y) * A1[d + 3];
      p0 += __shfl_xor(p0, 1, 64); p0 += __shfl_xor(p0, 2, 64);
      p0 += __shfl_xor(p0, 4, 64); p0 += __shfl_xor(p0, 8, 64);
      p1 += __shfl_xor(p1, 1, 64); p1 += __shfl_xor(p1, 2, 64);
      p1 += __shfl_xor(p1, 4, 64); p1 += __shfl_xor(p1, 8, 64);
      if (cl == 0){
        wa0[(size_t)side * nwords + wid] = p0 + ba[side * 4 + 0];
        wa1[(size_t)side * nwords + wid] = p1 + ba[side * 4 + 1];
      }
    }
  }
}

// ---------------- per-bucket CSR finalize: counts -> local scan -> rowfin + dst-grouped pedge ----------------
__global__ __launch_bounds__(256) void k_csr(
    const int* __restrict__ bbase, const int* __restrict__ ebuf,
    int* __restrict__ rowfin, int* __restrict__ pedge){
  __shared__ int hist[NBKT];   // 512 node-bins for this bucket; later reused as cursor
  __shared__ int sh[256];
  int b = blockIdx.x, t = threadIdx.x;
  int eb0 = bbase[b], eb1 = bbase[b + 1];
  hist[t] = 0; hist[t + 256] = 0;
  __syncthreads();
  for (int e = eb0 + t; e < eb1; e += 256)
    atomicAdd(&hist[(ebuf[e] >> 20) & 511], 1);
  __syncthreads();
  int c0 = hist[2 * t], c1 = hist[2 * t + 1];
  int s = c0 + c1;
  sh[t] = s; __syncthreads();
  for (int off = 1; off < 256; off <<= 1){
    int v = (t >= off) ? sh[t - off] : 0;
    __syncthreads();
    sh[t] += v;
    __syncthreads();
  }
  int excl = sh[t] - s;
  int nbase = b * 512;
  rowfin[nbase + 2 * t] = eb0 + excl;
  rowfin[nbase + 2 * t + 1] = eb0 + excl + c0;
  hist[2 * t] = excl;            // cursor init (own bins; all reads done above)
  hist[2 * t + 1] = excl + c0;
  __syncthreads();
  for (int e = eb0 + t; e < eb1; e += 256){
    int rec = ebuf[e];
    int bin = (rec >> 20) & 511;
    int p = atomicAdd(&hist[bin], 1);
    pedge[eb0 + p] = rec & 0xFFFFF;   // src | et<<18
  }
  if (b == NBKT - 1 && t == 0) rowfin[2 * NN] = 2 * NE;
}

// ---------------- aggregation: 8-lane groups, uint4 feature slices ----------------
// One node per 8-lane group (8 nodes/wave, one parallel pass). 8 edge slots
// statically unrolled; lane covers 16B (8 bf16) of the 128B row.
template<int L>
__device__ __forceinline__ void dev_agg(
    const int* __restrict__ rowptr, const int* __restrict__ pedge,
    const float* __restrict__ a0, const float* __restrict__ a1,        // L==1
    const float* __restrict__ wa0, const float* __restrict__ wa1,      // L==0
    const int* __restrict__ u_nodes, const int* __restrict__ i_nodes, int nwords,
    const float* __restrict__ rtab, const short* __restrict__ rows,
    unsigned* __restrict__ xo32){
  int lane = threadIdx.x & 63, w = threadIdx.x >> 6;
  int grp = lane >> 3, cl = lane & 7;
  int n = (blockIdx.x * 4 + w) * 8 + grp;          // node for this 8-lane group
  int side = n >= NN;                               // uniform per wave (NN % 8 == 0)
  const float* rt = rtab + (side * 2 + L) * 4;
  float rt0 = rt[0], rt1 = rt[1], rt2 = rt[2], rt3 = rt[3];
  const int* nodesS = side ? i_nodes : u_nodes;
  const float* wa0S = wa0 + (size_t)side * nwords;
  const float* wa1S = wa1 + (size_t)side * nwords;
  const uint4* h4 = (const uint4*)rows;

  int r0 = rowptr[n], r1 = rowptr[n + 1];          // broadcast loads
  int deg = r1 - r0;
  float a1n;
  if (L == 0) a1n = wa1S[nodesS[n - side * NN]];
  else        a1n = a1[n];

  int pe[8]; int rowv[8]; float av[8]; uint4 hv[8];
#pragma unroll
  for (int j = 0; j < 8; j++)
    pe[j] = (j < deg) ? pedge[r0 + j] : 0;         // 8 independent broadcast loads
#pragma unroll
  for (int j = 0; j < 8; j++){
    int s = pe[j] & 0x3FFFF;
    if (L == 0){
      int wid = 0;
      if (j < deg) wid = nodesS[s - side * NN];
      rowv[j] = wid;
    } else {
      rowv[j] = s;
    }
  }
#pragma unroll
  for (int j = 0; j < 8; j++){
    av[j] = 0.f;
    if (j < deg) av[j] = (L == 0) ? wa0S[rowv[j]] : a0[rowv[j]];
    uint4 z; z.x = 0u; z.y = 0u; z.z = 0u; z.w = 0u;
    hv[j] = z;
    if (j < deg) hv[j] = h4[(long)rowv[j] * 8 + cl];   // 16B feature slice
  }
  float ax0 = 0.f, ay0 = 0.f, ax1 = 0.f, ay1 = 0.f;
  float ax2 = 0.f, ay2 = 0.f, ax3 = 0.f, ay3 = 0.f, den = 0.f;
#pragma unroll
  for (int j = 0; j < 8; j++){
    int et = (pe[j] >> 18) & 3;
    float rr = (et & 2) ? ((et & 1) ? rt3 : rt2) : ((et & 1) ? rt1 : rt0);
    float v = av[j] + a1n + rr;
    v = (v > 0.f) ? v : 0.2f * v;
    float ex = (j < deg) ? __expf(v) : 0.f;
    ax0 += ex * ulo2f(hv[j].x); ay0 += ex * uhi2f(hv[j].x);
    ax1 += ex * ulo2f(hv[j].y); ay1 += ex * uhi2f(hv[j].y);
    ax2 += ex * ulo2f(hv[j].z); ay2 += ex * uhi2f(hv[j].z);
    ax3 += ex * ulo2f(hv[j].w); ay3 += ex * uhi2f(hv[j].w);
    den += ex;
  }
  // rare tail: deg > 8 (~2% of nodes at Poisson(4))
  for (int e = r0 + 8; e < r1; ++e){
    int pe2 = pedge[e];
    int s = pe2 & 0x3FFFF;
    int et = (pe2 >> 18) & 3;
    float rr = (et & 2) ? ((et & 1) ? rt3 : rt2) : ((et & 1) ? rt1 : rt0);
    float avv; long row;
    if (L == 0){ int wid = nodesS[s - side * NN]; avv = wa0S[wid]; row = wid; }
    else       { avv = a0[s]; row = s; }
    float v = avv + a1n + rr;
    v = (v > 0.f) ? v : 0.2f * v;
    float ex = __expf(v);
    uint4 hvv = h4[row * 8 + cl];
    ax0 += ex * ulo2f(hvv.x); ay0 += ex * uhi2f(hvv.x);
    ax1 += ex * ulo2f(hvv.y); ay1 += ex * uhi2f(hvv.y);
    ax2 += ex * ulo2f(hvv.z); ay2 += ex * uhi2f(hvv.z);
    ax3 += ex * ulo2f(hvv.w); ay3 += ex * uhi2f(hvv.w);
    den += ex;
  }
  float inv = 1.f / (den + 1e-16f);
  uint4 o;
  o.x = fpack(ax0 * inv, ay0 * inv);
  o.y = fpack(ax1 * inv, ay1 * inv);
  o.z = fpack(ax2 * inv, ay2 * inv);
  o.w = fpack(ax3 * inv, ay3 * inv);
  ((uint4*)xo32)[(long)n * 8 + cl] = o;            // coalesced: 1KB per wave
}

__global__ __launch_bounds__(256) void k_agg0(
    const int* __restrict__ rowptr, const int* __restrict__ pedge,
    const float* __restrict__ wa0, const float* __restrict__ wa1,
    const int* __restrict__ u_nodes, const int* __restrict__ i_nodes, int nwords,
    const float* __restrict__ rtab, const short* __restrict__ wtab,
    unsigned* __restrict__ xo32){
  dev_agg<0>(rowptr, pedge, nullptr, nullptr, wa0, wa1, u_nodes, i_nodes, nwords,
             rtab, wtab, xo32);
}

__global__ __launch_bounds__(256) void k_agg1(
    const int* __restrict__ rowptr, const int* __restrict__ pedge,
    const float* __restrict__ a0, const float* __restrict__ a1,
    const float* __restrict__ rtab, const short* __restrict__ x,
    unsigned* __restrict__ xo32){
  dev_agg<1>(rowptr, pedge, a0, a1, nullptr, nullptr, nullptr, nullptr, 0,
             rtab, x, xo32);
}

// ---------------- fused post: x=relu(xagg@W+b); gates; gmp; trans_w; gated X1 + a0/a1 ----------------
__global__ __launch_bounds__(256) void k_gp(
    int l, const short* __restrict__ xagg, const short8* __restrict__ frag,
    const float* __restrict__ cub, const float* __restrict__ cib,
    const float* __restrict__ waA_all, const float* __restrict__ ba_all,
    const float* __restrict__ qbuf, const float* __restrict__ twW_all,
    const float* __restrict__ twb_all, float* __restrict__ xfm,
    short* __restrict__ xnext, float* __restrict__ a0, float* __restrict__ a1){
  __shared__ short xt[128 * 72];       // padded rows (72 shorts) for bank spread
  __shared__ float gates[128];
  __shared__ float red[4][64];
  int b = blockIdx.x;                  // [0, 2NB)
  int side = b >= NB;
  int g = b - side * NB;
  long base = (long)side * NN + (long)g * 128;
  int tid = threadIdx.x, lane = tid & 63, w = tid >> 6;
  int m = lane & 15, q = lane >> 4;
  // stage A: conv GEMM
  const short8* wfrag = frag + (side * 2 + l) * 512;
  const float* bias = (side ? cib : cub) + l * 64;
  short8 Bf[4][2];
#pragma unroll
  for (int t = 0; t < 4; t++)
#pragma unroll
    for (int hh = 0; hh < 2; hh++)
      Bf[t][hh] = wfrag[(t * 2 + hh) * 64 + lane];
  float bs[4];
#pragma unroll
  for (int t = 0; t < 4; t++) bs[t] = bias[t * 16 + m];
  f32x4 accA[2][4];
#pragma unroll
  for (int rb = 0; rb < 2; rb++){
    long n0 = base + w * 32 + rb * 16;
    const short8* xr = (const short8*)(xagg + (n0 + m) * 64);
    short8 A0 = xr[q];
    short8 A1 = xr[q + 4];
#pragma unroll
    for (int t = 0; t < 4; t++){
      f32x4 acc = (f32x4){bs[t], bs[t], bs[t], bs[t]};
      acc = __builtin_amdgcn_mfma_f32_16x16x32_bf16(A0, Bf[t][0], acc, 0, 0, 0);
      acc = __builtin_amdgcn_mfma_f32_16x16x32_bf16(A1, Bf[t][1], acc, 0, 0, 0);
#pragma unroll
      for (int r = 0; r < 4; r++) acc[r] = fmaxf(acc[r], 0.f);
      accA[rb][t] = acc;
#pragma unroll
      for (int r = 0; r < 4; r++)
        xt[(w * 32 + rb * 16 + q * 4 + r) * 72 + t * 16 + m] = f2bs(acc[r]);
    }
  }
  __syncthreads();
  // stage B: pool GEMM from LDS -> gates
  const short8* pfrag = frag + 4 * 512;
  const float* qv_ = qbuf + ((size_t)(side * 2 + l) * NB + g) * 64;
  short8 Pf[4][2];
#pragma unroll
  for (int t = 0; t < 4; t++)
#pragma unroll
    for (int hh = 0; hh < 2; hh++)
      Pf[t][hh] = pfrag[(t * 2 + hh) * 64 + lane];
  float qv[4];
#pragma unroll
  for (int t = 0; t < 4; t++) qv[t] = qv_[t * 16 + m];
#pragma unroll
  for (int rb = 0; rb < 2; rb++){
    int rowb = w * 32 + rb * 16;
    short8 A0 = *(const short8*)(xt + (rowb + m) * 72 + q * 8);
    short8 A1 = *(const short8*)(xt + (rowb + m) * 72 + 32 + q * 8);
    f32x4 accp[4];
#pragma unroll
    for (int t = 0; t < 4; t++){
      accp[t] = (f32x4){0.f, 0.f, 0.f, 0.f};
      accp[t] = __builtin_amdgcn_mfma_f32_16x16x32_bf16(A0, Pf[t][0], accp[t], 0, 0, 0);
      accp[t] = __builtin_amdgcn_mfma_f32_16x16x32_bf16(A1, Pf[t][1], accp[t], 0, 0, 0);
    }
#pragma unroll
    for (int r = 0; r < 4; r++){
      float p = accp[0][r] * qv[0] + accp[1][r] * qv[1] +
                accp[2][r] * qv[2] + accp[3][r] * qv[3];
      p += __shfl_xor(p, 1, 64); p += __shfl_xor(p, 2, 64);
      p += __shfl_xor(p, 4, 64); p += __shfl_xor(p, 8, 64);
      if (m == 0)
        gates[rowb + q * 4 + r] = 1.f / (1.f + __expf(-p * 0.125f));
    }
  }
  __syncthreads();
  // gated max pool
  const unsigned* xt32 = (const unsigned*)xt;
  int c = lane & 31, half = lane >> 5;
  float mxx = 0.f, mxy = 0.f;
#pragma unroll
  for (int p = 0; p < 16; p++){
    int nn = w * 32 + 2 * p + half;
    unsigned v = xt32[nn * 36 + c];
    float gt = gates[nn];
    mxx = fmaxf(mxx, ulo2f(v) * gt);
    mxy = fmaxf(mxy, uhi2f(v) * gt);
  }
  mxx = fmaxf(mxx, __shfl_xor(mxx, 32, 64));
  mxy = fmaxf(mxy, __shfl_xor(mxy, 32, 64));
  if (half == 0){ red[w][2 * c] = mxx; red[w][2 * c + 1] = mxy; }
  __syncthreads();
  if (tid < 64){
    const float* twW = twW_all + l * 4096;
    const float* twb = twb_all + l * 64;
    int off = (side ? 256 : 64) + l * 64;
    float p = fmaxf(fmaxf(red[0][tid], red[1][tid]), fmaxf(red[2][tid], red[3][tid]));
    float o = twb[tid];
    red[0][tid] = p;
    __syncwarp();
    for (int d = 0; d < 64; d++) o += red[0][d] * twW[d * 64 + tid];
    xfm[g * 384 + off + tid] = fmaxf(o, 0.f);
  }
  if (l == 0){
    // gated next-layer input write (coalesced via LDS)
#pragma unroll
    for (int p = 0; p < 4; p++){
      int row = p * 32 + (tid >> 3);
      int col8 = (tid & 7) * 8;
      float gt = gates[row];
      short8 v = *(const short8*)(xt + row * 72 + col8);
      short8 o;
#pragma unroll
      for (int j = 0; j < 8; j++) o[j] = f2bs(bs2f(v[j]) * gt);
      *(short8*)(xnext + (base + row) * 64 + col8) = o;
    }
    // next-layer a0/a1 from gated x_next: a = g*(x.waA1) + ba1
    const float* wn0p = waA_all + ((side * 2 + 1) * 2 + 0) * 64;
    const float* wn1p = wn0p + 64;
    float wn0[4], wn1[4];
#pragma unroll
    for (int t = 0; t < 4; t++){ wn0[t] = wn0p[t * 16 + m]; wn1[t] = wn1p[t * 16 + m]; }
    float ban0 = ba_all[(side * 2 + 1) * 2 + 0];
    float ban1 = ba_all[(side * 2 + 1) * 2 + 1];
#pragma unroll
    for (int rb = 0; rb < 2; rb++)
#pragma unroll
      for (int r = 0; r < 4; r++){
        float p0 = accA[rb][0][r] * wn0[0] + accA[rb][1][r] * wn0[1] +
                   accA[rb][2][r] * wn0[2] + accA[rb][3][r] * wn0[3];
        float p1 = accA[rb][0][r] * wn1[0] + accA[rb][1][r] * wn1[1] +
                   accA[rb][2][r] * wn1[2] + accA[rb][3][r] * wn1[3];
        p0 += __shfl_xor(p0, 1, 64); p0 += __shfl_xor(p0, 2, 64);
        p0 += __shfl_xor(p0, 4, 64); p0 += __shfl_xor(p0, 8, 64);
        p1 += __shfl_xor(p1, 1, 64); p1 += __shfl_xor(p1, 2, 64);
        p1 += __shfl_xor(p1, 4, 64); p1 += __shfl_xor(p1, 8, 64);
        if (m == 0){
          int row = w * 32 + rb * 16 + q * 4 + r;
          float gr = gates[row];
          a0[base + row] = p0 * gr + ban0;
          a1[base + row] = p1 * gr + ban1;
        }
      }
  }
}

// ---------------- FM head: 4 graphs per block, V streamed once per block ----------------
__global__ __launch_bounds__(384) void k_fm(
    const float* __restrict__ xfm, const float* __restrict__ V,
    const float* __restrict__ fw, const float* __restrict__ bu,
    const float* __restrict__ bi, const float* __restrict__ b0,
    const int* __restrict__ uid, const int* __restrict__ iid,
    float* __restrict__ out){
  __shared__ float xsh[4][384];
  __shared__ float xsq[4][384];
  __shared__ float part[4][384];
  int j = threadIdx.x;
  int g0 = blockIdx.x * 4;
#pragma unroll
  for (int b = 0; b < 4; b++){
    float xv_ = xfm[(g0 + b) * 384 + j];
    xsh[b][j] = xv_;
    xsq[b][j] = xv_ * xv_;
  }
  __syncthreads();
  float xv[4] = {0.f, 0.f, 0.f, 0.f};
  float vv[4] = {0.f, 0.f, 0.f, 0.f};
  for (int k = 0; k < 384; k++){
    float v = V[(size_t)k * 384 + j];
    float v2 = v * v;
#pragma unroll
    for (int b = 0; b < 4; b++){
      xv[b] = fmaf(xsh[b][k], v, xv[b]);
      vv[b] = fmaf(xsq[b][k], v2, vv[b]);
    }
  }
  float fwj = fw[j];
#pragma unroll
  for (int b = 0; b < 4; b++)
    part[b][j] = 0.5f * (xv[b] * xv[b] - vv[b]) + xsh[b][j] * fwj;
  __syncthreads();
  int w = j >> 6, lane = j & 63;
  if (w < 4){
    float s = part[w][lane] + part[w][lane + 64] + part[w][lane + 128] +
              part[w][lane + 192] + part[w][lane + 256] + part[w][lane + 320];
    s = wsum(s);
    if (lane == 0){
      int b = g0 + w;
      out[b] = s + bu[uid[b]] + bi[iid[b]] + b0[0];
    }
  }
}

extern "C" void kernel_launch(void* const* d_in, const int* in_sizes, int n_in,
                              void* d_out, int out_size, void* d_ws, size_t ws_size,
                              hipStream_t stream) {
  const int* uid      = (const int*)d_in[0];
  const int* iid      = (const int*)d_in[1];
  const int* u_nodes  = (const int*)d_in[2];
  const int* i_nodes  = (const int*)d_in[3];
  const int* u_ei     = (const int*)d_in[4];
  const int* i_ei     = (const int*)d_in[5];
  const int* u_et     = (const int*)d_in[6];
  const int* i_et     = (const int*)d_in[7];
  const float* user_emb = (const float*)d_in[10];
  const float* item_emb = (const float*)d_in[11];
  const float* word_emb = (const float*)d_in[12];
  const float* trans_u_W = (const float*)d_in[13];
  const float* trans_u_b = (const float*)d_in[14];
  const float* trans_i_W = (const float*)d_in[15];
  const float* trans_i_b = (const float*)d_in[16];
  const float* trans_w_W = (const float*)d_in[17];
  const float* trans_w_b = (const float*)d_in[18];
  const float* inter_u_W = (const float*)d_in[19];
  const float* inter_u_b = (const float*)d_in[20];
  const float* inter_i_W = (const float*)d_in[21];
  const float* inter_i_b = (const float*)d_in[22];
  const float* conv_u_W  = (const float*)d_in[23];
  const float* conv_u_b  = (const float*)d_in[24];
  const float* conv_u_att= (const float*)d_in[25];
  const float* conv_u_rel= (const float*)d_in[26];
  const float* conv_i_W  = (const float*)d_in[27];
  const float* conv_i_b  = (const float*)d_in[28];
  const float* conv_i_att= (const float*)d_in[29];
  const float* conv_i_rel= (const float*)d_in[30];
  const float* pool_W    = (const float*)d_in[31];
  const float* fm_w      = (const float*)d_in[32];
  const float* fm_V      = (const float*)d_in[33];
  const float* fm_bias_u = (const float*)d_in[34];
  const float* fm_bias_i = (const float*)d_in[35];
  const float* fm_bias   = (const float*)d_in[36];
  float* out = (float*)d_out;
  int n32 = in_sizes[12] / 2;          // packed uints in word table
  int nwords = in_sizes[12] / 64;      // words (HID=64)
  int wconvB = (n32 + 255) / 256;

  // workspace carve-up (ebuf aliases X0 — dead before k_agg0 writes X0)
  char* w = (char*)d_ws;
  short* X0   = (short*)w;          w += (size_t)2 * NN * 64 * 2;   // 32 MB
  short* X1   = (short*)w;          w += (size_t)2 * NN * 64 * 2;   // 32 MB
  short* wtab = (short*)w;          w += (size_t)in_sizes[12] * 2;  // bf16 word table
  int* pedge  = (int*)w;            w += (size_t)2 * NE * 4;
  float* a0   = (float*)w;          w += (size_t)2 * NN * 4;
  float* a1   = (float*)w;          w += (size_t)2 * NN * 4;
  float* wa0  = (float*)w;          w += (size_t)2 * nwords * 4;
  float* wa1  = (float*)w;          w += (size_t)2 * nwords * 4;
  int* cntmat = (int*)w;            w += (size_t)K1B * NBKT * 4;    // 1 MB
  int* rowfin = (int*)w;            w += (size_t)(2 * NN + 256) * 4;
  int* btot   = (int*)w;            w += NBKT * 4;
  int* bbase  = (int*)w;            w += (NBKT + 1) * 4;
  short8* frag = (short8*)w;        w += (size_t)5 * 512 * 16;
  float* waA  = (float*)w;          w += 2 * 2 * 2 * 64 * 4;
  float* ba   = (float*)w;          w += 64;
  float* rtab = (float*)w;          w += 64;
  float* qbuf = (float*)w;          w += (size_t)4 * NB * 64 * 4;
  float* xfm  = (float*)w;          w += (size_t)NB * 384 * 4;
  int* ebuf = (int*)X0;             // 2*NE*4 B = 4 MB, dead before k_agg0 writes X0

  int megaB = K1B + 12 + wconvB + 2 * NB / 4;
  k_mega<<<megaB, 256, 0, stream>>>(wconvB, u_ei, i_ei, cntmat,
                                    word_emb, (unsigned*)wtab, n32,
                                    conv_u_W, conv_i_W, pool_W, conv_u_b, conv_i_b,
                                    conv_u_att, conv_i_att, conv_u_rel, conv_i_rel,
                                    frag, waA, ba, rtab,
                                    uid, iid, user_emb, item_emb,
                                    inter_u_W, inter_u_b, inter_i_W, inter_i_b,
                                    trans_u_W, trans_u_b, trans_i_W, trans_i_b,
                                    xfm, qbuf);
  k_colscan<<<NBKT, 256, 0, stream>>>(cntmat, btot);
  k_bscan<<<1, NBKT, 0, stream>>>(btot, bbase);
  int wgB = (2 * nwords + 31) / 32;
  k_scat<<<K1B + wgB, 256, 0, stream>>>(u_ei, i_ei, u_et, i_et, cntmat, bbase,
                                        ebuf, wtab, nwords, waA, ba, wa0, wa1);
  k_csr<<<NBKT, 256, 0, stream>>>(bbase, ebuf, rowfin, pedge);

  // layer 0: aggregate straight from the word table
  k_agg0<<<2 * NN / 32, 256, 0, stream>>>(rowfin, pedge, wa0, wa1,
                                          u_nodes, i_nodes, nwords, rtab,
                                          wtab, (unsigned*)X0);
  k_gp  <<<2 * NB, 256, 0, stream>>>(0, X0, frag, conv_u_b, conv_i_b, waA, ba,
                                     qbuf, trans_w_W, trans_w_b, xfm, X1, a0, a1);
  // layer 1
  k_agg1<<<2 * NN / 32, 256, 0, stream>>>(rowfin, pedge, a0, a1, rtab,
                                          X1, (unsigned*)X0);
  k_gp  <<<2 * NB, 256, 0, stream>>>(1, X0, frag, conv_u_b, conv_i_b, waA, ba,
                                     qbuf, trans_w_W, trans_w_b, xfm,
                                     nullptr, nullptr, nullptr);

  k_fm<<<NB / 4, 384, 0, stream>>>(xfm, fm_V, fm_w, fm_bias_u, fm_bias_i, fm_bias,
                                   uid, iid, out);
}

// Round 10
// 354.954 us; speedup vs baseline: 1.2359x; 1.0098x over previous
//
#include <hip/hip_runtime.h>
#include <hip/hip_bf16.h>

#define NN 131072   // nodes per side
#define NE 524288   // edges per side
#define NB 1024     // batch (graphs per side)
#define NBKT 512    // dst buckets (512-node ranges); 2NN/NBKT = 512 nodes/bucket
#define K1B 512     // edge-chunk blocks; CHUNK = 2NE/K1B = 2048 edges (8/thread)

typedef __attribute__((ext_vector_type(8))) short short8;   // 8 bf16
typedef __attribute__((ext_vector_type(4))) float f32x4;

__device__ __forceinline__ float wsum(float v){
#pragma unroll
  for (int o = 32; o > 0; o >>= 1) v += __shfl_xor(v, o, 64);
  return v;
}
__device__ __forceinline__ short f2bs(float f){
  __hip_bfloat16 t = __float2bfloat16(f);
  union { __hip_bfloat16 b; short s; } u; u.b = t; return u.s;
}
__device__ __forceinline__ float bs2f(short s){
  return __uint_as_float(((unsigned)(unsigned short)s) << 16);
}
__device__ __forceinline__ float ulo2f(unsigned v){ return __uint_as_float(v << 16); }
__device__ __forceinline__ float uhi2f(unsigned v){ return __uint_as_float(v & 0xFFFF0000u); }
__device__ __forceinline__ unsigned fpack(float x, float y){
  return (unsigned)(unsigned short)f2bs(x) | ((unsigned)(unsigned short)f2bs(y) << 16);
}

// ---------------- mega: K1 bucket-count (LDS hist, no global atomics) | frag | waA/ba/rtab | wconv | prep ----------------
__global__ void k_mega(int wconvB,
                       const int* __restrict__ u_ei, const int* __restrict__ i_ei,
                       int* __restrict__ cntmat,
                       const float* __restrict__ wemb, unsigned* __restrict__ wtab,
                       int n32,
                       const float* __restrict__ cuW, const float* __restrict__ ciW,
                       const float* __restrict__ pW,
                       const float* __restrict__ cub, const float* __restrict__ cib,
                       const float* __restrict__ uatt, const float* __restrict__ iatt,
                       const float* __restrict__ urel, const float* __restrict__ irel,
                       short8* __restrict__ frag, float* __restrict__ waA,
                       float* __restrict__ ba, float* __restrict__ rtab,
                       const int* __restrict__ uid, const int* __restrict__ iid,
                       const float* __restrict__ uemb, const float* __restrict__ iemb,
                       const float* __restrict__ uiW, const float* __restrict__ uib,
                       const float* __restrict__ iiW, const float* __restrict__ iib,
                       const float* __restrict__ utW, const float* __restrict__ utb,
                       const float* __restrict__ itW, const float* __restrict__ itb,
                       float* __restrict__ xfm, float* __restrict__ q){
  int blk = blockIdx.x, tid = threadIdx.x;
  if (blk < K1B){
    // per-chunk bucket histogram in LDS; write matrix row (no global atomics)
    __shared__ int hist[NBKT];
    hist[tid] = 0; hist[tid + 256] = 0;
    __syncthreads();
#pragma unroll
    for (int k = 0; k < 8; k++){
      int ee = blk * 2048 + k * 256 + tid;
      int side = ee >= NE;
      int e = ee - side * NE;
      const int* ei = side ? i_ei : u_ei;
      int dst = ei[NE + e] + side * NN;
      atomicAdd(&hist[dst >> 9], 1);
    }
    __syncthreads();
    cntmat[blk * NBKT + tid] = hist[tid];
    cntmat[blk * NBKT + tid + 256] = hist[tid + 256];
  } else if (blk < K1B + 10){
    int b2 = blk - K1B;
    int mat = b2 >> 1;
    const float* W = mat < 2 ? cuW + mat * 4096 : (mat < 4 ? ciW + (mat - 2) * 4096 : pW);
    int g = (b2 & 1) * 256 + tid;     // [0,512)
    int lane = g & 63, rest = g >> 6;
    int hh = rest & 1, t = rest >> 1;
    int m = lane & 15, qq = lane >> 4;
    short8 v;
#pragma unroll
    for (int j = 0; j < 8; j++)
      v[j] = f2bs(W[(hh * 32 + qq * 8 + j) * 64 + (t * 16 + m)]);
    frag[mat * 512 + g] = v;
  } else if (blk < K1B + 12){
    int side = blk - K1B - 10;
    const float* W    = side ? ciW : cuW;
    const float* bias = side ? cib : cub;
    const float* att  = side ? iatt : uatt;
    const float* rel  = side ? irel : urel;
    int l = tid >> 7, a = (tid >> 6) & 1, kk = tid & 63;
    float s = 0.f;
    for (int c = 0; c < 64; c++) s += W[l * 4096 + kk * 64 + c] * att[l * 192 + a * 64 + c];
    waA[((side * 2 + l) * 2 + a) * 64 + kk] = s;
    if (tid < 4){
      int l2 = tid >> 1, a2 = tid & 1;
      float sb = 0.f;
      for (int c = 0; c < 64; c++) sb += bias[l2 * 64 + c] * att[l2 * 192 + a2 * 64 + c];
      ba[(side * 2 + l2) * 2 + a2] = sb;
    }
    if (tid >= 4 && tid < 12){
      int id = tid - 4, l2 = id >> 2, tt = id & 3;
      float sr = 0.f;
      for (int c = 0; c < 64; c++) sr += rel[l2 * 256 + tt * 64 + c] * att[l2 * 192 + 128 + c];
      rtab[(side * 2 + l2) * 4 + tt] = sr;
    }
  } else if (blk < K1B + 12 + wconvB){
    int id = (blk - K1B - 12) * 256 + tid;
    if (id < n32){
      const float2* src = (const float2*)wemb;
      float2 v = src[id];
      wtab[id] = fpack(v.x, v.y);
    }
  } else {
    int lane = tid & 63, w = tid >> 6;
    int b = (blk - K1B - 12 - wconvB) * 4 + w;   // [0, 2NB)
    int side = b >= NB;
    int lb = b - side * NB;
    const int* ids = side ? iid : uid;
    const float* emb = side ? iemb : uemb;
    const float* interW = side ? iiW : uiW;
    const float* interB = side ? iib : uib;
    const float* transW = side ? itW : utW;
    const float* transB = side ? itb : utb;
    int repOff = side ? 192 : 0;
    float xe = emb[(long)ids[lb] * 64 + lane];
    float o = interB[lane];
#pragma unroll
    for (int k = 0; k < 64; k++) o += __shfl(xe, k, 64) * interW[k * 64 + lane];
    xfm[lb * 384 + repOff + lane] = fmaxf(o, 0.f);
    for (int l = 0; l < 2; l++){
      float t = transB[l * 64 + lane];
#pragma unroll
      for (int k = 0; k < 64; k++) t += __shfl(xe, k, 64) * transW[l * 4096 + k * 64 + lane];
      q[((size_t)(side * 2 + l) * NB + lb) * 64 + lane] = fmaxf(t, 0.f);
    }
  }
}

// column-exclusive-prefix of cntmat (per bucket over chunks) + bucket totals
__global__ void k_colscan(int* __restrict__ cntmat, int* __restrict__ btot){
  __shared__ int sh[256];
  int b = blockIdx.x, t = threadIdx.x;
  int c0 = cntmat[(2 * t) * NBKT + b];
  int c1 = cntmat[(2 * t + 1) * NBKT + b];
  int s = c0 + c1;
  sh[t] = s; __syncthreads();
  for (int off = 1; off < 256; off <<= 1){
    int v = (t >= off) ? sh[t - off] : 0;
    __syncthreads();
    sh[t] += v;
    __syncthreads();
  }
  int incl = sh[t];
  int excl = incl - s;
  cntmat[(2 * t) * NBKT + b] = excl;
  cntmat[(2 * t + 1) * NBKT + b] = excl + c0;
  if (t == 255) btot[b] = incl;
}

// exclusive scan of bucket totals -> bucket bases (+sentinel)
__global__ void k_bscan(const int* __restrict__ btot, int* __restrict__ bbase){
  __shared__ int sh[NBKT];
  int t = threadIdx.x;
  int v = btot[t];
  sh[t] = v; __syncthreads();
  for (int off = 1; off < NBKT; off <<= 1){
    int x = (t >= off) ? sh[t - off] : 0;
    __syncthreads();
    sh[t] += x;
    __syncthreads();
  }
  bbase[t] = sh[t] - v;
  if (t == NBKT - 1) bbase[NBKT] = 2 * NE;
}

// ---------------- scatter edges into bucket runs (LDS slots, no global atomics) | wa tables ----------------
__global__ void k_scat(const int* __restrict__ u_ei, const int* __restrict__ i_ei,
                       const int* __restrict__ u_et, const int* __restrict__ i_et,
                       const int* __restrict__ cntmat, const int* __restrict__ bbase,
                       int* __restrict__ ebuf,
                       const short* __restrict__ wtab, int nwords,
                       const float* __restrict__ waA, const float* __restrict__ ba,
                       float* __restrict__ wa0, float* __restrict__ wa1){
  int blk = blockIdx.x, tid = threadIdx.x;
  if (blk < K1B){
    __shared__ int hist[NBKT];
    __shared__ int mb[NBKT];
    hist[tid] = 0; hist[tid + 256] = 0;
    mb[tid]       = cntmat[blk * NBKT + tid]       + bbase[tid];
    mb[tid + 256] = cntmat[blk * NBKT + tid + 256] + bbase[tid + 256];
    __syncthreads();
#pragma unroll
    for (int k = 0; k < 8; k++){
      int ee = blk * 2048 + k * 256 + tid;
      int side = ee >= NE;
      int e = ee - side * NE;
      const int* ei = side ? i_ei : u_ei;
      const int* et = side ? i_et : u_et;
      int dst = ei[NE + e] + side * NN;
      int src = ei[e] + side * NN;
      int bin = dst >> 9;
      int slot = atomicAdd(&hist[bin], 1);
      ebuf[mb[bin] + slot] = src | (et[e] << 18) | ((dst & 511) << 20);
    }
  } else {
    // wa0/wa1[side][word] = wtab[word] . waA(side,l=0,a) + ba
    int lane = tid & 63, w = tid >> 6;
    int q = lane >> 4, cl = lane & 15;
    int sw0 = ((blk - K1B) * 4 + w) * 8;
    const uint2* wt2 = (const uint2*)wtab;
    for (int it = 0; it < 2; it++){
      int wj = sw0 + it * 4 + q;
      if (wj >= 2 * nwords) continue;
      int side = wj >= nwords;
      int wid = wj - side * nwords;
      const float* A0 = waA + (side * 2 + 0) * 2 * 64;
      const float* A1 = A0 + 64;
      uint2 v = wt2[(long)wid * 16 + cl];
      int d = 4 * cl;
      float p0 = ulo2f(v.x) * A0[d] + uhi2f(v.x) * A0[d + 1] +
                 ulo2f(v.y) * A0[d + 2] + uhi2f(v.y) * A0[d + 3];
      float p1 = ulo2f(v.x) * A1[d] + uhi2f(v.x) * A1[d + 1] +
                 ulo2f(v.y) * A1[d + 2] + uhi2f(v.y) * A1[d + 3];
      p0 += __shfl_xor(p0, 1, 64); p0 += __shfl_xor(p0, 2, 64);
      p0 += __shfl_xor(p0, 4, 64); p0 += __shfl_xor(p0, 8, 64);
      p1 += __shfl_xor(p1, 1, 64); p1 += __shfl_xor(p1, 2, 64);
      p1 += __shfl_xor(p1, 4, 64); p1 += __shfl_xor(p1, 8, 64);
      if (cl == 0){
        wa0[(size_t)side * nwords + wid] = p0 + ba[side * 4 + 0];
        wa1[(size_t)side * nwords + wid] = p1 + ba[side * 4 + 1];
      }
    }
  }
}

// ---------------- per-bucket CSR finalize: counts -> local scan -> rowfin + dst-grouped pedge ----------------
__global__ __launch_bounds__(256) void k_csr(
    const int* __restrict__ bbase, const int* __restrict__ ebuf,
    int* __restrict__ rowfin, int* __restrict__ pedge){
  __shared__ int hist[NBKT];   // 512 node-bins for this bucket; later reused as cursor
  __shared__ int sh[256];
  int b = blockIdx.x, t = threadIdx.x;
  int eb0 = bbase[b], eb1 = bbase[b + 1];
  hist[t] = 0; hist[t + 256] = 0;
  __syncthreads();
  for (int e = eb0 + t; e < eb1; e += 256)
    atomicAdd(&hist[(ebuf[e] >> 20) & 511], 1);
  __syncthreads();
  int c0 = hist[2 * t], c1 = hist[2 * t + 1];
  int s = c0 + c1;
  sh[t] = s; __syncthreads();
  for (int off = 1; off < 256; off <<= 1){
    int v = (t >= off) ? sh[t - off] : 0;
    __syncthreads();
    sh[t] += v;
    __syncthreads();
  }
  int excl = sh[t] - s;
  int nbase = b * 512;
  rowfin[nbase + 2 * t] = eb0 + excl;
  rowfin[nbase + 2 * t + 1] = eb0 + excl + c0;
  hist[2 * t] = excl;            // cursor init (own bins; all reads done above)
  hist[2 * t + 1] = excl + c0;
  __syncthreads();
  for (int e = eb0 + t; e < eb1; e += 256){
    int rec = ebuf[e];
    int bin = (rec >> 20) & 511;
    int p = atomicAdd(&hist[bin], 1);
    pedge[eb0 + p] = rec & 0xFFFFF;   // src | et<<18
  }
  if (b == NBKT - 1 && t == 0) rowfin[2 * NN] = 2 * NE;
}

// ---------------- aggregation: 8-lane groups, uint4 feature slices ----------------
template<int L>
__device__ __forceinline__ void dev_agg(
    const int* __restrict__ rowptr, const int* __restrict__ pedge,
    const float* __restrict__ a0, const float* __restrict__ a1,        // L==1
    const float* __restrict__ wa0, const float* __restrict__ wa1,      // L==0
    const int* __restrict__ u_nodes, const int* __restrict__ i_nodes, int nwords,
    const float* __restrict__ rtab, const short* __restrict__ rows,
    unsigned* __restrict__ xo32){
  int lane = threadIdx.x & 63, w = threadIdx.x >> 6;
  int grp = lane >> 3, cl = lane & 7;
  int n = (blockIdx.x * 4 + w) * 8 + grp;          // node for this 8-lane group
  int side = n >= NN;                               // uniform per wave (NN % 8 == 0)
  const float* rt = rtab + (side * 2 + L) * 4;
  float rt0 = rt[0], rt1 = rt[1], rt2 = rt[2], rt3 = rt[3];
  const int* nodesS = side ? i_nodes : u_nodes;
  const float* wa0S = wa0 + (size_t)side * nwords;
  const float* wa1S = wa1 + (size_t)side * nwords;
  const uint4* h4 = (const uint4*)rows;

  int r0 = rowptr[n], r1 = rowptr[n + 1];          // broadcast loads
  int deg = r1 - r0;
  float a1n;
  if (L == 0) a1n = wa1S[nodesS[n - side * NN]];
  else        a1n = a1[n];

  int pe[8]; int rowv[8]; float av[8]; uint4 hv[8];
#pragma unroll
  for (int j = 0; j < 8; j++)
    pe[j] = (j < deg) ? pedge[r0 + j] : 0;         // 8 independent broadcast loads
#pragma unroll
  for (int j = 0; j < 8; j++){
    int s = pe[j] & 0x3FFFF;
    if (L == 0){
      int wid = 0;
      if (j < deg) wid = nodesS[s - side * NN];
      rowv[j] = wid;
    } else {
      rowv[j] = s;
    }
  }
#pragma unroll
  for (int j = 0; j < 8; j++){
    av[j] = 0.f;
    if (j < deg) av[j] = (L == 0) ? wa0S[rowv[j]] : a0[rowv[j]];
    uint4 z; z.x = 0u; z.y = 0u; z.z = 0u; z.w = 0u;
    hv[j] = z;
    if (j < deg) hv[j] = h4[(long)rowv[j] * 8 + cl];   // 16B feature slice
  }
  float ax0 = 0.f, ay0 = 0.f, ax1 = 0.f, ay1 = 0.f;
  float ax2 = 0.f, ay2 = 0.f, ax3 = 0.f, ay3 = 0.f, den = 0.f;
#pragma unroll
  for (int j = 0; j < 8; j++){
    int et = (pe[j] >> 18) & 3;
    float rr = (et & 2) ? ((et & 1) ? rt3 : rt2) : ((et & 1) ? rt1 : rt0);
    float v = av[j] + a1n + rr;
    v = (v > 0.f) ? v : 0.2f * v;
    float ex = (j < deg) ? __expf(v) : 0.f;
    ax0 += ex * ulo2f(hv[j].x); ay0 += ex * uhi2f(hv[j].x);
    ax1 += ex * ulo2f(hv[j].y); ay1 += ex * uhi2f(hv[j].y);
    ax2 += ex * ulo2f(hv[j].z); ay2 += ex * uhi2f(hv[j].z);
    ax3 += ex * ulo2f(hv[j].w); ay3 += ex * uhi2f(hv[j].w);
    den += ex;
  }
  // rare tail: deg > 8 (~2% of nodes at Poisson(4))
  for (int e = r0 + 8; e < r1; ++e){
    int pe2 = pedge[e];
    int s = pe2 & 0x3FFFF;
    int et = (pe2 >> 18) & 3;
    float rr = (et & 2) ? ((et & 1) ? rt3 : rt2) : ((et & 1) ? rt1 : rt0);
    float avv; long row;
    if (L == 0){ int wid = nodesS[s - side * NN]; avv = wa0S[wid]; row = wid; }
    else       { avv = a0[s]; row = s; }
    float v = avv + a1n + rr;
    v = (v > 0.f) ? v : 0.2f * v;
    float ex = __expf(v);
    uint4 hvv = h4[row * 8 + cl];
    ax0 += ex * ulo2f(hvv.x); ay0 += ex * uhi2f(hvv.x);
    ax1 += ex * ulo2f(hvv.y); ay1 += ex * uhi2f(hvv.y);
    ax2 += ex * ulo2f(hvv.z); ay2 += ex * uhi2f(hvv.z);
    ax3 += ex * ulo2f(hvv.w); ay3 += ex * uhi2f(hvv.w);
    den += ex;
  }
  float inv = 1.f / (den + 1e-16f);
  uint4 o;
  o.x = fpack(ax0 * inv, ay0 * inv);
  o.y = fpack(ax1 * inv, ay1 * inv);
  o.z = fpack(ax2 * inv, ay2 * inv);
  o.w = fpack(ax3 * inv, ay3 * inv);
  ((uint4*)xo32)[(long)n * 8 + cl] = o;            // coalesced: 1KB per wave
}

__global__ __launch_bounds__(256) void k_agg0(
    const int* __restrict__ rowptr, const int* __restrict__ pedge,
    const float* __restrict__ wa0, const float* __restrict__ wa1,
    const int* __restrict__ u_nodes, const int* __restrict__ i_nodes, int nwords,
    const float* __restrict__ rtab, const short* __restrict__ wtab,
    unsigned* __restrict__ xo32){
  dev_agg<0>(rowptr, pedge, nullptr, nullptr, wa0, wa1, u_nodes, i_nodes, nwords,
             rtab, wtab, xo32);
}

__global__ __launch_bounds__(256) void k_agg1(
    const int* __restrict__ rowptr, const int* __restrict__ pedge,
    const float* __restrict__ a0, const float* __restrict__ a1,
    const float* __restrict__ rtab, const short* __restrict__ x,
    unsigned* __restrict__ xo32){
  dev_agg<1>(rowptr, pedge, a0, a1, nullptr, nullptr, nullptr, nullptr, 0,
             rtab, x, xo32);
}

// ---------------- fused post: x=relu(xagg@W+b); gates; gmp; trans_w; gated X1 + a0/a1 ----------------
__global__ __launch_bounds__(256) void k_gp(
    int l, const short* __restrict__ xagg, const short8* __restrict__ frag,
    const float* __restrict__ cub, const float* __restrict__ cib,
    const float* __restrict__ waA_all, const float* __restrict__ ba_all,
    const float* __restrict__ qbuf, const float* __restrict__ twW_all,
    const float* __restrict__ twb_all, float* __restrict__ xfm,
    short* __restrict__ xnext, float* __restrict__ a0, float* __restrict__ a1){
  __shared__ short xt[128 * 72];       // padded rows (72 shorts) for bank spread
  __shared__ float gates[128];
  __shared__ float red[4][64];
  int b = blockIdx.x;                  // [0, 2NB)
  int side = b >= NB;
  int g = b - side * NB;
  long base = (long)side * NN + (long)g * 128;
  int tid = threadIdx.x, lane = tid & 63, w = tid >> 6;
  int m = lane & 15, q = lane >> 4;
  // stage A: conv GEMM
  const short8* wfrag = frag + (side * 2 + l) * 512;
  const float* bias = (side ? cib : cub) + l * 64;
  short8 Bf[4][2];
#pragma unroll
  for (int t = 0; t < 4; t++)
#pragma unroll
    for (int hh = 0; hh < 2; hh++)
      Bf[t][hh] = wfrag[(t * 2 + hh) * 64 + lane];
  float bs[4];
#pragma unroll
  for (int t = 0; t < 4; t++) bs[t] = bias[t * 16 + m];
  f32x4 accA[2][4];
#pragma unroll
  for (int rb = 0; rb < 2; rb++){
    long n0 = base + w * 32 + rb * 16;
    const short8* xr = (const short8*)(xagg + (n0 + m) * 64);
    short8 A0 = xr[q];
    short8 A1 = xr[q + 4];
#pragma unroll
    for (int t = 0; t < 4; t++){
      f32x4 acc = (f32x4){bs[t], bs[t], bs[t], bs[t]};
      acc = __builtin_amdgcn_mfma_f32_16x16x32_bf16(A0, Bf[t][0], acc, 0, 0, 0);
      acc = __builtin_amdgcn_mfma_f32_16x16x32_bf16(A1, Bf[t][1], acc, 0, 0, 0);
#pragma unroll
      for (int r = 0; r < 4; r++) acc[r] = fmaxf(acc[r], 0.f);
      accA[rb][t] = acc;
#pragma unroll
      for (int r = 0; r < 4; r++)
        xt[(w * 32 + rb * 16 + q * 4 + r) * 72 + t * 16 + m] = f2bs(acc[r]);
    }
  }
  __syncthreads();
  // stage B: pool GEMM from LDS -> gates
  const short8* pfrag = frag + 4 * 512;
  const float* qv_ = qbuf + ((size_t)(side * 2 + l) * NB + g) * 64;
  short8 Pf[4][2];
#pragma unroll
  for (int t = 0; t < 4; t++)
#pragma unroll
    for (int hh = 0; hh < 2; hh++)
      Pf[t][hh] = pfrag[(t * 2 + hh) * 64 + lane];
  float qv[4];
#pragma unroll
  for (int t = 0; t < 4; t++) qv[t] = qv_[t * 16 + m];
#pragma unroll
  for (int rb = 0; rb < 2; rb++){
    int rowb = w * 32 + rb * 16;
    short8 A0 = *(const short8*)(xt + (rowb + m) * 72 + q * 8);
    short8 A1 = *(const short8*)(xt + (rowb + m) * 72 + 32 + q * 8);
    f32x4 accp[4];
#pragma unroll
    for (int t = 0; t < 4; t++){
      accp[t] = (f32x4){0.f, 0.f, 0.f, 0.f};
      accp[t] = __builtin_amdgcn_mfma_f32_16x16x32_bf16(A0, Pf[t][0], accp[t], 0, 0, 0);
      accp[t] = __builtin_amdgcn_mfma_f32_16x16x32_bf16(A1, Pf[t][1], accp[t], 0, 0, 0);
    }
#pragma unroll
    for (int r = 0; r < 4; r++){
      float p = accp[0][r] * qv[0] + accp[1][r] * qv[1] +
                accp[2][r] * qv[2] + accp[3][r] * qv[3];
      p += __shfl_xor(p, 1, 64); p += __shfl_xor(p, 2, 64);
      p += __shfl_xor(p, 4, 64); p += __shfl_xor(p, 8, 64);
      if (m == 0)
        gates[rowb + q * 4 + r] = 1.f / (1.f + __expf(-p * 0.125f));
    }
  }
  __syncthreads();
  // gated max pool
  const unsigned* xt32 = (const unsigned*)xt;
  int c = lane & 31, half = lane >> 5;
  float mxx = 0.f, mxy = 0.f;
#pragma unroll
  for (int p = 0; p < 16; p++){
    int nn = w * 32 + 2 * p + half;
    unsigned v = xt32[nn * 36 + c];
    float gt = gates[nn];
    mxx = fmaxf(mxx, ulo2f(v) * gt);
    mxy = fmaxf(mxy, uhi2f(v) * gt);
  }
  mxx = fmaxf(mxx, __shfl_xor(mxx, 32, 64));
  mxy = fmaxf(mxy, __shfl_xor(mxy, 32, 64));
  if (half == 0){ red[w][2 * c] = mxx; red[w][2 * c + 1] = mxy; }
  __syncthreads();
  if (tid < 64){
    const float* twW = twW_all + l * 4096;
    const float* twb = twb_all + l * 64;
    int off = (side ? 256 : 64) + l * 64;
    float p = fmaxf(fmaxf(red[0][tid], red[1][tid]), fmaxf(red[2][tid], red[3][tid]));
    float o = twb[tid];
    red[0][tid] = p;
    __syncwarp();
    for (int d = 0; d < 64; d++) o += red[0][d] * twW[d * 64 + tid];
    xfm[g * 384 + off + tid] = fmaxf(o, 0.f);
  }
  if (l == 0){
    // gated next-layer input write (coalesced via LDS)
#pragma unroll
    for (int p = 0; p < 4; p++){
      int row = p * 32 + (tid >> 3);
      int col8 = (tid & 7) * 8;
      float gt = gates[row];
      short8 v = *(const short8*)(xt + row * 72 + col8);
      short8 o;
#pragma unroll
      for (int j = 0; j < 8; j++) o[j] = f2bs(bs2f(v[j]) * gt);
      *(short8*)(xnext + (base + row) * 64 + col8) = o;
    }
    // next-layer a0/a1 from gated x_next: a = g*(x.waA1) + ba1
    const float* wn0p = waA_all + ((side * 2 + 1) * 2 + 0) * 64;
    const float* wn1p = wn0p + 64;
    float wn0[4], wn1[4];
#pragma unroll
    for (int t = 0; t < 4; t++){ wn0[t] = wn0p[t * 16 + m]; wn1[t] = wn1p[t * 16 + m]; }
    float ban0 = ba_all[(side * 2 + 1) * 2 + 0];
    float ban1 = ba_all[(side * 2 + 1) * 2 + 1];
#pragma unroll
    for (int rb = 0; rb < 2; rb++)
#pragma unroll
      for (int r = 0; r < 4; r++){
        float p0 = accA[rb][0][r] * wn0[0] + accA[rb][1][r] * wn0[1] +
                   accA[rb][2][r] * wn0[2] + accA[rb][3][r] * wn0[3];
        float p1 = accA[rb][0][r] * wn1[0] + accA[rb][1][r] * wn1[1] +
                   accA[rb][2][r] * wn1[2] + accA[rb][3][r] * wn1[3];
        p0 += __shfl_xor(p0, 1, 64); p0 += __shfl_xor(p0, 2, 64);
        p0 += __shfl_xor(p0, 4, 64); p0 += __shfl_xor(p0, 8, 64);
        p1 += __shfl_xor(p1, 1, 64); p1 += __shfl_xor(p1, 2, 64);
        p1 += __shfl_xor(p1, 4, 64); p1 += __shfl_xor(p1, 8, 64);
        if (m == 0){
          int row = w * 32 + rb * 16 + q * 4 + r;
          float gr = gates[row];
          a0[base + row] = p0 * gr + ban0;
          a1[base + row] = p1 * gr + ban1;
        }
      }
  }
}

// ---------------- FM main: k-split partial xv/vv (4 chunks of 96) ----------------
__global__ __launch_bounds__(384) void k_fm2(
    const float* __restrict__ xfm, const float* __restrict__ V,
    float* __restrict__ xvp, float* __restrict__ vvp){
  __shared__ float xsh[4][96];
  __shared__ float xsq[4][96];
  int j = threadIdx.x;
  int bc = blockIdx.x;
  int c = bc & 3;                   // k-chunk
  int g0 = (bc >> 2) * 4;           // 4 graphs per block
  int k0 = c * 96;
  {
    int b = j / 96, kk = j - b * 96;
    float xv_ = xfm[(g0 + b) * 384 + k0 + kk];
    xsh[b][kk] = xv_;
    xsq[b][kk] = xv_ * xv_;
  }
  __syncthreads();
  float xv[4] = {0.f, 0.f, 0.f, 0.f};
  float vv[4] = {0.f, 0.f, 0.f, 0.f};
  for (int k = 0; k < 96; k++){
    float v = V[(size_t)(k0 + k) * 384 + j];
    float v2 = v * v;
#pragma unroll
    for (int b = 0; b < 4; b++){
      xv[b] = fmaf(xsh[b][k], v, xv[b]);
      vv[b] = fmaf(xsq[b][k], v2, vv[b]);
    }
  }
#pragma unroll
  for (int b = 0; b < 4; b++){
    size_t o = ((size_t)c * NB + g0 + b) * 384 + j;
    xvp[o] = xv[b];
    vvp[o] = vv[b];
  }
}

// ---------------- FM epilogue: combine partials, quadratic, reduce, biases ----------------
__global__ __launch_bounds__(384) void k_fm3(
    const float* __restrict__ xfm, const float* __restrict__ xvp,
    const float* __restrict__ vvp, const float* __restrict__ fw,
    const float* __restrict__ bu, const float* __restrict__ bi,
    const float* __restrict__ b0,
    const int* __restrict__ uid, const int* __restrict__ iid,
    float* __restrict__ out){
  __shared__ float part[4][384];
  int j = threadIdx.x;
  int g0 = blockIdx.x * 4;
  float fwj = fw[j];
  const size_t CS = (size_t)NB * 384;
#pragma unroll
  for (int b = 0; b < 4; b++){
    size_t gi = (size_t)(g0 + b) * 384 + j;
    float xv = xvp[gi] + xvp[CS + gi] + xvp[2 * CS + gi] + xvp[3 * CS + gi];
    float vv = vvp[gi] + vvp[CS + gi] + vvp[2 * CS + gi] + vvp[3 * CS + gi];
    float x = xfm[gi];
    part[b][j] = 0.5f * (xv * xv - vv) + x * fwj;
  }
  __syncthreads();
  int w = j >> 6, lane = j & 63;
  if (w < 4){
    float s = part[w][lane] + part[w][lane + 64] + part[w][lane + 128] +
              part[w][lane + 192] + part[w][lane + 256] + part[w][lane + 320];
    s = wsum(s);
    if (lane == 0){
      int b = g0 + w;
      out[b] = s + bu[uid[b]] + bi[iid[b]] + b0[0];
    }
  }
}

extern "C" void kernel_launch(void* const* d_in, const int* in_sizes, int n_in,
                              void* d_out, int out_size, void* d_ws, size_t ws_size,
                              hipStream_t stream) {
  const int* uid      = (const int*)d_in[0];
  const int* iid      = (const int*)d_in[1];
  const int* u_nodes  = (const int*)d_in[2];
  const int* i_nodes  = (const int*)d_in[3];
  const int* u_ei     = (const int*)d_in[4];
  const int* i_ei     = (const int*)d_in[5];
  const int* u_et     = (const int*)d_in[6];
  const int* i_et     = (const int*)d_in[7];
  const float* user_emb = (const float*)d_in[10];
  const float* item_emb = (const float*)d_in[11];
  const float* word_emb = (const float*)d_in[12];
  const float* trans_u_W = (const float*)d_in[13];
  const float* trans_u_b = (const float*)d_in[14];
  const float* trans_i_W = (const float*)d_in[15];
  const float* trans_i_b = (const float*)d_in[16];
  const float* trans_w_W = (const float*)d_in[17];
  const float* trans_w_b = (const float*)d_in[18];
  const float* inter_u_W = (const float*)d_in[19];
  const float* inter_u_b = (const float*)d_in[20];
  const float* inter_i_W = (const float*)d_in[21];
  const float* inter_i_b = (const float*)d_in[22];
  const float* conv_u_W  = (const float*)d_in[23];
  const float* conv_u_b  = (const float*)d_in[24];
  const float* conv_u_att= (const float*)d_in[25];
  const float* conv_u_rel= (const float*)d_in[26];
  const float* conv_i_W  = (const float*)d_in[27];
  const float* conv_i_b  = (const float*)d_in[28];
  const float* conv_i_att= (const float*)d_in[29];
  const float* conv_i_rel= (const float*)d_in[30];
  const float* pool_W    = (const float*)d_in[31];
  const float* fm_w      = (const float*)d_in[32];
  const float* fm_V      = (const float*)d_in[33];
  const float* fm_bias_u = (const float*)d_in[34];
  const float* fm_bias_i = (const float*)d_in[35];
  const float* fm_bias   = (const float*)d_in[36];
  float* out = (float*)d_out;
  int n32 = in_sizes[12] / 2;          // packed uints in word table
  int nwords = in_sizes[12] / 64;      // words (HID=64)
  int wconvB = (n32 + 255) / 256;

  // workspace carve-up (ebuf + xvp/vvp alias X0 — dead in their live ranges)
  char* w = (char*)d_ws;
  short* X0   = (short*)w;          w += (size_t)2 * NN * 64 * 2;   // 32 MB
  short* X1   = (short*)w;          w += (size_t)2 * NN * 64 * 2;   // 32 MB
  short* wtab = (short*)w;          w += (size_t)in_sizes[12] * 2;  // bf16 word table
  int* pedge  = (int*)w;            w += (size_t)2 * NE * 4;
  float* a0   = (float*)w;          w += (size_t)2 * NN * 4;
  float* a1   = (float*)w;          w += (size_t)2 * NN * 4;
  float* wa0  = (float*)w;          w += (size_t)2 * nwords * 4;
  float* wa1  = (float*)w;          w += (size_t)2 * nwords * 4;
  int* cntmat = (int*)w;            w += (size_t)K1B * NBKT * 4;    // 1 MB
  int* rowfin = (int*)w;            w += (size_t)(2 * NN + 256) * 4;
  int* btot   = (int*)w;            w += NBKT * 4;
  int* bbase  = (int*)w;            w += (NBKT + 1) * 4;
  short8* frag = (short8*)w;        w += (size_t)5 * 512 * 16;
  float* waA  = (float*)w;          w += 2 * 2 * 2 * 64 * 4;
  float* ba   = (float*)w;          w += 64;
  float* rtab = (float*)w;          w += 64;
  float* qbuf = (float*)w;          w += (size_t)4 * NB * 64 * 4;
  float* xfm  = (float*)w;          w += (size_t)NB * 384 * 4;
  int* ebuf = (int*)X0;             // 4 MB, dead before k_agg0 writes X0
  float* xvp = (float*)X0;          // 6 MB, live only after k_gp<1> read X0
  float* vvp = xvp + (size_t)4 * NB * 384;   // +6 MB (still inside X0's 32 MB)

  int megaB = K1B + 12 + wconvB + 2 * NB / 4;
  k_mega<<<megaB, 256, 0, stream>>>(wconvB, u_ei, i_ei, cntmat,
                                    word_emb, (unsigned*)wtab, n32,
                                    conv_u_W, conv_i_W, pool_W, conv_u_b, conv_i_b,
                                    conv_u_att, conv_i_att, conv_u_rel, conv_i_rel,
                                    frag, waA, ba, rtab,
                                    uid, iid, user_emb, item_emb,
                                    inter_u_W, inter_u_b, inter_i_W, inter_i_b,
                                    trans_u_W, trans_u_b, trans_i_W, trans_i_b,
                                    xfm, qbuf);
  k_colscan<<<NBKT, 256, 0, stream>>>(cntmat, btot);
  k_bscan<<<1, NBKT, 0, stream>>>(btot, bbase);
  int wgB = (2 * nwords + 31) / 32;
  k_scat<<<K1B + wgB, 256, 0, stream>>>(u_ei, i_ei, u_et, i_et, cntmat, bbase,
                                        ebuf, wtab, nwords, waA, ba, wa0, wa1);
  k_csr<<<NBKT, 256, 0, stream>>>(bbase, ebuf, rowfin, pedge);

  // layer 0: aggregate straight from the word table
  k_agg0<<<2 * NN / 32, 256, 0, stream>>>(rowfin, pedge, wa0, wa1,
                                          u_nodes, i_nodes, nwords, rtab,
                                          wtab, (unsigned*)X0);
  k_gp  <<<2 * NB, 256, 0, stream>>>(0, X0, frag, conv_u_b, conv_i_b, waA, ba,
                                     qbuf, trans_w_W, trans_w_b, xfm, X1, a0, a1);
  // layer 1
  k_agg1<<<2 * NN / 32, 256, 0, stream>>>(rowfin, pedge, a0, a1, rtab,
                                          X1, (unsigned*)X0);
  k_gp  <<<2 * NB, 256, 0, stream>>>(1, X0, frag, conv_u_b, conv_i_b, waA, ba,
                                     qbuf, trans_w_W, trans_w_b, xfm,
                                     nullptr, nullptr, nullptr);

  // FM head: k-split main + epilogue (xvp/vvp alias X0, dead after k_gp<1>)
  k_fm2<<<NB, 384, 0, stream>>>(xfm, fm_V, xvp, vvp);
  k_fm3<<<NB / 4, 384, 0, stream>>>(xfm, xvp, vvp, fm_w, fm_bias_u, fm_bias_i,
                                    fm_bias, uid, iid, out);
}

// Round 11
// 350.835 us; speedup vs baseline: 1.2505x; 1.0117x over previous
//
#include <hip/hip_runtime.h>
#include <hip/hip_bf16.h>

#define NN 131072   // nodes per side
#define NE 524288   // edges per side
#define NB 1024     // batch (graphs per side)
#define NBKT 512    // dst buckets (512-node ranges); 2NN/NBKT = 512 nodes/bucket
#define K1B 512     // edge-chunk blocks; CHUNK = 2NE/K1B = 2048 edges (8/thread)

typedef __attribute__((ext_vector_type(8))) short short8;   // 8 bf16
typedef __attribute__((ext_vector_type(4))) float f32x4;

__device__ __forceinline__ float wsum(float v){
#pragma unroll
  for (int o = 32; o > 0; o >>= 1) v += __shfl_xor(v, o, 64);
  return v;
}
__device__ __forceinline__ short f2bs(float f){
  __hip_bfloat16 t = __float2bfloat16(f);
  union { __hip_bfloat16 b; short s; } u; u.b = t; return u.s;
}
__device__ __forceinline__ float bs2f(short s){
  return __uint_as_float(((unsigned)(unsigned short)s) << 16);
}
__device__ __forceinline__ float ulo2f(unsigned v){ return __uint_as_float(v << 16); }
__device__ __forceinline__ float uhi2f(unsigned v){ return __uint_as_float(v & 0xFFFF0000u); }
__device__ __forceinline__ unsigned fpack(float x, float y){
  return (unsigned)(unsigned short)f2bs(x) | ((unsigned)(unsigned short)f2bs(y) << 16);
}

// ---------------- mega: K1 bucket-count (LDS hist, no global atomics) | frag | waA/ba/rtab | wconv | prep ----------------
__global__ void k_mega(int wconvB,
                       const int* __restrict__ u_ei, const int* __restrict__ i_ei,
                       int* __restrict__ cntmat,
                       const float* __restrict__ wemb, unsigned* __restrict__ wtab,
                       int n32,
                       const float* __restrict__ cuW, const float* __restrict__ ciW,
                       const float* __restrict__ pW,
                       const float* __restrict__ cub, const float* __restrict__ cib,
                       const float* __restrict__ uatt, const float* __restrict__ iatt,
                       const float* __restrict__ urel, const float* __restrict__ irel,
                       short8* __restrict__ frag, float* __restrict__ waA,
                       float* __restrict__ ba, float* __restrict__ rtab,
                       const int* __restrict__ uid, const int* __restrict__ iid,
                       const float* __restrict__ uemb, const float* __restrict__ iemb,
                       const float* __restrict__ uiW, const float* __restrict__ uib,
                       const float* __restrict__ iiW, const float* __restrict__ iib,
                       const float* __restrict__ utW, const float* __restrict__ utb,
                       const float* __restrict__ itW, const float* __restrict__ itb,
                       float* __restrict__ xfm, float* __restrict__ q){
  int blk = blockIdx.x, tid = threadIdx.x;
  if (blk < K1B){
    // per-chunk bucket histogram in LDS; write matrix row (no global atomics)
    __shared__ int hist[NBKT];
    hist[tid] = 0; hist[tid + 256] = 0;
    __syncthreads();
#pragma unroll
    for (int k = 0; k < 8; k++){
      int ee = blk * 2048 + k * 256 + tid;
      int side = ee >= NE;
      int e = ee - side * NE;
      const int* ei = side ? i_ei : u_ei;
      int dst = ei[NE + e] + side * NN;
      atomicAdd(&hist[dst >> 9], 1);
    }
    __syncthreads();
    cntmat[blk * NBKT + tid] = hist[tid];
    cntmat[blk * NBKT + tid + 256] = hist[tid + 256];
  } else if (blk < K1B + 10){
    int b2 = blk - K1B;
    int mat = b2 >> 1;
    const float* W = mat < 2 ? cuW + mat * 4096 : (mat < 4 ? ciW + (mat - 2) * 4096 : pW);
    int g = (b2 & 1) * 256 + tid;     // [0,512)
    int lane = g & 63, rest = g >> 6;
    int hh = rest & 1, t = rest >> 1;
    int m = lane & 15, qq = lane >> 4;
    short8 v;
#pragma unroll
    for (int j = 0; j < 8; j++)
      v[j] = f2bs(W[(hh * 32 + qq * 8 + j) * 64 + (t * 16 + m)]);
    frag[mat * 512 + g] = v;
  } else if (blk < K1B + 12){
    int side = blk - K1B - 10;
    const float* W    = side ? ciW : cuW;
    const float* bias = side ? cib : cub;
    const float* att  = side ? iatt : uatt;
    const float* rel  = side ? irel : urel;
    int l = tid >> 7, a = (tid >> 6) & 1, kk = tid & 63;
    float s = 0.f;
    for (int c = 0; c < 64; c++) s += W[l * 4096 + kk * 64 + c] * att[l * 192 + a * 64 + c];
    waA[((side * 2 + l) * 2 + a) * 64 + kk] = s;
    if (tid < 4){
      int l2 = tid >> 1, a2 = tid & 1;
      float sb = 0.f;
      for (int c = 0; c < 64; c++) sb += bias[l2 * 64 + c] * att[l2 * 192 + a2 * 64 + c];
      ba[(side * 2 + l2) * 2 + a2] = sb;
    }
    if (tid >= 4 && tid < 12){
      int id = tid - 4, l2 = id >> 2, tt = id & 3;
      float sr = 0.f;
      for (int c = 0; c < 64; c++) sr += rel[l2 * 256 + tt * 64 + c] * att[l2 * 192 + 128 + c];
      rtab[(side * 2 + l2) * 4 + tt] = sr;
    }
  } else if (blk < K1B + 12 + wconvB){
    int id = (blk - K1B - 12) * 256 + tid;
    if (id < n32){
      const float2* src = (const float2*)wemb;
      float2 v = src[id];
      wtab[id] = fpack(v.x, v.y);
    }
  } else {
    int lane = tid & 63, w = tid >> 6;
    int b = (blk - K1B - 12 - wconvB) * 4 + w;   // [0, 2NB)
    int side = b >= NB;
    int lb = b - side * NB;
    const int* ids = side ? iid : uid;
    const float* emb = side ? iemb : uemb;
    const float* interW = side ? iiW : uiW;
    const float* interB = side ? iib : uib;
    const float* transW = side ? itW : utW;
    const float* transB = side ? itb : utb;
    int repOff = side ? 192 : 0;
    float xe = emb[(long)ids[lb] * 64 + lane];
    float o = interB[lane];
#pragma unroll
    for (int k = 0; k < 64; k++) o += __shfl(xe, k, 64) * interW[k * 64 + lane];
    xfm[lb * 384 + repOff + lane] = fmaxf(o, 0.f);
    for (int l = 0; l < 2; l++){
      float t = transB[l * 64 + lane];
#pragma unroll
      for (int k = 0; k < 64; k++) t += __shfl(xe, k, 64) * transW[l * 4096 + k * 64 + lane];
      q[((size_t)(side * 2 + l) * NB + lb) * 64 + lane] = fmaxf(t, 0.f);
    }
  }
}

// column-exclusive-prefix of cntmat (per bucket over chunks) + bucket totals
__global__ void k_colscan(int* __restrict__ cntmat, int* __restrict__ btot){
  __shared__ int sh[256];
  int b = blockIdx.x, t = threadIdx.x;
  int c0 = cntmat[(2 * t) * NBKT + b];
  int c1 = cntmat[(2 * t + 1) * NBKT + b];
  int s = c0 + c1;
  sh[t] = s; __syncthreads();
  for (int off = 1; off < 256; off <<= 1){
    int v = (t >= off) ? sh[t - off] : 0;
    __syncthreads();
    sh[t] += v;
    __syncthreads();
  }
  int incl = sh[t];
  int excl = incl - s;
  cntmat[(2 * t) * NBKT + b] = excl;
  cntmat[(2 * t + 1) * NBKT + b] = excl + c0;
  if (t == 255) btot[b] = incl;
}

// exclusive scan of bucket totals -> bucket bases (+sentinel)
__global__ void k_bscan(const int* __restrict__ btot, int* __restrict__ bbase){
  __shared__ int sh[NBKT];
  int t = threadIdx.x;
  int v = btot[t];
  sh[t] = v; __syncthreads();
  for (int off = 1; off < NBKT; off <<= 1){
    int x = (t >= off) ? sh[t - off] : 0;
    __syncthreads();
    sh[t] += x;
    __syncthreads();
  }
  bbase[t] = sh[t] - v;
  if (t == NBKT - 1) bbase[NBKT] = 2 * NE;
}

// ---------------- scatter edges into bucket runs (LDS slots, no global atomics) | wa tables ----------------
__global__ void k_scat(const int* __restrict__ u_ei, const int* __restrict__ i_ei,
                       const int* __restrict__ u_et, const int* __restrict__ i_et,
                       const int* __restrict__ cntmat, const int* __restrict__ bbase,
                       int* __restrict__ ebuf,
                       const short* __restrict__ wtab, int nwords,
                       const float* __restrict__ waA, const float* __restrict__ ba,
                       float* __restrict__ wa0, float* __restrict__ wa1){
  int blk = blockIdx.x, tid = threadIdx.x;
  if (blk < K1B){
    __shared__ int hist[NBKT];
    __shared__ int mb[NBKT];
    hist[tid] = 0; hist[tid + 256] = 0;
    mb[tid]       = cntmat[blk * NBKT + tid]       + bbase[tid];
    mb[tid + 256] = cntmat[blk * NBKT + tid + 256] + bbase[tid + 256];
    __syncthreads();
#pragma unroll
    for (int k = 0; k < 8; k++){
      int ee = blk * 2048 + k * 256 + tid;
      int side = ee >= NE;
      int e = ee - side * NE;
      const int* ei = side ? i_ei : u_ei;
      const int* et = side ? i_et : u_et;
      int dst = ei[NE + e] + side * NN;
      int src = ei[e] + side * NN;
      int bin = dst >> 9;
      int slot = atomicAdd(&hist[bin], 1);
      ebuf[mb[bin] + slot] = src | (et[e] << 18) | ((dst & 511) << 20);
    }
  } else {
    // wa0/wa1[side][word] = wtab[word] . waA(side,l=0,a) + ba
    int lane = tid & 63, w = tid >> 6;
    int q = lane >> 4, cl = lane & 15;
    int sw0 = ((blk - K1B) * 4 + w) * 8;
    const uint2* wt2 = (const uint2*)wtab;
    for (int it = 0; it < 2; it++){
      int wj = sw0 + it * 4 + q;
      if (wj >= 2 * nwords) continue;
      int side = wj >= nwords;
      int wid = wj - side * nwords;
      const float* A0 = waA + (side * 2 + 0) * 2 * 64;
      const float* A1 = A0 + 64;
      uint2 v = wt2[(long)wid * 16 + cl];
      int d = 4 * cl;
      float p0 = ulo2f(v.x) * A0[d] + uhi2f(v.x) * A0[d + 1] +
                 ulo2f(v.y) * A0[d + 2] + uhi2f(v.y) * A0[d + 3];
      float p1 = ulo2f(v.x) * A1[d] + uhi2f(v.x) * A1[d + 1] +
                 ulo2f(v.y) * A1[d + 2] + uhi2f(v.y) * A1[d + 3];
      p0 += __shfl_xor(p0, 1, 64); p0 += __shfl_xor(p0, 2, 64);
      p0 += __shfl_xor(p0, 4, 64); p0 += __shfl_xor(p0, 8, 64);
      p1 += __shfl_xor(p1, 1, 64); p1 += __shfl_xor(p1, 2, 64);
      p1 += __shfl_xor(p1, 4, 64); p1 += __shfl_xor(p1, 8, 64);
      if (cl == 0){
        wa0[(size_t)side * nwords + wid] = p0 + ba[side * 4 + 0];
        wa1[(size_t)side * nwords + wid] = p1 + ba[side * 4 + 1];
      }
    }
  }
}

// ---------------- per-bucket CSR finalize: counts -> local scan -> rowfin + dst-grouped pedge ----------------
__global__ __launch_bounds__(256) void k_csr(
    const int* __restrict__ bbase, const int* __restrict__ ebuf,
    int* __restrict__ rowfin, int* __restrict__ pedge){
  __shared__ int hist[NBKT];   // 512 node-bins for this bucket; later reused as cursor
  __shared__ int sh[256];
  int b = blockIdx.x, t = threadIdx.x;
  int eb0 = bbase[b], eb1 = bbase[b + 1];
  hist[t] = 0; hist[t + 256] = 0;
  __syncthreads();
  for (int e = eb0 + t; e < eb1; e += 256)
    atomicAdd(&hist[(ebuf[e] >> 20) & 511], 1);
  __syncthreads();
  int c0 = hist[2 * t], c1 = hist[2 * t + 1];
  int s = c0 + c1;
  sh[t] = s; __syncthreads();
  for (int off = 1; off < 256; off <<= 1){
    int v = (t >= off) ? sh[t - off] : 0;
    __syncthreads();
    sh[t] += v;
    __syncthreads();
  }
  int excl = sh[t] - s;
  int nbase = b * 512;
  rowfin[nbase + 2 * t] = eb0 + excl;
  rowfin[nbase + 2 * t + 1] = eb0 + excl + c0;
  hist[2 * t] = excl;            // cursor init (own bins; all reads done above)
  hist[2 * t + 1] = excl + c0;
  __syncthreads();
  for (int e = eb0 + t; e < eb1; e += 256){
    int rec = ebuf[e];
    int bin = (rec >> 20) & 511;
    int p = atomicAdd(&hist[bin], 1);
    pedge[eb0 + p] = rec & 0xFFFFF;   // src | et<<18
  }
  if (b == NBKT - 1 && t == 0) rowfin[2 * NN] = 2 * NE;
}

// ---------------- aggregation: 8-lane groups, uint4 feature slices ----------------
template<int L>
__device__ __forceinline__ void dev_agg(
    const int* __restrict__ rowptr, const int* __restrict__ pedge,
    const float* __restrict__ a0, const float* __restrict__ a1,        // L==1
    const float* __restrict__ wa0, const float* __restrict__ wa1,      // L==0
    const int* __restrict__ u_nodes, const int* __restrict__ i_nodes, int nwords,
    const float* __restrict__ rtab, const short* __restrict__ rows,
    unsigned* __restrict__ xo32){
  int lane = threadIdx.x & 63, w = threadIdx.x >> 6;
  int grp = lane >> 3, cl = lane & 7;
  int n = (blockIdx.x * 4 + w) * 8 + grp;          // node for this 8-lane group
  int side = n >= NN;                               // uniform per wave (NN % 8 == 0)
  const float* rt = rtab + (side * 2 + L) * 4;
  float rt0 = rt[0], rt1 = rt[1], rt2 = rt[2], rt3 = rt[3];
  const int* nodesS = side ? i_nodes : u_nodes;
  const float* wa0S = wa0 + (size_t)side * nwords;
  const float* wa1S = wa1 + (size_t)side * nwords;
  const uint4* h4 = (const uint4*)rows;

  int r0 = rowptr[n], r1 = rowptr[n + 1];          // broadcast loads
  int deg = r1 - r0;
  float a1n;
  if (L == 0) a1n = wa1S[nodesS[n - side * NN]];
  else        a1n = a1[n];

  int pe[8]; int rowv[8]; float av[8]; uint4 hv[8];
#pragma unroll
  for (int j = 0; j < 8; j++)
    pe[j] = (j < deg) ? pedge[r0 + j] : 0;         // 8 independent broadcast loads
#pragma unroll
  for (int j = 0; j < 8; j++){
    int s = pe[j] & 0x3FFFF;
    if (L == 0){
      int wid = 0;
      if (j < deg) wid = nodesS[s - side * NN];
      rowv[j] = wid;
    } else {
      rowv[j] = s;
    }
  }
#pragma unroll
  for (int j = 0; j < 8; j++){
    av[j] = 0.f;
    if (j < deg) av[j] = (L == 0) ? wa0S[rowv[j]] : a0[rowv[j]];
    uint4 z; z.x = 0u; z.y = 0u; z.z = 0u; z.w = 0u;
    hv[j] = z;
    if (j < deg) hv[j] = h4[(long)rowv[j] * 8 + cl];   // 16B feature slice
  }
  float ax0 = 0.f, ay0 = 0.f, ax1 = 0.f, ay1 = 0.f;
  float ax2 = 0.f, ay2 = 0.f, ax3 = 0.f, ay3 = 0.f, den = 0.f;
#pragma unroll
  for (int j = 0; j < 8; j++){
    int et = (pe[j] >> 18) & 3;
    float rr = (et & 2) ? ((et & 1) ? rt3 : rt2) : ((et & 1) ? rt1 : rt0);
    float v = av[j] + a1n + rr;
    v = (v > 0.f) ? v : 0.2f * v;
    float ex = (j < deg) ? __expf(v) : 0.f;
    ax0 += ex * ulo2f(hv[j].x); ay0 += ex * uhi2f(hv[j].x);
    ax1 += ex * ulo2f(hv[j].y); ay1 += ex * uhi2f(hv[j].y);
    ax2 += ex * ulo2f(hv[j].z); ay2 += ex * uhi2f(hv[j].z);
    ax3 += ex * ulo2f(hv[j].w); ay3 += ex * uhi2f(hv[j].w);
    den += ex;
  }
  // rare tail: deg > 8 (~2% of nodes at Poisson(4))
  for (int e = r0 + 8; e < r1; ++e){
    int pe2 = pedge[e];
    int s = pe2 & 0x3FFFF;
    int et = (pe2 >> 18) & 3;
    float rr = (et & 2) ? ((et & 1) ? rt3 : rt2) : ((et & 1) ? rt1 : rt0);
    float avv; long row;
    if (L == 0){ int wid = nodesS[s - side * NN]; avv = wa0S[wid]; row = wid; }
    else       { avv = a0[s]; row = s; }
    float v = avv + a1n + rr;
    v = (v > 0.f) ? v : 0.2f * v;
    float ex = __expf(v);
    uint4 hvv = h4[row * 8 + cl];
    ax0 += ex * ulo2f(hvv.x); ay0 += ex * uhi2f(hvv.x);
    ax1 += ex * ulo2f(hvv.y); ay1 += ex * uhi2f(hvv.y);
    ax2 += ex * ulo2f(hvv.z); ay2 += ex * uhi2f(hvv.z);
    ax3 += ex * ulo2f(hvv.w); ay3 += ex * uhi2f(hvv.w);
    den += ex;
  }
  float inv = 1.f / (den + 1e-16f);
  uint4 o;
  o.x = fpack(ax0 * inv, ay0 * inv);
  o.y = fpack(ax1 * inv, ay1 * inv);
  o.z = fpack(ax2 * inv, ay2 * inv);
  o.w = fpack(ax3 * inv, ay3 * inv);
  ((uint4*)xo32)[(long)n * 8 + cl] = o;            // coalesced: 1KB per wave
}

__global__ __launch_bounds__(256) void k_agg0(
    const int* __restrict__ rowptr, const int* __restrict__ pedge,
    const float* __restrict__ wa0, const float* __restrict__ wa1,
    const int* __restrict__ u_nodes, const int* __restrict__ i_nodes, int nwords,
    const float* __restrict__ rtab, const short* __restrict__ wtab,
    unsigned* __restrict__ xo32){
  dev_agg<0>(rowptr, pedge, nullptr, nullptr, wa0, wa1, u_nodes, i_nodes, nwords,
             rtab, wtab, xo32);
}

__global__ __launch_bounds__(256) void k_agg1(
    const int* __restrict__ rowptr, const int* __restrict__ pedge,
    const float* __restrict__ a0, const float* __restrict__ a1,
    const float* __restrict__ rtab, const short* __restrict__ x,
    unsigned* __restrict__ xo32){
  dev_agg<1>(rowptr, pedge, a0, a1, nullptr, nullptr, nullptr, nullptr, 0,
             rtab, x, xo32);
}

// ---------------- fused post: x=relu(xagg@W+b); gates; gmp; trans_w; gated X1 + a0/a1 ----------------
// Stages A/B/maxpool are wave-local (rows [w*32,w*32+32), own gates) -> no block
// barriers needed there; only the cross-wave pooled-max combine + trans_w partials
// use __syncthreads. trans_w is k-split across the 4 waves (depth 16, not 64).
__global__ __launch_bounds__(256) void k_gp(
    int l, const short* __restrict__ xagg, const short8* __restrict__ frag,
    const float* __restrict__ cub, const float* __restrict__ cib,
    const float* __restrict__ waA_all, const float* __restrict__ ba_all,
    const float* __restrict__ qbuf, const float* __restrict__ twW_all,
    const float* __restrict__ twb_all, float* __restrict__ xfm,
    short* __restrict__ xnext, float* __restrict__ a0, float* __restrict__ a1){
  __shared__ short xt[128 * 72];       // padded rows (72 shorts) for bank spread
  __shared__ float gates[128];
  __shared__ float red[4][64];
  __shared__ float part[4][64];
  int b = blockIdx.x;                  // [0, 2NB)
  int side = b >= NB;
  int g = b - side * NB;
  long base = (long)side * NN + (long)g * 128;
  int tid = threadIdx.x, lane = tid & 63, w = tid >> 6;
  int m = lane & 15, q = lane >> 4;
  // hoisted loads: conv frags + bias + pool frags + qv (latency overlaps stage A)
  const short8* wfrag = frag + (side * 2 + l) * 512;
  const short8* pfrag = frag + 4 * 512;
  const float* bias = (side ? cib : cub) + l * 64;
  const float* qv_ = qbuf + ((size_t)(side * 2 + l) * NB + g) * 64;
  short8 Bf[4][2], Pf[4][2];
#pragma unroll
  for (int t = 0; t < 4; t++)
#pragma unroll
    for (int hh = 0; hh < 2; hh++){
      Bf[t][hh] = wfrag[(t * 2 + hh) * 64 + lane];
      Pf[t][hh] = pfrag[(t * 2 + hh) * 64 + lane];
    }
  float bs[4], qv[4];
#pragma unroll
  for (int t = 0; t < 4; t++){ bs[t] = bias[t * 16 + m]; qv[t] = qv_[t * 16 + m]; }
  // stage A: conv GEMM (rows w*32..w*32+31, wave-local)
  f32x4 accA[2][4];
#pragma unroll
  for (int rb = 0; rb < 2; rb++){
    long n0 = base + w * 32 + rb * 16;
    const short8* xr = (const short8*)(xagg + (n0 + m) * 64);
    short8 A0 = xr[q];
    short8 A1 = xr[q + 4];
#pragma unroll
    for (int t = 0; t < 4; t++){
      f32x4 acc = (f32x4){bs[t], bs[t], bs[t], bs[t]};
      acc = __builtin_amdgcn_mfma_f32_16x16x32_bf16(A0, Bf[t][0], acc, 0, 0, 0);
      acc = __builtin_amdgcn_mfma_f32_16x16x32_bf16(A1, Bf[t][1], acc, 0, 0, 0);
#pragma unroll
      for (int r = 0; r < 4; r++) acc[r] = fmaxf(acc[r], 0.f);
      accA[rb][t] = acc;
#pragma unroll
      for (int r = 0; r < 4; r++)
        xt[(w * 32 + rb * 16 + q * 4 + r) * 72 + t * 16 + m] = f2bs(acc[r]);
    }
  }
  __syncwarp();   // intra-wave LDS ordering only (xt rows are wave-local)
  // stage B: pool GEMM from LDS -> gates (wave-local rows)
#pragma unroll
  for (int rb = 0; rb < 2; rb++){
    int rowb = w * 32 + rb * 16;
    short8 A0 = *(const short8*)(xt + (rowb + m) * 72 + q * 8);
    short8 A1 = *(const short8*)(xt + (rowb + m) * 72 + 32 + q * 8);
    f32x4 accp[4];
#pragma unroll
    for (int t = 0; t < 4; t++){
      accp[t] = (f32x4){0.f, 0.f, 0.f, 0.f};
      accp[t] = __builtin_amdgcn_mfma_f32_16x16x32_bf16(A0, Pf[t][0], accp[t], 0, 0, 0);
      accp[t] = __builtin_amdgcn_mfma_f32_16x16x32_bf16(A1, Pf[t][1], accp[t], 0, 0, 0);
    }
#pragma unroll
    for (int r = 0; r < 4; r++){
      float p = accp[0][r] * qv[0] + accp[1][r] * qv[1] +
                accp[2][r] * qv[2] + accp[3][r] * qv[3];
      p += __shfl_xor(p, 1, 64); p += __shfl_xor(p, 2, 64);
      p += __shfl_xor(p, 4, 64); p += __shfl_xor(p, 8, 64);
      if (m == 0)
        gates[rowb + q * 4 + r] = 1.f / (1.f + __expf(-p * 0.125f));
    }
  }
  __syncwarp();   // intra-wave: gates rows are wave-local
  // gated max pool (wave-local rows) -> red[w][*]
  const unsigned* xt32 = (const unsigned*)xt;
  int c = lane & 31, half = lane >> 5;
  float mxx = 0.f, mxy = 0.f;
#pragma unroll
  for (int p = 0; p < 16; p++){
    int nn = w * 32 + 2 * p + half;
    unsigned v = xt32[nn * 36 + c];
    float gt = gates[nn];
    mxx = fmaxf(mxx, ulo2f(v) * gt);
    mxy = fmaxf(mxy, uhi2f(v) * gt);
  }
  mxx = fmaxf(mxx, __shfl_xor(mxx, 32, 64));
  mxy = fmaxf(mxy, __shfl_xor(mxy, 32, 64));
  if (half == 0){ red[w][2 * c] = mxx; red[w][2 * c + 1] = mxy; }
  __syncthreads();
  // trans_w: k-split across the 4 waves (depth 16 each), partials to LDS
  {
    const float* twW = twW_all + l * 4096;
    float o = 0.f;
    int k0 = w * 16;
#pragma unroll
    for (int kk = 0; kk < 16; kk++){
      int k = k0 + kk;
      float rk = fmaxf(fmaxf(red[0][k], red[1][k]), fmaxf(red[2][k], red[3][k]));
      o += rk * twW[k * 64 + lane];
    }
    part[w][lane] = o;
  }
  __syncthreads();
  if (tid < 64){
    const float* twb = twb_all + l * 64;
    int off = (side ? 256 : 64) + l * 64;
    float o = twb[tid] + part[0][tid] + part[1][tid] + part[2][tid] + part[3][tid];
    xfm[g * 384 + off + tid] = fmaxf(o, 0.f);
  }
  if (l == 0){
    // gated next-layer input write (coalesced via LDS; xt/gates visible post-barrier)
#pragma unroll
    for (int p = 0; p < 4; p++){
      int row = p * 32 + (tid >> 3);
      int col8 = (tid & 7) * 8;
      float gt = gates[row];
      short8 v = *(const short8*)(xt + row * 72 + col8);
      short8 o;
#pragma unroll
      for (int j = 0; j < 8; j++) o[j] = f2bs(bs2f(v[j]) * gt);
      *(short8*)(xnext + (base + row) * 64 + col8) = o;
    }
    // next-layer a0/a1 from gated x_next: a = g*(x.waA1) + ba1
    const float* wn0p = waA_all + ((side * 2 + 1) * 2 + 0) * 64;
    const float* wn1p = wn0p + 64;
    float wn0[4], wn1[4];
#pragma unroll
    for (int t = 0; t < 4; t++){ wn0[t] = wn0p[t * 16 + m]; wn1[t] = wn1p[t * 16 + m]; }
    float ban0 = ba_all[(side * 2 + 1) * 2 + 0];
    float ban1 = ba_all[(side * 2 + 1) * 2 + 1];
#pragma unroll
    for (int rb = 0; rb < 2; rb++)
#pragma unroll
      for (int r = 0; r < 4; r++){
        float p0 = accA[rb][0][r] * wn0[0] + accA[rb][1][r] * wn0[1] +
                   accA[rb][2][r] * wn0[2] + accA[rb][3][r] * wn0[3];
        float p1 = accA[rb][0][r] * wn1[0] + accA[rb][1][r] * wn1[1] +
                   accA[rb][2][r] * wn1[2] + accA[rb][3][r] * wn1[3];
        p0 += __shfl_xor(p0, 1, 64); p0 += __shfl_xor(p0, 2, 64);
        p0 += __shfl_xor(p0, 4, 64); p0 += __shfl_xor(p0, 8, 64);
        p1 += __shfl_xor(p1, 1, 64); p1 += __shfl_xor(p1, 2, 64);
        p1 += __shfl_xor(p1, 4, 64); p1 += __shfl_xor(p1, 8, 64);
        if (m == 0){
          int row = w * 32 + rb * 16 + q * 4 + r;
          float gr = gates[row];
          a0[base + row] = p0 * gr + ban0;
          a1[base + row] = p1 * gr + ban1;
        }
      }
  }
}

// ---------------- FM main: k-split partial xv/vv (4 chunks of 96) ----------------
__global__ __launch_bounds__(384) void k_fm2(
    const float* __restrict__ xfm, const float* __restrict__ V,
    float* __restrict__ xvp, float* __restrict__ vvp){
  __shared__ float xsh[4][96];
  __shared__ float xsq[4][96];
  int j = threadIdx.x;
  int bc = blockIdx.x;
  int c = bc & 3;                   // k-chunk
  int g0 = (bc >> 2) * 4;           // 4 graphs per block
  int k0 = c * 96;
  {
    int b = j / 96, kk = j - b * 96;
    float xv_ = xfm[(g0 + b) * 384 + k0 + kk];
    xsh[b][kk] = xv_;
    xsq[b][kk] = xv_ * xv_;
  }
  __syncthreads();
  float xv[4] = {0.f, 0.f, 0.f, 0.f};
  float vv[4] = {0.f, 0.f, 0.f, 0.f};
  for (int k = 0; k < 96; k++){
    float v = V[(size_t)(k0 + k) * 384 + j];
    float v2 = v * v;
#pragma unroll
    for (int b = 0; b < 4; b++){
      xv[b] = fmaf(xsh[b][k], v, xv[b]);
      vv[b] = fmaf(xsq[b][k], v2, vv[b]);
    }
  }
#pragma unroll
  for (int b = 0; b < 4; b++){
    size_t o = ((size_t)c * NB + g0 + b) * 384 + j;
    xvp[o] = xv[b];
    vvp[o] = vv[b];
  }
}

// ---------------- FM epilogue: combine partials, quadratic, reduce, biases ----------------
__global__ __launch_bounds__(384) void k_fm3(
    const float* __restrict__ xfm, const float* __restrict__ xvp,
    const float* __restrict__ vvp, const float* __restrict__ fw,
    const float* __restrict__ bu, const float* __restrict__ bi,
    const float* __restrict__ b0,
    const int* __restrict__ uid, const int* __restrict__ iid,
    float* __restrict__ out){
  __shared__ float part[4][384];
  int j = threadIdx.x;
  int g0 = blockIdx.x * 4;
  float fwj = fw[j];
  const size_t CS = (size_t)NB * 384;
#pragma unroll
  for (int b = 0; b < 4; b++){
    size_t gi = (size_t)(g0 + b) * 384 + j;
    float xv = xvp[gi] + xvp[CS + gi] + xvp[2 * CS + gi] + xvp[3 * CS + gi];
    float vv = vvp[gi] + vvp[CS + gi] + vvp[2 * CS + gi] + vvp[3 * CS + gi];
    float x = xfm[gi];
    part[b][j] = 0.5f * (xv * xv - vv) + x * fwj;
  }
  __syncthreads();
  int w = j >> 6, lane = j & 63;
  if (w < 4){
    float s = part[w][lane] + part[w][lane + 64] + part[w][lane + 128] +
              part[w][lane + 192] + part[w][lane + 256] + part[w][lane + 320];
    s = wsum(s);
    if (lane == 0){
      int b = g0 + w;
      out[b] = s + bu[uid[b]] + bi[iid[b]] + b0[0];
    }
  }
}

extern "C" void kernel_launch(void* const* d_in, const int* in_sizes, int n_in,
                              void* d_out, int out_size, void* d_ws, size_t ws_size,
                              hipStream_t stream) {
  const int* uid      = (const int*)d_in[0];
  const int* iid      = (const int*)d_in[1];
  const int* u_nodes  = (const int*)d_in[2];
  const int* i_nodes  = (const int*)d_in[3];
  const int* u_ei     = (const int*)d_in[4];
  const int* i_ei     = (const int*)d_in[5];
  const int* u_et     = (const int*)d_in[6];
  const int* i_et     = (const int*)d_in[7];
  const float* user_emb = (const float*)d_in[10];
  const float* item_emb = (const float*)d_in[11];
  const float* word_emb = (const float*)d_in[12];
  const float* trans_u_W = (const float*)d_in[13];
  const float* trans_u_b = (const float*)d_in[14];
  const float* trans_i_W = (const float*)d_in[15];
  const float* trans_i_b = (const float*)d_in[16];
  const float* trans_w_W = (const float*)d_in[17];
  const float* trans_w_b = (const float*)d_in[18];
  const float* inter_u_W = (const float*)d_in[19];
  const float* inter_u_b = (const float*)d_in[20];
  const float* inter_i_W = (const float*)d_in[21];
  const float* inter_i_b = (const float*)d_in[22];
  const float* conv_u_W  = (const float*)d_in[23];
  const float* conv_u_b  = (const float*)d_in[24];
  const float* conv_u_att= (const float*)d_in[25];
  const float* conv_u_rel= (const float*)d_in[26];
  const float* conv_i_W  = (const float*)d_in[27];
  const float* conv_i_b  = (const float*)d_in[28];
  const float* conv_i_att= (const float*)d_in[29];
  const float* conv_i_rel= (const float*)d_in[30];
  const float* pool_W    = (const float*)d_in[31];
  const float* fm_w      = (const float*)d_in[32];
  const float* fm_V      = (const float*)d_in[33];
  const float* fm_bias_u = (const float*)d_in[34];
  const float* fm_bias_i = (const float*)d_in[35];
  const float* fm_bias   = (const float*)d_in[36];
  float* out = (float*)d_out;
  int n32 = in_sizes[12] / 2;          // packed uints in word table
  int nwords = in_sizes[12] / 64;      // words (HID=64)
  int wconvB = (n32 + 255) / 256;

  // workspace carve-up (ebuf + xvp/vvp alias X0 — dead in their live ranges)
  char* w = (char*)d_ws;
  short* X0   = (short*)w;          w += (size_t)2 * NN * 64 * 2;   // 32 MB
  short* X1   = (short*)w;          w += (size_t)2 * NN * 64 * 2;   // 32 MB
  short* wtab = (short*)w;          w += (size_t)in_sizes[12] * 2;  // bf16 word table
  int* pedge  = (int*)w;            w += (size_t)2 * NE * 4;
  float* a0   = (float*)w;          w += (size_t)2 * NN * 4;
  float* a1   = (float*)w;          w += (size_t)2 * NN * 4;
  float* wa0  = (float*)w;          w += (size_t)2 * nwords * 4;
  float* wa1  = (float*)w;          w += (size_t)2 * nwords * 4;
  int* cntmat = (int*)w;            w += (size_t)K1B * NBKT * 4;    // 1 MB
  int* rowfin = (int*)w;            w += (size_t)(2 * NN + 256) * 4;
  int* btot   = (int*)w;            w += NBKT * 4;
  int* bbase  = (int*)w;            w += (NBKT + 1) * 4;
  short8* frag = (short8*)w;        w += (size_t)5 * 512 * 16;
  float* waA  = (float*)w;          w += 2 * 2 * 2 * 64 * 4;
  float* ba   = (float*)w;          w += 64;
  float* rtab = (float*)w;          w += 64;
  float* qbuf = (float*)w;          w += (size_t)4 * NB * 64 * 4;
  float* xfm  = (float*)w;          w += (size_t)NB * 384 * 4;
  int* ebuf = (int*)X0;             // 4 MB, dead before k_agg0 writes X0
  float* xvp = (float*)X0;          // 6 MB, live only after k_gp<1> read X0
  float* vvp = xvp + (size_t)4 * NB * 384;   // +6 MB (still inside X0's 32 MB)

  int megaB = K1B + 12 + wconvB + 2 * NB / 4;
  k_mega<<<megaB, 256, 0, stream>>>(wconvB, u_ei, i_ei, cntmat,
                                    word_emb, (unsigned*)wtab, n32,
                                    conv_u_W, conv_i_W, pool_W, conv_u_b, conv_i_b,
                                    conv_u_att, conv_i_att, conv_u_rel, conv_i_rel,
                                    frag, waA, ba, rtab,
                                    uid, iid, user_emb, item_emb,
                                    inter_u_W, inter_u_b, inter_i_W, inter_i_b,
                                    trans_u_W, trans_u_b, trans_i_W, trans_i_b,
                                    xfm, qbuf);
  k_colscan<<<NBKT, 256, 0, stream>>>(cntmat, btot);
  k_bscan<<<1, NBKT, 0, stream>>>(btot, bbase);
  int wgB = (2 * nwords + 31) / 32;
  k_scat<<<K1B + wgB, 256, 0, stream>>>(u_ei, i_ei, u_et, i_et, cntmat, bbase,
                                        ebuf, wtab, nwords, waA, ba, wa0, wa1);
  k_csr<<<NBKT, 256, 0, stream>>>(bbase, ebuf, rowfin, pedge);

  // layer 0: aggregate straight from the word table
  k_agg0<<<2 * NN / 32, 256, 0, stream>>>(rowfin, pedge, wa0, wa1,
                                          u_nodes, i_nodes, nwords, rtab,
                                          wtab, (unsigned*)X0);
  k_gp  <<<2 * NB, 256, 0, stream>>>(0, X0, frag, conv_u_b, conv_i_b, waA, ba,
                                     qbuf, trans_w_W, trans_w_b, xfm, X1, a0, a1);
  // layer 1
  k_agg1<<<2 * NN / 32, 256, 0, stream>>>(rowfin, pedge, a0, a1, rtab,
                                          X1, (unsigned*)X0);
  k_gp  <<<2 * NB, 256, 0, stream>>>(1, X0, frag, conv_u_b, conv_i_b, waA, ba,
                                     qbuf, trans_w_W, trans_w_b, xfm,
                                     nullptr, nullptr, nullptr);

  // FM head: k-split main + epilogue (xvp/vvp alias X0, dead after k_gp<1>)
  k_fm2<<<NB, 384, 0, stream>>>(xfm, fm_V, xvp, vvp);
  k_fm3<<<NB / 4, 384, 0, stream>>>(xfm, xvp, vvp, fm_w, fm_bias_u, fm_bias_i,
                                    fm_bias, uid, iid, out);
}